// Round 8
// baseline (344.419 us; speedup 1.0000x reference)
//
#include <hip/hip_runtime.h>
#include <hip/hip_bf16.h>
#include <cmath>
#include <cstdint>

typedef unsigned int u32;
typedef unsigned char u8;
typedef unsigned short ushort;
typedef __attribute__((ext_vector_type(8))) short short8;
typedef __attribute__((ext_vector_type(4))) float f32x4;
typedef __attribute__((ext_vector_type(16))) float f32x16;
typedef __attribute__((ext_vector_type(4))) unsigned short us4;

#define Gn 2048
#define Hd 256
#define CSTRIDE 192

static __device__ __forceinline__ ushort f2bf(float x) {
    __hip_bfloat16 b = __float2bfloat16(x);
    return *reinterpret_cast<ushort*>(&b);
}
static __device__ __forceinline__ float bf2f(ushort u) {
    return __uint_as_float(((u32)u) << 16);
}
// order-preserving float<->u32 encoding for deterministic atomicMax
static __device__ __forceinline__ u32 encf(float f) {
    u32 u = __float_as_uint(f);
    return u ^ (u32)(((int)u >> 31) | 0x80000000);
}
static __device__ __forceinline__ float decf(u32 u) {
    return __uint_as_float((u & 0x80000000u) ? (u ^ 0x80000000u) : ~u);
}

// ---------------------------------------------------------------------------
// Mask dtype detection (64 blocks x 256 thr x 16B = 256KB scan).
// cnt[0]: nonzero bytes at offset%4==0; cnt[1]: elsewhere.
// ---------------------------------------------------------------------------
__global__ __launch_bounds__(256) void detect2_kernel(const u8* __restrict__ src,
                                                      int* __restrict__ cnt) {
    const int idx = blockIdx.x * 256 + threadIdx.x;
    const uint4 w = ((const uint4*)src)[idx];
    int c0 = ((w.x & 0xffu) ? 1 : 0) + ((w.y & 0xffu) ? 1 : 0) +
             ((w.z & 0xffu) ? 1 : 0) + ((w.w & 0xffu) ? 1 : 0);
    int c1 = ((w.x & 0xffffff00u) ? 1 : 0) + ((w.y & 0xffffff00u) ? 1 : 0) +
             ((w.z & 0xffffff00u) ? 1 : 0) + ((w.w & 0xffffff00u) ? 1 : 0);
    #pragma unroll
    for (int o = 1; o < 64; o <<= 1) { c0 += __shfl_xor(c0, o); c1 += __shfl_xor(c1, o); }
    if ((threadIdx.x & 63) == 0) {
        if (c0) atomicAdd(&cnt[0], c0);
        if (c1) atomicAdd(&cnt[1], c1);
    }
}

// pack mask[2048][2048] (True=attend) into bits[z][2048][64]; z=0 pp, 1 rr
__global__ __launch_bounds__(256) void pack_mask_kernel(
    const u8* __restrict__ src0, const u8* __restrict__ src1,
    const int* __restrict__ cnt, u32* __restrict__ bits)
{
    const int z = blockIdx.y;
    const u8* src = z ? src1 : src0;
    u32* bz = bits + (long)z * 131072;
    const int idx = blockIdx.x * 256 + threadIdx.x;
    const int row = idx >> 6;
    const int w = idx & 63;
    const int f = (cnt[0] > 0) ? ((cnt[1] > 0) ? 1 : 0) : 2;
    u32 v = 0;
    if (f == 1) {
        const uint4* p = (const uint4*)(src + (long)row * 2048 + w * 32);
        const uint4 q0 = p[0], q1 = p[1];
        const u32 ws8[8] = {q0.x, q0.y, q0.z, q0.w, q1.x, q1.y, q1.z, q1.w};
        #pragma unroll
        for (int j = 0; j < 8; ++j) {
            const u32 x = ws8[j];
            const u32 m = (((x & 0x7f7f7f7fu) + 0x7f7f7f7fu) | x) & 0x80808080u;
            const u32 b4 = ((m >> 7) & 1u) | ((m >> 14) & 2u) |
                           ((m >> 21) & 4u) | ((m >> 28) & 8u);
            v |= b4 << (j * 4);
        }
    } else if (f == 0) {
        const uint4* p = (const uint4*)((const int*)src + (long)row * 2048 + w * 32);
        #pragma unroll
        for (int j = 0; j < 8; ++j) {
            const uint4 q = p[j];
            v |= (q.x ? 1u : 0u) << (j * 4 + 0);
            v |= (q.y ? 1u : 0u) << (j * 4 + 1);
            v |= (q.z ? 1u : 0u) << (j * 4 + 2);
            v |= (q.w ? 1u : 0u) << (j * 4 + 3);
        }
    } else {
        const uint4* p = (const uint4*)((const float*)src + (long)row * 2048 + w * 32);
        #pragma unroll
        for (int j = 0; j < 8; ++j) {
            const uint4 q = p[j];
            v |= ((q.x & 0x7fffffffu) ? 1u : 0u) << (j * 4 + 0);
            v |= ((q.y & 0x7fffffffu) ? 1u : 0u) << (j * 4 + 1);
            v |= ((q.z & 0x7fffffffu) ? 1u : 0u) << (j * 4 + 2);
            v |= ((q.w & 0x7fffffffu) ? 1u : 0u) << (j * 4 + 3);
        }
    }
    bz[idx] = v;
}

// ---------------------------------------------------------------------------
// Direct CSR with fixed row stride (192 >> max expected degree ~20, 9+ sigma;
// clamp would fail absmax loudly). One thread per row, in-order bits.
// ---------------------------------------------------------------------------
__global__ __launch_bounds__(256) void csr_direct_kernel(
    const u32* __restrict__ bits, int* __restrict__ deg, int* __restrict__ colidx)
{
    const int z = blockIdx.y;
    const int r = blockIdx.x * 256 + threadIdx.x;
    const u32* b = bits + (long)z * 131072 + r * 64;
    int* ci = colidx + ((long)z * 2048 + r) * CSTRIDE;
    int d = 0;
    for (int w = 0; w < 64; ++w) {
        u32 x = b[w];
        while (x) {
            const int j = __ffs(x) - 1;
            if (d < CSTRIDE) ci[d] = w * 32 + j;
            ++d;
            x &= x - 1;
        }
    }
    deg[z * 2048 + r] = d < CSTRIDE ? d : CSTRIDE;
}

// ---------------------------------------------------------------------------
// Weight pre-pass: transposed bf16 split arenas Bt_hi[n][k], Bt_lo[n][k].
// slots: 0 pre_w1, 1 pre_w2, 2-5 wm0 QKVO, 6-9 wm1 QKVO, 10-13 ws0 QKVO,
//        14 gate_w1 (ncols=128), 15 tr_w.
// ---------------------------------------------------------------------------
__global__ __launch_bounds__(256) void preconv_kernel(
    const float* __restrict__ pre_w1, const float* __restrict__ pre_w2,
    const float* __restrict__ wm, const float* __restrict__ wsw,
    const float* __restrict__ gate_w1, const float* __restrict__ tr_w,
    ushort* __restrict__ bt_hi, ushort* __restrict__ bt_lo)
{
    const int slot = blockIdx.x;
    const int k0 = blockIdx.y * 32;
    const float* src; int ncols = 256;
    if (slot == 0) src = pre_w1;
    else if (slot == 1) src = pre_w2;
    else if (slot < 6) src = wm + (long)(slot - 2) * 65536;
    else if (slot < 10) src = wm + (long)(4 + slot - 6) * 65536;
    else if (slot < 14) src = wsw + (long)(slot - 10) * 65536;
    else if (slot == 14) { src = gate_w1; ncols = 128; }
    else src = tr_w;

    __shared__ float T[32][257];
    const int tid = threadIdx.x;
    const int lsh = (ncols == 256) ? 6 : 5;
    const int tot = 32 << lsh;
    for (int i = tid; i < tot; i += 256) {
        const int kk = i >> lsh, c4 = (i & ((1 << lsh) - 1)) << 2;
        const float4 v = *(const float4*)&src[(long)(k0 + kk) * ncols + c4];
        T[kk][c4 + 0] = v.x; T[kk][c4 + 1] = v.y;
        T[kk][c4 + 2] = v.z; T[kk][c4 + 3] = v.w;
    }
    __syncthreads();
    if (tid < ncols) {
        ushort hb[32], lb[32];
        #pragma unroll
        for (int kk = 0; kk < 32; ++kk) {
            const float x = T[kk][tid];
            const u32 bi = __float_as_uint(x);
            const ushort h = (ushort)(bi >> 16);
            const float fh = __uint_as_float(bi & 0xffff0000u);
            hb[kk] = h; lb[kk] = f2bf(x - fh);
        }
        ushort* oh = bt_hi + (long)slot * 65536 + tid * 256 + k0;
        ushort* ol = bt_lo + (long)slot * 65536 + tid * 256 + k0;
        #pragma unroll
        for (int q = 0; q < 4; ++q) {
            *(uint4*)&oh[q * 8] = *(const uint4*)&hb[q * 8];
            *(uint4*)&ol[q * 8] = *(const uint4*)&lb[q * 8];
        }
    }
}

// ---------------------------------------------------------------------------
// bf16x3 split-precision MFMA GEMM (~fp32 accurate): C[M,N] (+)= A @ W
// 1-wave blocks, 16 rows x 32 cols. OUTMODE 1 = QKV bf16 epilogue
// (Q pre-scaled 1/sqrt(32)*log2e). QKVMODE 1: M block, V row-layout;
// QKVMODE 2: S block, V transposed. KT=512: k>=256 from slot2 (dual-Wo).
// ---------------------------------------------------------------------------
template <int BETA, int RELU, int OUTMODE, int QKVMODE, int KT>
__global__ __launch_bounds__(64) void gemm_mfma_kernel(
    const float* __restrict__ A, int lda,
    const ushort* __restrict__ bt_hi, const ushort* __restrict__ bt_lo,
    int slot0, int slot2, const float* __restrict__ bias,
    float* __restrict__ C, int N)
{
    const int l = threadIdx.x;
    const int lr = l & 15, lg = l >> 4;
    const int row = blockIdx.x * 16 + lr;
    const int col0 = blockIdx.y * 32;
    int slot = slot0, zq = 0, buf = 0;
    if (QKVMODE == 1) {
        const int z = blockIdx.z;
        slot = slot0 + z + z / 3; zq = z % 3; buf = z / 3;
    } else if (QKVMODE == 2) {
        slot = slot0 + blockIdx.z; zq = blockIdx.z;
    }
    const ushort* bhb = bt_hi + (long)slot * 65536;
    const ushort* blb = bt_lo + (long)slot * 65536;
    const float* arow = A + (long)row * lda;

    const f32x4 z4 = {0.f, 0.f, 0.f, 0.f};
    f32x4 acc[2] = {z4, z4};

    #pragma unroll
    for (int ks = 0; ks < KT / 32; ++ks) {
        const int k0 = ks * 32;
        const ushort* bh; const ushort* bl;
        if (KT == 512 && k0 >= 256) {
            bh = bt_hi + (long)slot2 * 65536 + (k0 - 256);
            bl = bt_lo + (long)slot2 * 65536 + (k0 - 256);
        } else { bh = bhb + k0; bl = blb + k0; }
        float av[8];
        *(float4*)&av[0] = *(const float4*)&arow[k0 + lg * 8];
        *(float4*)&av[4] = *(const float4*)&arow[k0 + lg * 8 + 4];
        short8 ahi, alo;
        #pragma unroll
        for (int j = 0; j < 8; ++j) {
            const u32 bi = __float_as_uint(av[j]);
            ahi[j] = (short)(bi >> 16);
            const float fh = __uint_as_float(bi & 0xffff0000u);
            alo[j] = (short)f2bf(av[j] - fh);
        }
        #pragma unroll
        for (int f = 0; f < 2; ++f) {
            const long bo = (long)(col0 + f * 16 + lr) * 256 + lg * 8;
            const short8 bhi = *(const short8*)&bh[bo];
            const short8 blo = *(const short8*)&bl[bo];
            acc[f] = __builtin_amdgcn_mfma_f32_16x16x32_bf16(ahi, bhi, acc[f], 0, 0, 0);
            acc[f] = __builtin_amdgcn_mfma_f32_16x16x32_bf16(alo, bhi, acc[f], 0, 0, 0);
            acc[f] = __builtin_amdgcn_mfma_f32_16x16x32_bf16(ahi, blo, acc[f], 0, 0, 0);
        }
    }

    const float QS = 0.17677669529663687f * 1.4426950408889634f;

    #pragma unroll
    for (int f = 0; f < 2; ++f) {
        const int col = col0 + f * 16 + lr;
        const float bv = bias ? bias[col] : 0.f;
        #pragma unroll
        for (int r = 0; r < 4; ++r) {
            const int rr = blockIdx.x * 16 + lg * 4 + r;
            float v = acc[f][r] + bv;
            if (OUTMODE == 1) {
                if (zq == 0) v *= QS;
                ushort* ob = (ushort*)C + (long)buf * 1572864;
                const int h = col >> 5, d = col & 31;
                if (QKVMODE == 1 || zq < 2)
                    ob[zq * 524288 + ((h * 2048 + rr) << 5) + d] = f2bf(v);
                else
                    ob[1048576 + ((h * 32 + d) << 11) + rr] = f2bf(v);
            } else {
                if (BETA) v += C[(long)rr * N + col];
                if (RELU) v = fmaxf(v, 0.f);
                C[(long)rr * N + col] = v;
            }
        }
    }
}

// ---------------------------------------------------------------------------
// Fused GEMM(+residual) + LayerNorm (+relu) (+dup): 1 wave = 16 rows x 256
// cols (16 frags). Row stats via in-lane sums + 4-step shfl within the
// 16-lane group that shares lg. Exact LN semantics (mean, E[x^2]-mean^2).
// ---------------------------------------------------------------------------
template <int RELU, int DUP, int BETA>
__global__ __launch_bounds__(64) void gemm_ln_kernel(
    const float* __restrict__ A, int lda,
    const ushort* __restrict__ bt_hi, const ushort* __restrict__ bt_lo, int slot,
    const float* __restrict__ bias, const float* __restrict__ bsrc,
    const float* __restrict__ gw, const float* __restrict__ bw,
    float* __restrict__ Y, float* __restrict__ Y2)
{
    const int l = threadIdx.x;
    const int lr = l & 15, lg = l >> 4;
    const int row0 = blockIdx.x * 16;
    const ushort* bh0 = bt_hi + (long)slot * 65536;
    const ushort* bl0 = bt_lo + (long)slot * 65536;
    const float* arow = A + (long)(row0 + lr) * lda;

    const f32x4 z4 = {0.f, 0.f, 0.f, 0.f};
    f32x4 acc[16];
    #pragma unroll
    for (int f = 0; f < 16; ++f) acc[f] = z4;

    #pragma unroll
    for (int ks = 0; ks < 8; ++ks) {
        const int k0 = ks * 32;
        float av[8];
        *(float4*)&av[0] = *(const float4*)&arow[k0 + lg * 8];
        *(float4*)&av[4] = *(const float4*)&arow[k0 + lg * 8 + 4];
        short8 ahi, alo;
        #pragma unroll
        for (int j = 0; j < 8; ++j) {
            const u32 bi = __float_as_uint(av[j]);
            ahi[j] = (short)(bi >> 16);
            const float fh = __uint_as_float(bi & 0xffff0000u);
            alo[j] = (short)f2bf(av[j] - fh);
        }
        #pragma unroll
        for (int f = 0; f < 16; ++f) {
            const long bo = (long)(f * 16 + lr) * 256 + k0 + lg * 8;
            const short8 bhi = *(const short8*)&bh0[bo];
            const short8 blo = *(const short8*)&bl0[bo];
            acc[f] = __builtin_amdgcn_mfma_f32_16x16x32_bf16(ahi, bhi, acc[f], 0, 0, 0);
            acc[f] = __builtin_amdgcn_mfma_f32_16x16x32_bf16(alo, bhi, acc[f], 0, 0, 0);
            acc[f] = __builtin_amdgcn_mfma_f32_16x16x32_bf16(ahi, blo, acc[f], 0, 0, 0);
        }
    }

    float bv[16];
    #pragma unroll
    for (int f = 0; f < 16; ++f) bv[f] = bias ? bias[f * 16 + lr] : 0.f;
    #pragma unroll
    for (int f = 0; f < 16; ++f)
        #pragma unroll
        for (int r = 0; r < 4; ++r) {
            float v = acc[f][r] + bv[f];
            if (BETA) v += bsrc[(long)(row0 + lg * 4 + r) * 256 + f * 16 + lr];
            acc[f][r] = v;
        }
    float gl[16], bl_[16];
    #pragma unroll
    for (int f = 0; f < 16; ++f) { gl[f] = gw[f * 16 + lr]; bl_[f] = bw[f * 16 + lr]; }

    #pragma unroll
    for (int r = 0; r < 4; ++r) {
        float s = 0.f, s2 = 0.f;
        #pragma unroll
        for (int f = 0; f < 16; ++f) { const float v = acc[f][r]; s += v; s2 += v * v; }
        #pragma unroll
        for (int o = 1; o < 16; o <<= 1) { s += __shfl_xor(s, o); s2 += __shfl_xor(s2, o); }
        const float mean = s * (1.f / 256.f);
        const float var = s2 * (1.f / 256.f) - mean * mean;
        const float rs = rsqrtf(var + 1e-5f);
        const long rowoff = (long)(row0 + lg * 4 + r) * 256;
        #pragma unroll
        for (int f = 0; f < 16; ++f) {
            float y = (acc[f][r] - mean) * rs * gl[f] + bl_[f];
            if (RELU) y = fmaxf(y, 0.f);
            Y[rowoff + f * 16 + lr] = y;
            if (DUP) Y2[rowoff + f * 16 + lr] = y;
        }
    }
}

// ---------------------------------------------------------------------------
// Sparse masked attention (M block), exp2 domain. One wave per (row, graph):
// lane = head(3b) x dim-group(3b). Online softmax over the row's allowed keys
// only — consistent with dense where(mask,s,-1e9) since exp underflows to 0.
// deg==0 -> uniform = mean(V) (inline; probability ~1e-9 on fixed data).
// ---------------------------------------------------------------------------
__global__ __launch_bounds__(64) void attn_sparse_kernel(
    const ushort* __restrict__ qkvb, const int* __restrict__ deg,
    const int* __restrict__ colidx, float* __restrict__ ctx)
{
    const int r = blockIdx.x, z = blockIdx.y;
    const ushort* qb = qkvb + (long)z * 1572864;
    const ushort* kb = qb + 524288;
    const ushort* vr = qb + 1048576;
    const int l = threadIdx.x;
    const int h = l >> 3, dg = l & 7;
    float* orow = &ctx[(long)r * 512 + z * 256 + h * 32 + dg * 4];
    const int n = deg[z * 2048 + r];
    if (n == 0) {
        float a0 = 0.f, a1 = 0.f, a2 = 0.f, a3 = 0.f;
        for (int k = 0; k < 2048; ++k) {
            const us4 vv = *(const us4*)&vr[((h * 2048 + k) << 5) + dg * 4];
            a0 += bf2f(vv[0]); a1 += bf2f(vv[1]); a2 += bf2f(vv[2]); a3 += bf2f(vv[3]);
        }
        float4 o; const float inv = 1.f / 2048.f;
        o.x = a0 * inv; o.y = a1 * inv; o.z = a2 * inv; o.w = a3 * inv;
        *(float4*)orow = o;
        return;
    }
    float q0, q1, q2, q3;
    {
        const us4 qv = *(const us4*)&qb[((h * 2048 + r) << 5) + dg * 4];
        q0 = bf2f(qv[0]); q1 = bf2f(qv[1]); q2 = bf2f(qv[2]); q3 = bf2f(qv[3]);
    }
    const int* ci = colidx + ((long)z * 2048 + r) * CSTRIDE;
    float m = -INFINITY, lsum = 0.f;
    float a0 = 0.f, a1 = 0.f, a2 = 0.f, a3 = 0.f;
    int kn = ci[0];
    us4 kv = *(const us4*)&kb[((h * 2048 + kn) << 5) + dg * 4];
    us4 vv = *(const us4*)&vr[((h * 2048 + kn) << 5) + dg * 4];
    for (int e = 0; e < n; ++e) {
        const us4 kc = kv, vc = vv;
        if (e + 1 < n) {
            kn = ci[e + 1];
            kv = *(const us4*)&kb[((h * 2048 + kn) << 5) + dg * 4];
            vv = *(const us4*)&vr[((h * 2048 + kn) << 5) + dg * 4];
        }
        float s = q0 * bf2f(kc[0]) + q1 * bf2f(kc[1]) +
                  q2 * bf2f(kc[2]) + q3 * bf2f(kc[3]);
        s += __shfl_xor(s, 1); s += __shfl_xor(s, 2); s += __shfl_xor(s, 4);
        const float mn = fmaxf(m, s);
        const float fac = __builtin_amdgcn_exp2f(m - mn);
        const float p = __builtin_amdgcn_exp2f(s - mn);
        lsum = lsum * fac + p;
        a0 = a0 * fac + p * bf2f(vc[0]);
        a1 = a1 * fac + p * bf2f(vc[1]);
        a2 = a2 * fac + p * bf2f(vc[2]);
        a3 = a3 * fac + p * bf2f(vc[3]);
        m = mn;
    }
    const float inv = 1.f / lsum;
    float4 o; o.x = a0 * inv; o.y = a1 * inv; o.z = a2 * inv; o.w = a3 * inv;
    *(float4*)orow = o;
}

// ---------------------------------------------------------------------------
// Dense attention (S block): 32x32x16 swapped MFMA, in-register P via
// cvt_pk_bf16 + permlane32_swap, exp2 domain, k-split x8 (512 threads),
// LDS merge + padded-LDS transposed coalesced store.
// ---------------------------------------------------------------------------
__global__ __launch_bounds__(512) void attn_dense_kernel(
    const ushort* __restrict__ qkvb, float* __restrict__ ctx)
{
    const ushort* qb = qkvb;
    const ushort* kb = qb + 524288;
    const ushort* vt = qb + 1048576;
    const int h = blockIdx.x, qt = blockIdx.y;
    const int wv = threadIdx.x >> 6;
    const int l = threadIdx.x & 63;
    const int lq = l & 31;
    const int hi = l >> 5;
    const int qglob = qt * 32 + lq;

    __shared__ float Mm[7][32], Ml[7][32];
    __shared__ float Macc[7][64][16];
    __shared__ float ctile[32][33];

    const int qoff = ((h * 2048 + qglob) << 5) + hi * 8;
    const short8 qf0 = *(const short8*)&qb[qoff];
    const short8 qf1 = *(const short8*)&qb[qoff + 16];

    float m = -INFINITY, lsum = 0.f;
    f32x16 acc, zz16;
    #pragma unroll
    for (int i = 0; i < 16; ++i) { acc[i] = 0.f; zz16[i] = 0.f; }

    const int kt0 = wv * 256;
    #pragma unroll 2
    for (int it = 0; it < 8; ++it) {
        const int kbase = kt0 + it * 32;
        const int koff = ((h * 2048 + kbase + lq) << 5) + hi * 8;
        const short8 kf0 = *(const short8*)&kb[koff];
        const short8 kf1 = *(const short8*)&kb[koff + 16];
        f32x16 s = __builtin_amdgcn_mfma_f32_32x32x16_bf16(kf0, qf0, zz16, 0, 0, 0);
        s = __builtin_amdgcn_mfma_f32_32x32x16_bf16(kf1, qf1, s, 0, 0, 0);
        float sc[16];
        #pragma unroll
        for (int i = 0; i < 16; ++i) sc[i] = s[i];
        float t[8];
        #pragma unroll
        for (int i = 0; i < 8; ++i) t[i] = fmaxf(sc[i], sc[i + 8]);
        #pragma unroll
        for (int i = 0; i < 4; ++i) t[i] = fmaxf(t[i], t[i + 4]);
        float mt = fmaxf(fmaxf(t[0], t[1]), fmaxf(t[2], t[3]));
        mt = fmaxf(mt, __shfl_xor(mt, 32));
        const float mn = fmaxf(m, mt);
        if (__ballot(mn != m)) {
            const float fac = __builtin_amdgcn_exp2f(m - mn);
            lsum *= fac;
            #pragma unroll
            for (int i = 0; i < 16; ++i) acc[i] *= fac;
            m = mn;
        }
        #pragma unroll
        for (int i = 0; i < 16; ++i) sc[i] = __builtin_amdgcn_exp2f(sc[i] - m);
        #pragma unroll
        for (int i = 0; i < 8; ++i) t[i] = sc[i] + sc[i + 8];
        #pragma unroll
        for (int i = 0; i < 4; ++i) t[i] = t[i] + t[i + 4];
        float ps = (t[0] + t[1]) + (t[2] + t[3]);
        ps += __shfl_xor(ps, 32);
        lsum += ps;
        u32 pk[8];
        #pragma unroll
        for (int g = 0; g < 4; ++g) {
            asm("v_cvt_pk_bf16_f32 %0, %1, %2"
                : "=v"(pk[2 * g]) : "v"(sc[4 * g + 0]), "v"(sc[4 * g + 1]));
            asm("v_cvt_pk_bf16_f32 %0, %1, %2"
                : "=v"(pk[2 * g + 1]) : "v"(sc[4 * g + 2]), "v"(sc[4 * g + 3]));
        }
        asm volatile("v_permlane32_swap_b32 %0, %1" : "+v"(pk[0]), "+v"(pk[2]));
        asm volatile("v_permlane32_swap_b32 %0, %1" : "+v"(pk[1]), "+v"(pk[3]));
        asm volatile("v_permlane32_swap_b32 %0, %1" : "+v"(pk[4]), "+v"(pk[6]));
        asm volatile("v_permlane32_swap_b32 %0, %1" : "+v"(pk[5]), "+v"(pk[7]));
        short8 pB0, pB1;
        ((u32*)&pB0)[0] = pk[0]; ((u32*)&pB0)[1] = pk[1];
        ((u32*)&pB0)[2] = pk[2]; ((u32*)&pB0)[3] = pk[3];
        ((u32*)&pB1)[0] = pk[4]; ((u32*)&pB1)[1] = pk[5];
        ((u32*)&pB1)[2] = pk[6]; ((u32*)&pB1)[3] = pk[7];
        const int voff = ((h * 32 + lq) << 11) + kbase + hi * 8;
        const short8 vf0 = *(const short8*)&vt[voff];
        const short8 vf1 = *(const short8*)&vt[voff + 16];
        acc = __builtin_amdgcn_mfma_f32_32x32x16_bf16(vf0, pB0, acc, 0, 0, 0);
        acc = __builtin_amdgcn_mfma_f32_32x32x16_bf16(vf1, pB1, acc, 0, 0, 0);
    }

    if (wv) {
        if (l < 32) { Mm[wv - 1][l] = m; Ml[wv - 1][l] = lsum; }
        #pragma unroll
        for (int i = 0; i < 16; ++i) Macc[wv - 1][l][i] = acc[i];
    }
    __syncthreads();
    if (wv == 0) {
        float M = m;
        #pragma unroll
        for (int w = 0; w < 7; ++w) M = fmaxf(M, Mm[w][lq]);
        const float f0 = __builtin_amdgcn_exp2f(m - M);
        float den = lsum * f0;
        float o[16];
        #pragma unroll
        for (int i = 0; i < 16; ++i) o[i] = acc[i] * f0;
        #pragma unroll
        for (int w = 0; w < 7; ++w) {
            const float fw = __builtin_amdgcn_exp2f(Mm[w][lq] - M);
            den += Ml[w][lq] * fw;
            #pragma unroll
            for (int i = 0; i < 16; ++i) o[i] += Macc[w][l][i] * fw;
        }
        const float inv = 1.f / den;
        #pragma unroll
        for (int i = 0; i < 16; ++i)
            ctile[(i & 3) + 8 * (i >> 2) + 4 * hi][lq] = o[i] * inv;
    }
    __syncthreads();
    if (threadIdx.x < 256) {
        const int t = threadIdx.x;
        const int q = t >> 3, d0 = (t & 7) << 2;
        float4 ov;
        ov.x = ctile[d0 + 0][q]; ov.y = ctile[d0 + 1][q];
        ov.z = ctile[d0 + 2][q]; ov.w = ctile[d0 + 3][q];
        *(float4*)&ctx[(long)(qt * 32 + q) * 512 + h * 32 + d0] = ov;
    }
}

// ---------------------------------------------------------------------------
// Aggregation GEMM: y<8 -> t = relu(xg@tr_w + tr_b) tile (32 cols);
// y==8 -> gate: relu(xg@gate_w1+gate_b1)@gate_w2+gate_b2 fully in-register
// (8 frags = 128 cols, shfl dot), writes gv + deterministic encoded atomicMax.
// ---------------------------------------------------------------------------
__global__ __launch_bounds__(64) void aggr_gemm_kernel(
    const float* __restrict__ xg,
    const ushort* __restrict__ bt_hi, const ushort* __restrict__ bt_lo,
    const float* __restrict__ tr_b, const float* __restrict__ g_b1,
    const float* __restrict__ g_w2, const float* __restrict__ g_b2,
    float* __restrict__ t_out, float* __restrict__ gv, u32* __restrict__ gmax)
{
    const int l = threadIdx.x;
    const int lr = l & 15, lg = l >> 4;
    const int row0 = blockIdx.x * 16;
    const int gate = (blockIdx.y == 8);
    const int slot = gate ? 14 : 15;
    const int col0 = gate ? 0 : blockIdx.y * 32;
    const int NF = gate ? 8 : 2;
    const ushort* bh0 = bt_hi + (long)slot * 65536;
    const ushort* bl0 = bt_lo + (long)slot * 65536;
    const float* arow = xg + (long)(row0 + lr) * 256;

    const f32x4 z4 = {0.f, 0.f, 0.f, 0.f};
    f32x4 acc[8] = {z4, z4, z4, z4, z4, z4, z4, z4};

    #pragma unroll
    for (int ks = 0; ks < 8; ++ks) {
        const int k0 = ks * 32;
        float av[8];
        *(float4*)&av[0] = *(const float4*)&arow[k0 + lg * 8];
        *(float4*)&av[4] = *(const float4*)&arow[k0 + lg * 8 + 4];
        short8 ahi, alo;
        #pragma unroll
        for (int j = 0; j < 8; ++j) {
            const u32 bi = __float_as_uint(av[j]);
            ahi[j] = (short)(bi >> 16);
            const float fh = __uint_as_float(bi & 0xffff0000u);
            alo[j] = (short)f2bf(av[j] - fh);
        }
        for (int f = 0; f < NF; ++f) {
            const long bo = (long)(col0 + f * 16 + lr) * 256 + k0 + lg * 8;
            const short8 bhi = *(const short8*)&bh0[bo];
            const short8 blo = *(const short8*)&bl0[bo];
            acc[f] = __builtin_amdgcn_mfma_f32_16x16x32_bf16(ahi, bhi, acc[f], 0, 0, 0);
            acc[f] = __builtin_amdgcn_mfma_f32_16x16x32_bf16(alo, bhi, acc[f], 0, 0, 0);
            acc[f] = __builtin_amdgcn_mfma_f32_16x16x32_bf16(ahi, blo, acc[f], 0, 0, 0);
        }
    }

    if (!gate) {
        #pragma unroll
        for (int f = 0; f < 2; ++f) {
            const int col = col0 + f * 16 + lr;
            const float bv = tr_b[col];
            #pragma unroll
            for (int r = 0; r < 4; ++r) {
                const int rr = row0 + lg * 4 + r;
                t_out[(long)rr * 256 + col] = fmaxf(acc[f][r] + bv, 0.f);
            }
        }
    } else {
        float b1v[8], w2v[8];
        #pragma unroll
        for (int f = 0; f < 8; ++f) {
            b1v[f] = g_b1[f * 16 + lr];
            w2v[f] = g_w2[f * 16 + lr];
        }
        const float b2 = g_b2[0];
        #pragma unroll
        for (int r = 0; r < 4; ++r) {
            float t = 0.f;
            #pragma unroll
            for (int f = 0; f < 8; ++f)
                t += fmaxf(acc[f][r] + b1v[f], 0.f) * w2v[f];
            #pragma unroll
            for (int o = 1; o < 16; o <<= 1) t += __shfl_xor(t, o);
            if (lr == 0) {
                const float g = t + b2;
                gv[row0 + lg * 4 + r] = g;
                atomicMax(gmax, encf(g));
            }
        }
    }
}

// partial[b][col] = sum over 32 rows of exp2((g-M)*log2e) * t[r][col];
// denp[b] = block's exp-sum. grid 64 x 256 thr.
__global__ __launch_bounds__(256) void wsum_part_kernel(
    const float* __restrict__ gv, const u32* __restrict__ gmax,
    const float* __restrict__ t, float* __restrict__ partial,
    float* __restrict__ denp)
{
    const float L2E = 1.4426950408889634f;
    const int b = blockIdx.x, tid = threadIdx.x;
    const float M = decf(*gmax);
    float s = 0.f, den = 0.f;
    #pragma unroll 4
    for (int i = 0; i < 32; ++i) {
        const int r = b * 32 + i;
        const float w = __builtin_amdgcn_exp2f((gv[r] - M) * L2E);
        den += w;
        s += w * t[(long)r * 256 + tid];
    }
    partial[b * 256 + tid] = s;
    if (tid == 0) denp[b] = den;
}

// out = (sum_b partial / sum_b den) @ head_w + head_b
__global__ __launch_bounds__(256) void head2_kernel(
    const float* __restrict__ partial, const float* __restrict__ denp,
    const float* __restrict__ hw, const float* __restrict__ hb,
    float* __restrict__ out)
{
    __shared__ float red0[4], red1[4];
    const int tid = threadIdx.x;
    float p = 0.f;
    #pragma unroll 8
    for (int b = 0; b < 64; ++b) p += partial[b * 256 + tid];
    float den = 0.f;
    #pragma unroll
    for (int b = 0; b < 64; ++b) den += denp[b];
    p /= den;
    float s0 = p * hw[tid * 2 + 0];
    float s1 = p * hw[tid * 2 + 1];
    #pragma unroll
    for (int o = 1; o < 64; o <<= 1) { s0 += __shfl_xor(s0, o); s1 += __shfl_xor(s1, o); }
    if ((tid & 63) == 0) { red0[tid >> 6] = s0; red1[tid >> 6] = s1; }
    __syncthreads();
    if (tid == 0) {
        out[0] = red0[0] + red0[1] + red0[2] + red0[3] + hb[0];
        out[1] = red1[0] + red1[1] + red1[2] + red1[3] + hb[1];
    }
}

// ---------------------------------------------------------------------------
extern "C" void kernel_launch(void* const* d_in, const int* in_sizes, int n_in,
                              void* d_out, int out_size, void* d_ws, size_t ws_size,
                              hipStream_t stream)
{
    (void)in_sizes; (void)n_in; (void)out_size; (void)ws_size;
    const float* gene_emb = (const float*)d_in[0];
    const float* pre_w1   = (const float*)d_in[3];
    const float* pre_b1   = (const float*)d_in[4];
    const float* pre_w2   = (const float*)d_in[5];
    const float* pre_b2   = (const float*)d_in[6];
    const float* pre_ln_g = (const float*)d_in[7];
    const float* pre_ln_b = (const float*)d_in[8];
    const float* wm       = (const float*)d_in[9];
    const float* wsw      = (const float*)d_in[10];
    const float* ln_g     = (const float*)d_in[11];
    const float* ln_b     = (const float*)d_in[12];
    const float* gate_w1  = (const float*)d_in[13];
    const float* gate_b1  = (const float*)d_in[14];
    const float* gate_w2  = (const float*)d_in[15];
    const float* gate_b2  = (const float*)d_in[16];
    const float* tr_w     = (const float*)d_in[17];
    const float* tr_b     = (const float*)d_in[18];
    const float* head_w   = (const float*)d_in[19];
    const float* head_b   = (const float*)d_in[20];
    const u8* adj_pp      = (const u8*)d_in[21];
    const u8* adj_rr      = (const u8*)d_in[22];
    // d_in[1],[2],[23],[24] dead (reaction/metab branches never reach output)

    const long NHf = (long)Gn * Hd;
    float* tmp0    = (float*)d_ws;                     // [2048][256] (t matrix)
    float* xg      = tmp0 + NHf;
    float* xg1     = xg + NHf;
    float* ctx2    = xg1 + NHf;                        // [2048][512]
    float* gv      = ctx2 + 2 * NHf;                   // [2048]
    float* partial = gv + Gn;                          // [64][256]
    float* denp    = partial + 64 * 256;               // [64]
    int* cnt       = (int*)(denp + 64);                // cnt[0],cnt[1],gmax
    int* deg       = cnt + 64;                         // [2][2048]
    int* colidx    = deg + 4096;                       // [2][2048][192]
    u32* bits      = (u32*)(colidx + 2L * 2048 * CSTRIDE);
    ushort* qkvb   = (ushort*)(bits + 262144);         // 2 x 1572864 bf16
    ushort* bt_hi  = qkvb + 2L * 1572864;              // 16 slots x 65536
    ushort* bt_lo  = bt_hi + 16L * 65536;

    dim3 B256(256), T64(64);
    dim3 gStd(128, 8);

    // prep: masks -> bits -> CSR; weights -> split arenas
    hipMemsetAsync((void*)cnt, 0, 16, stream);
    detect2_kernel<<<dim3(64), B256, 0, stream>>>(adj_pp, cnt);
    pack_mask_kernel<<<dim3(512, 2), B256, 0, stream>>>(adj_pp, adj_rr, cnt, bits);
    csr_direct_kernel<<<dim3(8, 2), B256, 0, stream>>>(bits, deg, colidx);
    preconv_kernel<<<dim3(16, 8), B256, 0, stream>>>(pre_w1, pre_w2, wm, wsw,
                                                     gate_w1, tr_w, bt_hi, bt_lo);

    // preprocessor (GEMM+LN fused): xg = relu(LN(relu(LN(ge@w1+b1))@w2+b2))
    gemm_ln_kernel<1, 0, 0><<<dim3(128), T64, 0, stream>>>(gene_emb, 256, bt_hi, bt_lo, 0, pre_b1, nullptr, pre_ln_g, pre_ln_b, xg, nullptr);
    gemm_ln_kernel<1, 1, 0><<<dim3(128), T64, 0, stream>>>(xg, 256, bt_hi, bt_lo, 1, pre_b2, nullptr, pre_ln_g, pre_ln_b, xg, xg1);

    // M block: QKV (z=6, V rows) -> sparse attn -> fused dual-Wo (K=512)
    gemm_mfma_kernel<0, 0, 1, 1, 256><<<dim3(128, 8, 6), T64, 0, stream>>>(xg, 256, bt_hi, bt_lo, 2, 0, nullptr, (float*)qkvb, 256);
    attn_sparse_kernel<<<dim3(2048, 2), T64, 0, stream>>>(qkvb, deg, colidx, ctx2);
    gemm_mfma_kernel<1, 0, 0, 0, 512><<<gStd, T64, 0, stream>>>(ctx2, 512, bt_hi, bt_lo, 5, 9, nullptr, xg1, 256);

    // S block: QKV (z=3, V transposed) -> dense attn -> Wo+residual+LN fused
    gemm_mfma_kernel<0, 0, 1, 2, 256><<<dim3(128, 8, 3), T64, 0, stream>>>(xg1, 256, bt_hi, bt_lo, 10, 0, nullptr, (float*)qkvb, 256);
    attn_dense_kernel<<<dim3(8, 64), dim3(512), 0, stream>>>(qkvb, ctx2);
    gemm_ln_kernel<0, 0, 1><<<dim3(128), T64, 0, stream>>>(ctx2, 512, bt_hi, bt_lo, 13, nullptr, xg1, ln_g, ln_b, xg, nullptr);

    // aggregation: tr tiles + in-register gate (y=8) -> weighted sum -> head
    aggr_gemm_kernel<<<dim3(128, 9), T64, 0, stream>>>(xg, bt_hi, bt_lo, tr_b, gate_b1, gate_w2, gate_b2, tmp0, gv, (u32*)&cnt[2]);
    wsum_part_kernel<<<dim3(64), B256, 0, stream>>>(gv, (const u32*)&cnt[2], tmp0, partial, denp);
    head2_kernel<<<dim3(1), B256, 0, stream>>>(partial, denp, head_w, head_b, (float*)d_out);
}

// Round 9
// 226.957 us; speedup vs baseline: 1.5175x; 1.5175x over previous
//
#include <hip/hip_runtime.h>
#include <hip/hip_bf16.h>
#include <cmath>
#include <cstdint>

typedef unsigned int u32;
typedef unsigned char u8;
typedef unsigned short ushort;
typedef __attribute__((ext_vector_type(8))) short short8;
typedef __attribute__((ext_vector_type(4))) float f32x4;
typedef __attribute__((ext_vector_type(16))) float f32x16;
typedef __attribute__((ext_vector_type(4))) unsigned short us4;

#define Gn 2048
#define Hd 256
#define CSTRIDE 192

static __device__ __forceinline__ ushort f2bf(float x) {
    __hip_bfloat16 b = __float2bfloat16(x);
    return *reinterpret_cast<ushort*>(&b);
}
static __device__ __forceinline__ float bf2f(ushort u) {
    return __uint_as_float(((u32)u) << 16);
}
// order-preserving float<->u32 encoding for deterministic atomicMax
static __device__ __forceinline__ u32 encf(float f) {
    u32 u = __float_as_uint(f);
    return u ^ (u32)(((int)u >> 31) | 0x80000000);
}
static __device__ __forceinline__ float decf(u32 u) {
    return __uint_as_float((u & 0x80000000u) ? (u ^ 0x80000000u) : ~u);
}

// ---------------------------------------------------------------------------
// Mask dtype detection (64 blocks x 256 thr x 16B = 256KB scan).
// cnt[0]: nonzero bytes at offset%4==0; cnt[1]: elsewhere.
// ---------------------------------------------------------------------------
__global__ __launch_bounds__(256) void detect2_kernel(const u8* __restrict__ src,
                                                      int* __restrict__ cnt) {
    const int idx = blockIdx.x * 256 + threadIdx.x;
    const uint4 w = ((const uint4*)src)[idx];
    int c0 = ((w.x & 0xffu) ? 1 : 0) + ((w.y & 0xffu) ? 1 : 0) +
             ((w.z & 0xffu) ? 1 : 0) + ((w.w & 0xffu) ? 1 : 0);
    int c1 = ((w.x & 0xffffff00u) ? 1 : 0) + ((w.y & 0xffffff00u) ? 1 : 0) +
             ((w.z & 0xffffff00u) ? 1 : 0) + ((w.w & 0xffffff00u) ? 1 : 0);
    #pragma unroll
    for (int o = 1; o < 64; o <<= 1) { c0 += __shfl_xor(c0, o); c1 += __shfl_xor(c1, o); }
    if ((threadIdx.x & 63) == 0) {
        if (c0) atomicAdd(&cnt[0], c0);
        if (c1) atomicAdd(&cnt[1], c1);
    }
}

// pack mask[2048][2048] (True=attend) into bits[z][2048][64]; z=0 pp, 1 rr
__global__ __launch_bounds__(256) void pack_mask_kernel(
    const u8* __restrict__ src0, const u8* __restrict__ src1,
    const int* __restrict__ cnt, u32* __restrict__ bits)
{
    const int z = blockIdx.y;
    const u8* src = z ? src1 : src0;
    u32* bz = bits + (long)z * 131072;
    const int idx = blockIdx.x * 256 + threadIdx.x;
    const int row = idx >> 6;
    const int w = idx & 63;
    const int f = (cnt[0] > 0) ? ((cnt[1] > 0) ? 1 : 0) : 2;
    u32 v = 0;
    if (f == 1) {
        const uint4* p = (const uint4*)(src + (long)row * 2048 + w * 32);
        const uint4 q0 = p[0], q1 = p[1];
        const u32 ws8[8] = {q0.x, q0.y, q0.z, q0.w, q1.x, q1.y, q1.z, q1.w};
        #pragma unroll
        for (int j = 0; j < 8; ++j) {
            const u32 x = ws8[j];
            const u32 m = (((x & 0x7f7f7f7fu) + 0x7f7f7f7fu) | x) & 0x80808080u;
            const u32 b4 = ((m >> 7) & 1u) | ((m >> 14) & 2u) |
                           ((m >> 21) & 4u) | ((m >> 28) & 8u);
            v |= b4 << (j * 4);
        }
    } else if (f == 0) {
        const uint4* p = (const uint4*)((const int*)src + (long)row * 2048 + w * 32);
        #pragma unroll
        for (int j = 0; j < 8; ++j) {
            const uint4 q = p[j];
            v |= (q.x ? 1u : 0u) << (j * 4 + 0);
            v |= (q.y ? 1u : 0u) << (j * 4 + 1);
            v |= (q.z ? 1u : 0u) << (j * 4 + 2);
            v |= (q.w ? 1u : 0u) << (j * 4 + 3);
        }
    } else {
        const uint4* p = (const uint4*)((const float*)src + (long)row * 2048 + w * 32);
        #pragma unroll
        for (int j = 0; j < 8; ++j) {
            const uint4 q = p[j];
            v |= ((q.x & 0x7fffffffu) ? 1u : 0u) << (j * 4 + 0);
            v |= ((q.y & 0x7fffffffu) ? 1u : 0u) << (j * 4 + 1);
            v |= ((q.z & 0x7fffffffu) ? 1u : 0u) << (j * 4 + 2);
            v |= ((q.w & 0x7fffffffu) ? 1u : 0u) << (j * 4 + 3);
        }
    }
    bz[idx] = v;
}

// ---------------------------------------------------------------------------
// Direct CSR with fixed row stride (192 >> expected max degree ~20; clamp
// would fail absmax loudly). One thread per row, in-order bit enumeration.
// ---------------------------------------------------------------------------
__global__ __launch_bounds__(256) void csr_direct_kernel(
    const u32* __restrict__ bits, int* __restrict__ deg, int* __restrict__ colidx)
{
    const int z = blockIdx.y;
    const int r = blockIdx.x * 256 + threadIdx.x;
    const u32* b = bits + (long)z * 131072 + r * 64;
    int* ci = colidx + ((long)z * 2048 + r) * CSTRIDE;
    int d = 0;
    for (int w = 0; w < 64; ++w) {
        u32 x = b[w];
        while (x) {
            const int j = __ffs(x) - 1;
            if (d < CSTRIDE) ci[d] = w * 32 + j;
            ++d;
            x &= x - 1;
        }
    }
    deg[z * 2048 + r] = d < CSTRIDE ? d : CSTRIDE;
}

// ---------------------------------------------------------------------------
// Weight pre-pass: transposed bf16 split arenas Bt_hi[n][k], Bt_lo[n][k].
// slots: 0 pre_w1, 1 pre_w2, 2-5 wm0 QKVO, 6-9 wm1 QKVO, 10-13 ws0 QKVO,
//        14 gate_w1 (ncols=128), 15 tr_w.
// ---------------------------------------------------------------------------
__global__ __launch_bounds__(256) void preconv_kernel(
    const float* __restrict__ pre_w1, const float* __restrict__ pre_w2,
    const float* __restrict__ wm, const float* __restrict__ wsw,
    const float* __restrict__ gate_w1, const float* __restrict__ tr_w,
    ushort* __restrict__ bt_hi, ushort* __restrict__ bt_lo)
{
    const int slot = blockIdx.x;
    const int k0 = blockIdx.y * 32;
    const float* src; int ncols = 256;
    if (slot == 0) src = pre_w1;
    else if (slot == 1) src = pre_w2;
    else if (slot < 6) src = wm + (long)(slot - 2) * 65536;
    else if (slot < 10) src = wm + (long)(4 + slot - 6) * 65536;
    else if (slot < 14) src = wsw + (long)(slot - 10) * 65536;
    else if (slot == 14) { src = gate_w1; ncols = 128; }
    else src = tr_w;

    __shared__ float T[32][257];
    const int tid = threadIdx.x;
    const int lsh = (ncols == 256) ? 6 : 5;
    const int tot = 32 << lsh;
    for (int i = tid; i < tot; i += 256) {
        const int kk = i >> lsh, c4 = (i & ((1 << lsh) - 1)) << 2;
        const float4 v = *(const float4*)&src[(long)(k0 + kk) * ncols + c4];
        T[kk][c4 + 0] = v.x; T[kk][c4 + 1] = v.y;
        T[kk][c4 + 2] = v.z; T[kk][c4 + 3] = v.w;
    }
    __syncthreads();
    if (tid < ncols) {
        ushort hb[32], lb[32];
        #pragma unroll
        for (int kk = 0; kk < 32; ++kk) {
            const float x = T[kk][tid];
            const u32 bi = __float_as_uint(x);
            const ushort h = (ushort)(bi >> 16);
            const float fh = __uint_as_float(bi & 0xffff0000u);
            hb[kk] = h; lb[kk] = f2bf(x - fh);
        }
        ushort* oh = bt_hi + (long)slot * 65536 + tid * 256 + k0;
        ushort* ol = bt_lo + (long)slot * 65536 + tid * 256 + k0;
        #pragma unroll
        for (int q = 0; q < 4; ++q) {
            *(uint4*)&oh[q * 8] = *(const uint4*)&hb[q * 8];
            *(uint4*)&ol[q * 8] = *(const uint4*)&lb[q * 8];
        }
    }
}

// ---------------------------------------------------------------------------
// bf16x3 split-precision MFMA GEMM (~fp32 accurate): C[M,N] (+)= A @ W (+bias)
// R6-proven config: 32x64 tile, 2 waves (128 thr), 4 frags, no LDS.
// OUTMODE 1 = QKV bf16 epilogue (Q pre-scaled 1/sqrt(32)*log2e).
// QKVMODE 1 (M): Q/K/V all row-layout [h][2048][32] (sparse attn needs V rows).
// QKVMODE 2 (S): Q/K rows + V transposed [h][32][2048] (dense attn).
// KT=512: k>=256 reads slot2 arena (fused dual-Wo accumulate).
// ---------------------------------------------------------------------------
template <int BETA, int RELU, int OUTMODE, int QKVMODE, int KT>
__global__ __launch_bounds__(128) void gemm_mfma_kernel(
    const float* __restrict__ A, int lda,
    const ushort* __restrict__ bt_hi, const ushort* __restrict__ bt_lo,
    int slot0, int slot2, const float* __restrict__ bias,
    float* __restrict__ C, int N)
{
    const int tid = threadIdx.x;
    const int wv = tid >> 6, l = tid & 63;
    const int lr = l & 15, lg = l >> 4;
    const int row = blockIdx.x * 32 + wv * 16 + lr;
    const int col0 = blockIdx.y * 64;
    int slot = slot0, zq = 0, buf = 0;
    if (QKVMODE == 1) {
        const int z = blockIdx.z;
        slot = slot0 + z + z / 3; zq = z % 3; buf = z / 3;
    } else if (QKVMODE == 2) {
        slot = slot0 + blockIdx.z; zq = blockIdx.z;
    }
    const ushort* bhb = bt_hi + (long)slot * 65536;
    const ushort* blb = bt_lo + (long)slot * 65536;
    const float* arow = A + (long)row * lda;

    const f32x4 z4 = {0.f, 0.f, 0.f, 0.f};
    f32x4 acc[4] = {z4, z4, z4, z4};

    #pragma unroll
    for (int ks = 0; ks < KT / 32; ++ks) {
        const int k0 = ks * 32;
        const ushort* bh; const ushort* bl;
        if (KT == 512 && k0 >= 256) {
            bh = bt_hi + (long)slot2 * 65536 + (k0 - 256);
            bl = bt_lo + (long)slot2 * 65536 + (k0 - 256);
        } else { bh = bhb + k0; bl = blb + k0; }
        float av[8];
        *(float4*)&av[0] = *(const float4*)&arow[k0 + lg * 8];
        *(float4*)&av[4] = *(const float4*)&arow[k0 + lg * 8 + 4];
        short8 ahi, alo;
        #pragma unroll
        for (int j = 0; j < 8; ++j) {
            const u32 bi = __float_as_uint(av[j]);
            ahi[j] = (short)(bi >> 16);
            const float fh = __uint_as_float(bi & 0xffff0000u);
            alo[j] = (short)f2bf(av[j] - fh);
        }
        #pragma unroll
        for (int f = 0; f < 4; ++f) {
            const long bo = (long)(col0 + f * 16 + lr) * 256 + lg * 8;
            const short8 bhi = *(const short8*)&bh[bo];
            const short8 blo = *(const short8*)&bl[bo];
            acc[f] = __builtin_amdgcn_mfma_f32_16x16x32_bf16(ahi, bhi, acc[f], 0, 0, 0);
            acc[f] = __builtin_amdgcn_mfma_f32_16x16x32_bf16(alo, bhi, acc[f], 0, 0, 0);
            acc[f] = __builtin_amdgcn_mfma_f32_16x16x32_bf16(ahi, blo, acc[f], 0, 0, 0);
        }
    }

    // Q pre-scale: 1/sqrt(32) * log2(e) (exp2-domain softmax)
    const float QS = 0.17677669529663687f * 1.4426950408889634f;

    #pragma unroll
    for (int f = 0; f < 4; ++f) {
        const int col = col0 + f * 16 + lr;
        const float bv = bias ? bias[col] : 0.f;
        #pragma unroll
        for (int r = 0; r < 4; ++r) {
            const int rr = blockIdx.x * 32 + wv * 16 + lg * 4 + r;
            float v = acc[f][r] + bv;
            if (OUTMODE == 1) {
                if (zq == 0) v *= QS;
                ushort* ob = (ushort*)C + (long)buf * 1572864;
                const int h = col >> 5, d = col & 31;
                if (QKVMODE == 1 || zq < 2)
                    ob[zq * 524288 + ((h * 2048 + rr) << 5) + d] = f2bf(v);
                else
                    ob[1048576 + ((h * 32 + d) << 11) + rr] = f2bf(v);
            } else {
                if (BETA) v += C[(long)rr * N + col];
                if (RELU) v = fmaxf(v, 0.f);
                C[(long)rr * N + col] = v;
            }
        }
    }
}

// ---------------------------------------------------------------------------
// LayerNorm over rows of 256 (+optional relu) (+optional duplicate store).
// One wave per row, 2048 blocks (full occupancy — the R8 fusion lesson).
// ---------------------------------------------------------------------------
template <int RELU, int DUP>
__global__ __launch_bounds__(64) void ln_kernel(
    const float* __restrict__ X, const float* __restrict__ gw,
    const float* __restrict__ bw, float* __restrict__ Y, float* __restrict__ Y2)
{
    const int row = blockIdx.x, tid = threadIdx.x;
    const float4 x = *(const float4*)&X[(long)row * 256 + (tid << 2)];
    float s = x.x + x.y + x.z + x.w;
    float s2 = x.x * x.x + x.y * x.y + x.z * x.z + x.w * x.w;
    #pragma unroll
    for (int o = 1; o < 64; o <<= 1) { s += __shfl_xor(s, o); s2 += __shfl_xor(s2, o); }
    const float mean = s * (1.f / 256.f);
    const float var = s2 * (1.f / 256.f) - mean * mean;
    const float rs = rsqrtf(var + 1e-5f);
    const float4 g4 = *(const float4*)&gw[tid << 2];
    const float4 b4 = *(const float4*)&bw[tid << 2];
    float4 y;
    y.x = (x.x - mean) * rs * g4.x + b4.x;
    y.y = (x.y - mean) * rs * g4.y + b4.y;
    y.z = (x.z - mean) * rs * g4.z + b4.z;
    y.w = (x.w - mean) * rs * g4.w + b4.w;
    if (RELU) {
        y.x = fmaxf(y.x, 0.f); y.y = fmaxf(y.y, 0.f);
        y.z = fmaxf(y.z, 0.f); y.w = fmaxf(y.w, 0.f);
    }
    *(float4*)&Y[(long)row * 256 + (tid << 2)] = y;
    if (DUP) *(float4*)&Y2[(long)row * 256 + (tid << 2)] = y;
}

// ---------------------------------------------------------------------------
// Sparse masked attention (M block), exp2 domain. One wave per (row, graph):
// lane = head(3b) x dim-group(3b). Online softmax over the row's allowed keys
// only — consistent with dense where(mask,s,-1e9) since exp underflows to 0.
// deg==0 -> uniform = mean(V) (inline; probability ~1e-9 on fixed data).
// ---------------------------------------------------------------------------
__global__ __launch_bounds__(64) void attn_sparse_kernel(
    const ushort* __restrict__ qkvb, const int* __restrict__ deg,
    const int* __restrict__ colidx, float* __restrict__ ctx)
{
    const int r = blockIdx.x, z = blockIdx.y;
    const ushort* qb = qkvb + (long)z * 1572864;
    const ushort* kb = qb + 524288;
    const ushort* vr = qb + 1048576;
    const int l = threadIdx.x;
    const int h = l >> 3, dg = l & 7;
    float* orow = &ctx[(long)r * 512 + z * 256 + h * 32 + dg * 4];
    const int n = deg[z * 2048 + r];
    if (n == 0) {
        float a0 = 0.f, a1 = 0.f, a2 = 0.f, a3 = 0.f;
        for (int k = 0; k < 2048; ++k) {
            const us4 vv = *(const us4*)&vr[((h * 2048 + k) << 5) + dg * 4];
            a0 += bf2f(vv[0]); a1 += bf2f(vv[1]); a2 += bf2f(vv[2]); a3 += bf2f(vv[3]);
        }
        float4 o; const float inv = 1.f / 2048.f;
        o.x = a0 * inv; o.y = a1 * inv; o.z = a2 * inv; o.w = a3 * inv;
        *(float4*)orow = o;
        return;
    }
    float q0, q1, q2, q3;
    {
        const us4 qv = *(const us4*)&qb[((h * 2048 + r) << 5) + dg * 4];
        q0 = bf2f(qv[0]); q1 = bf2f(qv[1]); q2 = bf2f(qv[2]); q3 = bf2f(qv[3]);
    }
    const int* ci = colidx + ((long)z * 2048 + r) * CSTRIDE;
    float m = -INFINITY, lsum = 0.f;
    float a0 = 0.f, a1 = 0.f, a2 = 0.f, a3 = 0.f;
    int kn = ci[0];
    us4 kv = *(const us4*)&kb[((h * 2048 + kn) << 5) + dg * 4];
    us4 vv = *(const us4*)&vr[((h * 2048 + kn) << 5) + dg * 4];
    for (int e = 0; e < n; ++e) {
        const us4 kc = kv, vc = vv;
        if (e + 1 < n) {
            kn = ci[e + 1];
            kv = *(const us4*)&kb[((h * 2048 + kn) << 5) + dg * 4];
            vv = *(const us4*)&vr[((h * 2048 + kn) << 5) + dg * 4];
        }
        float s = q0 * bf2f(kc[0]) + q1 * bf2f(kc[1]) +
                  q2 * bf2f(kc[2]) + q3 * bf2f(kc[3]);
        s += __shfl_xor(s, 1); s += __shfl_xor(s, 2); s += __shfl_xor(s, 4);
        const float mn = fmaxf(m, s);
        const float fac = __builtin_amdgcn_exp2f(m - mn);
        const float p = __builtin_amdgcn_exp2f(s - mn);
        lsum = lsum * fac + p;
        a0 = a0 * fac + p * bf2f(vc[0]);
        a1 = a1 * fac + p * bf2f(vc[1]);
        a2 = a2 * fac + p * bf2f(vc[2]);
        a3 = a3 * fac + p * bf2f(vc[3]);
        m = mn;
    }
    const float inv = 1.f / lsum;
    float4 o; o.x = a0 * inv; o.y = a1 * inv; o.z = a2 * inv; o.w = a3 * inv;
    *(float4*)orow = o;
}

// ---------------------------------------------------------------------------
// Dense attention (S block): 32x32x16 swapped MFMA, in-register P via
// cvt_pk_bf16 + permlane32_swap, exp2 domain, k-split x8 (512 threads),
// LDS merge + padded-LDS transposed coalesced store.
// ---------------------------------------------------------------------------
__global__ __launch_bounds__(512) void attn_dense_kernel(
    const ushort* __restrict__ qkvb, float* __restrict__ ctx)
{
    const ushort* qb = qkvb;
    const ushort* kb = qb + 524288;
    const ushort* vt = qb + 1048576;
    const int h = blockIdx.x, qt = blockIdx.y;
    const int wv = threadIdx.x >> 6;
    const int l = threadIdx.x & 63;
    const int lq = l & 31;
    const int hi = l >> 5;
    const int qglob = qt * 32 + lq;

    __shared__ float Mm[7][32], Ml[7][32];
    __shared__ float Macc[7][64][16];
    __shared__ float ctile[32][33];

    const int qoff = ((h * 2048 + qglob) << 5) + hi * 8;
    const short8 qf0 = *(const short8*)&qb[qoff];
    const short8 qf1 = *(const short8*)&qb[qoff + 16];

    float m = -INFINITY, lsum = 0.f;
    f32x16 acc, zz16;
    #pragma unroll
    for (int i = 0; i < 16; ++i) { acc[i] = 0.f; zz16[i] = 0.f; }

    const int kt0 = wv * 256;
    #pragma unroll 2
    for (int it = 0; it < 8; ++it) {
        const int kbase = kt0 + it * 32;
        const int koff = ((h * 2048 + kbase + lq) << 5) + hi * 8;
        const short8 kf0 = *(const short8*)&kb[koff];
        const short8 kf1 = *(const short8*)&kb[koff + 16];
        f32x16 s = __builtin_amdgcn_mfma_f32_32x32x16_bf16(kf0, qf0, zz16, 0, 0, 0);
        s = __builtin_amdgcn_mfma_f32_32x32x16_bf16(kf1, qf1, s, 0, 0, 0);
        float sc[16];
        #pragma unroll
        for (int i = 0; i < 16; ++i) sc[i] = s[i];
        float t[8];
        #pragma unroll
        for (int i = 0; i < 8; ++i) t[i] = fmaxf(sc[i], sc[i + 8]);
        #pragma unroll
        for (int i = 0; i < 4; ++i) t[i] = fmaxf(t[i], t[i + 4]);
        float mt = fmaxf(fmaxf(t[0], t[1]), fmaxf(t[2], t[3]));
        mt = fmaxf(mt, __shfl_xor(mt, 32));
        const float mn = fmaxf(m, mt);
        if (__ballot(mn != m)) {
            const float fac = __builtin_amdgcn_exp2f(m - mn);
            lsum *= fac;
            #pragma unroll
            for (int i = 0; i < 16; ++i) acc[i] *= fac;
            m = mn;
        }
        #pragma unroll
        for (int i = 0; i < 16; ++i) sc[i] = __builtin_amdgcn_exp2f(sc[i] - m);
        #pragma unroll
        for (int i = 0; i < 8; ++i) t[i] = sc[i] + sc[i + 8];
        #pragma unroll
        for (int i = 0; i < 4; ++i) t[i] = t[i] + t[i + 4];
        float ps = (t[0] + t[1]) + (t[2] + t[3]);
        ps += __shfl_xor(ps, 32);
        lsum += ps;
        u32 pk[8];
        #pragma unroll
        for (int g = 0; g < 4; ++g) {
            asm("v_cvt_pk_bf16_f32 %0, %1, %2"
                : "=v"(pk[2 * g]) : "v"(sc[4 * g + 0]), "v"(sc[4 * g + 1]));
            asm("v_cvt_pk_bf16_f32 %0, %1, %2"
                : "=v"(pk[2 * g + 1]) : "v"(sc[4 * g + 2]), "v"(sc[4 * g + 3]));
        }
        asm volatile("v_permlane32_swap_b32 %0, %1" : "+v"(pk[0]), "+v"(pk[2]));
        asm volatile("v_permlane32_swap_b32 %0, %1" : "+v"(pk[1]), "+v"(pk[3]));
        asm volatile("v_permlane32_swap_b32 %0, %1" : "+v"(pk[4]), "+v"(pk[6]));
        asm volatile("v_permlane32_swap_b32 %0, %1" : "+v"(pk[5]), "+v"(pk[7]));
        short8 pB0, pB1;
        ((u32*)&pB0)[0] = pk[0]; ((u32*)&pB0)[1] = pk[1];
        ((u32*)&pB0)[2] = pk[2]; ((u32*)&pB0)[3] = pk[3];
        ((u32*)&pB1)[0] = pk[4]; ((u32*)&pB1)[1] = pk[5];
        ((u32*)&pB1)[2] = pk[6]; ((u32*)&pB1)[3] = pk[7];
        const int voff = ((h * 32 + lq) << 11) + kbase + hi * 8;
        const short8 vf0 = *(const short8*)&vt[voff];
        const short8 vf1 = *(const short8*)&vt[voff + 16];
        acc = __builtin_amdgcn_mfma_f32_32x32x16_bf16(vf0, pB0, acc, 0, 0, 0);
        acc = __builtin_amdgcn_mfma_f32_32x32x16_bf16(vf1, pB1, acc, 0, 0, 0);
    }

    if (wv) {
        if (l < 32) { Mm[wv - 1][l] = m; Ml[wv - 1][l] = lsum; }
        #pragma unroll
        for (int i = 0; i < 16; ++i) Macc[wv - 1][l][i] = acc[i];
    }
    __syncthreads();
    if (wv == 0) {
        float M = m;
        #pragma unroll
        for (int w = 0; w < 7; ++w) M = fmaxf(M, Mm[w][lq]);
        const float f0 = __builtin_amdgcn_exp2f(m - M);
        float den = lsum * f0;
        float o[16];
        #pragma unroll
        for (int i = 0; i < 16; ++i) o[i] = acc[i] * f0;
        #pragma unroll
        for (int w = 0; w < 7; ++w) {
            const float fw = __builtin_amdgcn_exp2f(Mm[w][lq] - M);
            den += Ml[w][lq] * fw;
            #pragma unroll
            for (int i = 0; i < 16; ++i) o[i] += Macc[w][l][i] * fw;
        }
        const float inv = 1.f / den;
        #pragma unroll
        for (int i = 0; i < 16; ++i)
            ctile[(i & 3) + 8 * (i >> 2) + 4 * hi][lq] = o[i] * inv;
    }
    __syncthreads();
    if (threadIdx.x < 256) {
        const int t = threadIdx.x;
        const int q = t >> 3, d0 = (t & 7) << 2;
        float4 ov;
        ov.x = ctile[d0 + 0][q]; ov.y = ctile[d0 + 1][q];
        ov.z = ctile[d0 + 2][q]; ov.w = ctile[d0 + 3][q];
        *(float4*)&ctx[(long)(qt * 32 + q) * 512 + h * 32 + d0] = ov;
    }
}

// ---------------------------------------------------------------------------
// Aggregation GEMM: y<8 -> t = relu(xg@tr_w + tr_b) tile (32 cols);
// y==8 -> gate: relu(xg@gate_w1+gate_b1)@gate_w2+gate_b2 fully in-register
// (8 frags = 128 cols, shfl dot), writes gv + deterministic encoded atomicMax.
// ---------------------------------------------------------------------------
__global__ __launch_bounds__(64) void aggr_gemm_kernel(
    const float* __restrict__ xg,
    const ushort* __restrict__ bt_hi, const ushort* __restrict__ bt_lo,
    const float* __restrict__ tr_b, const float* __restrict__ g_b1,
    const float* __restrict__ g_w2, const float* __restrict__ g_b2,
    float* __restrict__ t_out, float* __restrict__ gv, u32* __restrict__ gmax)
{
    const int l = threadIdx.x;
    const int lr = l & 15, lg = l >> 4;
    const int row0 = blockIdx.x * 16;
    const int gate = (blockIdx.y == 8);
    const int slot = gate ? 14 : 15;
    const int col0 = gate ? 0 : blockIdx.y * 32;
    const int NF = gate ? 8 : 2;
    const ushort* bh0 = bt_hi + (long)slot * 65536;
    const ushort* bl0 = bt_lo + (long)slot * 65536;
    const float* arow = xg + (long)(row0 + lr) * 256;

    const f32x4 z4 = {0.f, 0.f, 0.f, 0.f};
    f32x4 acc[8] = {z4, z4, z4, z4, z4, z4, z4, z4};

    #pragma unroll
    for (int ks = 0; ks < 8; ++ks) {
        const int k0 = ks * 32;
        float av[8];
        *(float4*)&av[0] = *(const float4*)&arow[k0 + lg * 8];
        *(float4*)&av[4] = *(const float4*)&arow[k0 + lg * 8 + 4];
        short8 ahi, alo;
        #pragma unroll
        for (int j = 0; j < 8; ++j) {
            const u32 bi = __float_as_uint(av[j]);
            ahi[j] = (short)(bi >> 16);
            const float fh = __uint_as_float(bi & 0xffff0000u);
            alo[j] = (short)f2bf(av[j] - fh);
        }
        for (int f = 0; f < NF; ++f) {
            const long bo = (long)(col0 + f * 16 + lr) * 256 + k0 + lg * 8;
            const short8 bhi = *(const short8*)&bh0[bo];
            const short8 blo = *(const short8*)&bl0[bo];
            acc[f] = __builtin_amdgcn_mfma_f32_16x16x32_bf16(ahi, bhi, acc[f], 0, 0, 0);
            acc[f] = __builtin_amdgcn_mfma_f32_16x16x32_bf16(alo, bhi, acc[f], 0, 0, 0);
            acc[f] = __builtin_amdgcn_mfma_f32_16x16x32_bf16(ahi, blo, acc[f], 0, 0, 0);
        }
    }

    if (!gate) {
        #pragma unroll
        for (int f = 0; f < 2; ++f) {
            const int col = col0 + f * 16 + lr;
            const float bv = tr_b[col];
            #pragma unroll
            for (int r = 0; r < 4; ++r) {
                const int rr = row0 + lg * 4 + r;
                t_out[(long)rr * 256 + col] = fmaxf(acc[f][r] + bv, 0.f);
            }
        }
    } else {
        float b1v[8], w2v[8];
        #pragma unroll
        for (int f = 0; f < 8; ++f) {
            b1v[f] = g_b1[f * 16 + lr];
            w2v[f] = g_w2[f * 16 + lr];
        }
        const float b2 = g_b2[0];
        #pragma unroll
        for (int r = 0; r < 4; ++r) {
            float t = 0.f;
            #pragma unroll
            for (int f = 0; f < 8; ++f)
                t += fmaxf(acc[f][r] + b1v[f], 0.f) * w2v[f];
            #pragma unroll
            for (int o = 1; o < 16; o <<= 1) t += __shfl_xor(t, o);
            if (lr == 0) {
                const float g = t + b2;
                gv[row0 + lg * 4 + r] = g;
                atomicMax(gmax, encf(g));
            }
        }
    }
}

// partial[b][col] = sum over 32 rows of exp2((g-M)*log2e) * t[r][col];
// denp[b] = block's exp-sum. grid 64 x 256 thr.
__global__ __launch_bounds__(256) void wsum_part_kernel(
    const float* __restrict__ gv, const u32* __restrict__ gmax,
    const float* __restrict__ t, float* __restrict__ partial,
    float* __restrict__ denp)
{
    const float L2E = 1.4426950408889634f;
    const int b = blockIdx.x, tid = threadIdx.x;
    const float M = decf(*gmax);
    float s = 0.f, den = 0.f;
    #pragma unroll 4
    for (int i = 0; i < 32; ++i) {
        const int r = b * 32 + i;
        const float w = __builtin_amdgcn_exp2f((gv[r] - M) * L2E);
        den += w;
        s += w * t[(long)r * 256 + tid];
    }
    partial[b * 256 + tid] = s;
    if (tid == 0) denp[b] = den;
}

// out = (sum_b partial / sum_b den) @ head_w + head_b
__global__ __launch_bounds__(256) void head2_kernel(
    const float* __restrict__ partial, const float* __restrict__ denp,
    const float* __restrict__ hw, const float* __restrict__ hb,
    float* __restrict__ out)
{
    __shared__ float red0[4], red1[4];
    const int tid = threadIdx.x;
    float p = 0.f;
    #pragma unroll 8
    for (int b = 0; b < 64; ++b) p += partial[b * 256 + tid];
    float den = 0.f;
    #pragma unroll
    for (int b = 0; b < 64; ++b) den += denp[b];
    p /= den;
    float s0 = p * hw[tid * 2 + 0];
    float s1 = p * hw[tid * 2 + 1];
    #pragma unroll
    for (int o = 1; o < 64; o <<= 1) { s0 += __shfl_xor(s0, o); s1 += __shfl_xor(s1, o); }
    if ((tid & 63) == 0) { red0[tid >> 6] = s0; red1[tid >> 6] = s1; }
    __syncthreads();
    if (tid == 0) {
        out[0] = red0[0] + red0[1] + red0[2] + red0[3] + hb[0];
        out[1] = red1[0] + red1[1] + red1[2] + red1[3] + hb[1];
    }
}

// ---------------------------------------------------------------------------
extern "C" void kernel_launch(void* const* d_in, const int* in_sizes, int n_in,
                              void* d_out, int out_size, void* d_ws, size_t ws_size,
                              hipStream_t stream)
{
    (void)in_sizes; (void)n_in; (void)out_size; (void)ws_size;
    const float* gene_emb = (const float*)d_in[0];
    const float* pre_w1   = (const float*)d_in[3];
    const float* pre_b1   = (const float*)d_in[4];
    const float* pre_w2   = (const float*)d_in[5];
    const float* pre_b2   = (const float*)d_in[6];
    const float* pre_ln_g = (const float*)d_in[7];
    const float* pre_ln_b = (const float*)d_in[8];
    const float* wm       = (const float*)d_in[9];
    const float* wsw      = (const float*)d_in[10];
    const float* ln_g     = (const float*)d_in[11];
    const float* ln_b     = (const float*)d_in[12];
    const float* gate_w1  = (const float*)d_in[13];
    const float* gate_b1  = (const float*)d_in[14];
    const float* gate_w2  = (const float*)d_in[15];
    const float* gate_b2  = (const float*)d_in[16];
    const float* tr_w     = (const float*)d_in[17];
    const float* tr_b     = (const float*)d_in[18];
    const float* head_w   = (const float*)d_in[19];
    const float* head_b   = (const float*)d_in[20];
    const u8* adj_pp      = (const u8*)d_in[21];
    const u8* adj_rr      = (const u8*)d_in[22];
    // d_in[1],[2],[23],[24] dead (reaction/metab branches never reach output)

    const long NHf = (long)Gn * Hd;
    float* tmp0    = (float*)d_ws;                     // [2048][256] (t matrix)
    float* xg      = tmp0 + NHf;
    float* xg1     = xg + NHf;
    float* ctx2    = xg1 + NHf;                        // [2048][512]
    float* gv      = ctx2 + 2 * NHf;                   // [2048]
    float* partial = gv + Gn;                          // [64][256]
    float* denp    = partial + 64 * 256;               // [64]
    int* cnt       = (int*)(denp + 64);                // cnt[0],cnt[1],gmax
    int* deg       = cnt + 64;                         // [2][2048]
    int* colidx    = deg + 4096;                       // [2][2048][192]
    u32* bits      = (u32*)(colidx + 2L * 2048 * CSTRIDE);
    ushort* qkvb   = (ushort*)(bits + 262144);         // 2 x 1572864 bf16
    ushort* bt_hi  = qkvb + 2L * 1572864;              // 16 slots x 65536
    ushort* bt_lo  = bt_hi + 16L * 65536;

    dim3 B256(256), T64(64), B128(128);
    dim3 gS(64, 4);

    // prep: masks -> bits -> CSR; weights -> split arenas
    hipMemsetAsync((void*)cnt, 0, 16, stream);
    detect2_kernel<<<dim3(64), B256, 0, stream>>>(adj_pp, cnt);
    pack_mask_kernel<<<dim3(512, 2), B256, 0, stream>>>(adj_pp, adj_rr, cnt, bits);
    csr_direct_kernel<<<dim3(8, 2), B256, 0, stream>>>(bits, deg, colidx);
    preconv_kernel<<<dim3(16, 8), B256, 0, stream>>>(pre_w1, pre_w2, wm, wsw,
                                                     gate_w1, tr_w, bt_hi, bt_lo);

    // preprocessor: xg = relu(LN(relu(LN(ge@w1+b1))@w2+b2)); xg1 = xg
    gemm_mfma_kernel<0, 0, 0, 0, 256><<<gS, B128, 0, stream>>>(gene_emb, 256, bt_hi, bt_lo, 0, 0, pre_b1, tmp0, 256);
    ln_kernel<1, 0><<<dim3(2048), T64, 0, stream>>>(tmp0, pre_ln_g, pre_ln_b, xg, nullptr);
    gemm_mfma_kernel<0, 0, 0, 0, 256><<<gS, B128, 0, stream>>>(xg, 256, bt_hi, bt_lo, 1, 0, pre_b2, tmp0, 256);
    ln_kernel<1, 1><<<dim3(2048), T64, 0, stream>>>(tmp0, pre_ln_g, pre_ln_b, xg, xg1);

    // M block: QKV (z=6, V rows) -> sparse attn -> fused dual-Wo (K=512)
    gemm_mfma_kernel<0, 0, 1, 1, 256><<<dim3(64, 4, 6), B128, 0, stream>>>(xg, 256, bt_hi, bt_lo, 2, 0, nullptr, (float*)qkvb, 256);
    attn_sparse_kernel<<<dim3(2048, 2), T64, 0, stream>>>(qkvb, deg, colidx, ctx2);
    gemm_mfma_kernel<1, 0, 0, 0, 512><<<gS, B128, 0, stream>>>(ctx2, 512, bt_hi, bt_lo, 5, 9, nullptr, xg1, 256);

    // S block: QKV (z=3, V transposed) -> dense attn -> Wo+residual, then LN
    gemm_mfma_kernel<0, 0, 1, 2, 256><<<dim3(64, 4, 3), B128, 0, stream>>>(xg1, 256, bt_hi, bt_lo, 10, 0, nullptr, (float*)qkvb, 256);
    attn_dense_kernel<<<dim3(8, 64), dim3(512), 0, stream>>>(qkvb, ctx2);
    gemm_mfma_kernel<1, 0, 0, 0, 256><<<gS, B128, 0, stream>>>(ctx2, 512, bt_hi, bt_lo, 13, 0, nullptr, xg1, 256);
    ln_kernel<0, 0><<<dim3(2048), T64, 0, stream>>>(xg1, ln_g, ln_b, xg, nullptr);

    // aggregation: tr tiles + in-register gate (y=8) -> weighted sum -> head
    aggr_gemm_kernel<<<dim3(128, 9), T64, 0, stream>>>(xg, bt_hi, bt_lo, tr_b, gate_b1, gate_w2, gate_b2, tmp0, gv, (u32*)&cnt[2]);
    wsum_part_kernel<<<dim3(64), B256, 0, stream>>>(gv, (const u32*)&cnt[2], tmp0, partial, denp);
    head2_kernel<<<dim3(1), B256, 0, stream>>>(partial, denp, head_w, head_b, (float*)d_out);
}

// Round 10
// 204.246 us; speedup vs baseline: 1.6863x; 1.1112x over previous
//
#include <hip/hip_runtime.h>
#include <hip/hip_bf16.h>
#include <cmath>
#include <cstdint>

typedef unsigned int u32;
typedef unsigned char u8;
typedef unsigned short ushort;
typedef __attribute__((ext_vector_type(8))) short short8;
typedef __attribute__((ext_vector_type(4))) float f32x4;
typedef __attribute__((ext_vector_type(16))) float f32x16;
typedef __attribute__((ext_vector_type(4))) unsigned short us4;

#define Gn 2048
#define Hd 256
#define CSTRIDE 192

static __device__ __forceinline__ ushort f2bf(float x) {
    __hip_bfloat16 b = __float2bfloat16(x);
    return *reinterpret_cast<ushort*>(&b);
}
static __device__ __forceinline__ float bf2f(ushort u) {
    return __uint_as_float(((u32)u) << 16);
}

// ===========================================================================
// GEMM body (device fn): bf16x3 split-precision MFMA, 32x64 tile, 2 waves.
// LNF: apply LayerNorm(+LNRELU relu) to A rows on the fly (stats via 2-pass
//   read + shfl_xor(16/32) over the 4 lanes sharing a row). Exact fp32 LN.
// WRA: (by==0 && bz==0) blocks write normalized A rows to Aout (residual).
// OUTMODE 1 = QKV bf16 epilogue (Q pre-scaled 1/sqrt(32)*log2e).
// QKVMODE 1 (M): V row-layout; QKVMODE 2 (S): V transposed.
// KT=512: k>=256 reads slot2 arena (fused dual-Wo accumulate).
// ===========================================================================
template <int BETA, int OUTMODE, int QKVMODE, int KT, int LNF, int LNRELU, int WRA>
static __device__ __forceinline__ void gemm_body(
    const int bx, const int by, const int bz,
    const float* __restrict__ A, int lda,
    const ushort* __restrict__ bt_hi, const ushort* __restrict__ bt_lo,
    int slot0, int slot2, const float* __restrict__ bias,
    const float* __restrict__ lng, const float* __restrict__ lnb,
    float* __restrict__ C, int N, float* __restrict__ Aout)
{
    const int tid = threadIdx.x;
    const int wv = tid >> 6, l = tid & 63;
    const int lr = l & 15, lg = l >> 4;
    const int row = bx * 32 + wv * 16 + lr;
    const int col0 = by * 64;
    int slot = slot0, zq = 0, buf = 0;
    if (QKVMODE == 1) { slot = slot0 + bz + bz / 3; zq = bz % 3; buf = bz / 3; }
    else if (QKVMODE == 2) { slot = slot0 + bz; zq = bz; }
    const ushort* bhb = bt_hi + (long)slot * 65536;
    const ushort* blb = bt_lo + (long)slot * 65536;
    const float* arow = A + (long)row * lda;

    float mean = 0.f, rs = 0.f;
    if (LNF) {
        float s = 0.f, s2 = 0.f;
        #pragma unroll
        for (int ks = 0; ks < 8; ++ks) {
            const float4 a0 = *(const float4*)&arow[ks * 32 + lg * 8];
            const float4 a1 = *(const float4*)&arow[ks * 32 + lg * 8 + 4];
            s  += (a0.x + a0.y) + (a0.z + a0.w) + (a1.x + a1.y) + (a1.z + a1.w);
            s2 += a0.x * a0.x + a0.y * a0.y + a0.z * a0.z + a0.w * a0.w +
                  a1.x * a1.x + a1.y * a1.y + a1.z * a1.z + a1.w * a1.w;
        }
        s += __shfl_xor(s, 16);  s += __shfl_xor(s, 32);
        s2 += __shfl_xor(s2, 16); s2 += __shfl_xor(s2, 32);
        mean = s * (1.f / 256.f);
        rs = rsqrtf(s2 * (1.f / 256.f) - mean * mean + 1e-5f);
    }

    const f32x4 z4 = {0.f, 0.f, 0.f, 0.f};
    f32x4 acc[4] = {z4, z4, z4, z4};

    #pragma unroll
    for (int ks = 0; ks < KT / 32; ++ks) {
        const int k0 = ks * 32;
        const ushort* bh; const ushort* bl;
        if (KT == 512 && k0 >= 256) {
            bh = bt_hi + (long)slot2 * 65536 + (k0 - 256);
            bl = bt_lo + (long)slot2 * 65536 + (k0 - 256);
        } else { bh = bhb + k0; bl = blb + k0; }
        float av[8];
        *(float4*)&av[0] = *(const float4*)&arow[k0 + lg * 8];
        *(float4*)&av[4] = *(const float4*)&arow[k0 + lg * 8 + 4];
        if (LNF) {
            float gvv[8], bvv[8];
            *(float4*)&gvv[0] = *(const float4*)&lng[k0 + lg * 8];
            *(float4*)&gvv[4] = *(const float4*)&lng[k0 + lg * 8 + 4];
            *(float4*)&bvv[0] = *(const float4*)&lnb[k0 + lg * 8];
            *(float4*)&bvv[4] = *(const float4*)&lnb[k0 + lg * 8 + 4];
            #pragma unroll
            for (int j = 0; j < 8; ++j) {
                float v = (av[j] - mean) * rs * gvv[j] + bvv[j];
                if (LNRELU) v = fmaxf(v, 0.f);
                av[j] = v;
            }
            if (WRA && by == 0 && bz == 0) {
                *(float4*)&Aout[(long)row * 256 + k0 + lg * 8] = *(float4*)&av[0];
                *(float4*)&Aout[(long)row * 256 + k0 + lg * 8 + 4] = *(float4*)&av[4];
            }
        }
        short8 ahi, alo;
        #pragma unroll
        for (int j = 0; j < 8; ++j) {
            const u32 bi = __float_as_uint(av[j]);
            ahi[j] = (short)(bi >> 16);
            const float fh = __uint_as_float(bi & 0xffff0000u);
            alo[j] = (short)f2bf(av[j] - fh);
        }
        #pragma unroll
        for (int f = 0; f < 4; ++f) {
            const long bo = (long)(col0 + f * 16 + lr) * 256 + lg * 8;
            const short8 bhi = *(const short8*)&bh[bo];
            const short8 blo = *(const short8*)&bl[bo];
            acc[f] = __builtin_amdgcn_mfma_f32_16x16x32_bf16(ahi, bhi, acc[f], 0, 0, 0);
            acc[f] = __builtin_amdgcn_mfma_f32_16x16x32_bf16(alo, bhi, acc[f], 0, 0, 0);
            acc[f] = __builtin_amdgcn_mfma_f32_16x16x32_bf16(ahi, blo, acc[f], 0, 0, 0);
        }
    }

    const float QS = 0.17677669529663687f * 1.4426950408889634f;

    #pragma unroll
    for (int f = 0; f < 4; ++f) {
        const int col = col0 + f * 16 + lr;
        const float bv = bias ? bias[col] : 0.f;
        #pragma unroll
        for (int r = 0; r < 4; ++r) {
            const int rr = bx * 32 + wv * 16 + lg * 4 + r;
            float v = acc[f][r] + bv;
            if (OUTMODE == 1) {
                if (zq == 0) v *= QS;
                ushort* ob = (ushort*)C + (long)buf * 1572864;
                const int h = col >> 5, d = col & 31;
                if (QKVMODE == 1 || zq < 2)
                    ob[zq * 524288 + ((h * 2048 + rr) << 5) + d] = f2bf(v);
                else
                    ob[1048576 + ((h * 32 + d) << 11) + rr] = f2bf(v);
            } else {
                if (BETA) v += C[(long)rr * N + col];
                C[(long)rr * N + col] = v;
            }
        }
    }
}

// ===========================================================================
// Merged A (256 thr, grid 192): blocks 0-63 mask-dtype detect (per-block
// slots, no atomics/no init); blocks 64-191 weight pre-split (preconv).
// ===========================================================================
__global__ __launch_bounds__(256) void mergedA_kernel(
    const u8* __restrict__ adj, int* __restrict__ det0, int* __restrict__ det1,
    const float* __restrict__ pre_w1, const float* __restrict__ pre_w2,
    const float* __restrict__ wm, const float* __restrict__ wsw,
    const float* __restrict__ gate_w1, const float* __restrict__ tr_w,
    ushort* __restrict__ bt_hi, ushort* __restrict__ bt_lo)
{
    __shared__ float T[32][257];
    __shared__ int sd0[4], sd1[4];
    const int tid = threadIdx.x;
    if (blockIdx.x < 64) {
        const int idx = blockIdx.x * 256 + tid;
        const uint4 w = ((const uint4*)adj)[idx];
        int c0 = ((w.x & 0xffu) ? 1 : 0) + ((w.y & 0xffu) ? 1 : 0) +
                 ((w.z & 0xffu) ? 1 : 0) + ((w.w & 0xffu) ? 1 : 0);
        int c1 = ((w.x & 0xffffff00u) ? 1 : 0) + ((w.y & 0xffffff00u) ? 1 : 0) +
                 ((w.z & 0xffffff00u) ? 1 : 0) + ((w.w & 0xffffff00u) ? 1 : 0);
        #pragma unroll
        for (int o = 1; o < 64; o <<= 1) { c0 += __shfl_xor(c0, o); c1 += __shfl_xor(c1, o); }
        if ((tid & 63) == 0) { sd0[tid >> 6] = c0; sd1[tid >> 6] = c1; }
        __syncthreads();
        if (tid == 0) {
            det0[blockIdx.x] = sd0[0] + sd0[1] + sd0[2] + sd0[3];
            det1[blockIdx.x] = sd1[0] + sd1[1] + sd1[2] + sd1[3];
        }
        return;
    }
    const int b2 = blockIdx.x - 64;
    const int slot = b2 >> 3;
    const int k0 = (b2 & 7) * 32;
    const float* src; int ncols = 256;
    if (slot == 0) src = pre_w1;
    else if (slot == 1) src = pre_w2;
    else if (slot < 6) src = wm + (long)(slot - 2) * 65536;
    else if (slot < 10) src = wm + (long)(4 + slot - 6) * 65536;
    else if (slot < 14) src = wsw + (long)(slot - 10) * 65536;
    else if (slot == 14) { src = gate_w1; ncols = 128; }
    else src = tr_w;

    const int lsh = (ncols == 256) ? 6 : 5;
    const int tot = 32 << lsh;
    for (int i = tid; i < tot; i += 256) {
        const int kk = i >> lsh, c4 = (i & ((1 << lsh) - 1)) << 2;
        const float4 v = *(const float4*)&src[(long)(k0 + kk) * ncols + c4];
        T[kk][c4 + 0] = v.x; T[kk][c4 + 1] = v.y;
        T[kk][c4 + 2] = v.z; T[kk][c4 + 3] = v.w;
    }
    __syncthreads();
    if (tid < ncols) {
        ushort hb[32], lb[32];
        #pragma unroll
        for (int kk = 0; kk < 32; ++kk) {
            const float x = T[kk][tid];
            const u32 bi = __float_as_uint(x);
            const ushort h = (ushort)(bi >> 16);
            const float fh = __uint_as_float(bi & 0xffff0000u);
            hb[kk] = h; lb[kk] = f2bf(x - fh);
        }
        ushort* oh = bt_hi + (long)slot * 65536 + tid * 256 + k0;
        ushort* ol = bt_lo + (long)slot * 65536 + tid * 256 + k0;
        #pragma unroll
        for (int q = 0; q < 4; ++q) {
            *(uint4*)&oh[q * 8] = *(const uint4*)&hb[q * 8];
            *(uint4*)&ol[q * 8] = *(const uint4*)&lb[q * 8];
        }
    }
}

// ===========================================================================
// Merged B (128 thr, grid 2304): blocks 0-2047 pack masks into bitwords;
// blocks 2048-2303 preGEMM1 (tmp0 = gene_emb @ pre_w1 + b1).
// ===========================================================================
__global__ __launch_bounds__(128) void mergedB_kernel(
    const u8* __restrict__ src0, const u8* __restrict__ src1,
    const int* __restrict__ det0, const int* __restrict__ det1,
    u32* __restrict__ bits,
    const float* __restrict__ gene_emb,
    const ushort* __restrict__ bt_hi, const ushort* __restrict__ bt_lo,
    const float* __restrict__ pre_b1, float* __restrict__ tmp0)
{
    const int tid = threadIdx.x;
    if (blockIdx.x < 2048) {
        // dtype decision from detect slots (wave reduce, 2 loads/thread)
        const int lane = tid & 63;
        int c0 = det0[lane], c1 = det1[lane];
        #pragma unroll
        for (int o = 1; o < 64; o <<= 1) { c0 += __shfl_xor(c0, o); c1 += __shfl_xor(c1, o); }
        const int f = (c0 > 0) ? ((c1 > 0) ? 1 : 0) : 2;
        const int W = blockIdx.x * 128 + tid;   // global word id [0, 262144)
        const int z = W >> 17;
        const int rem = W & 131071;
        const int row = rem >> 6, w = rem & 63;
        const u8* src = z ? src1 : src0;
        u32 v = 0;
        if (f == 1) {
            const uint4* p = (const uint4*)(src + (long)row * 2048 + w * 32);
            const uint4 q0 = p[0], q1 = p[1];
            const u32 ws8[8] = {q0.x, q0.y, q0.z, q0.w, q1.x, q1.y, q1.z, q1.w};
            #pragma unroll
            for (int j = 0; j < 8; ++j) {
                const u32 x = ws8[j];
                const u32 m = (((x & 0x7f7f7f7fu) + 0x7f7f7f7fu) | x) & 0x80808080u;
                const u32 b4 = ((m >> 7) & 1u) | ((m >> 14) & 2u) |
                               ((m >> 21) & 4u) | ((m >> 28) & 8u);
                v |= b4 << (j * 4);
            }
        } else if (f == 0) {
            const uint4* p = (const uint4*)((const int*)src + (long)row * 2048 + w * 32);
            #pragma unroll
            for (int j = 0; j < 8; ++j) {
                const uint4 q = p[j];
                v |= (q.x ? 1u : 0u) << (j * 4 + 0);
                v |= (q.y ? 1u : 0u) << (j * 4 + 1);
                v |= (q.z ? 1u : 0u) << (j * 4 + 2);
                v |= (q.w ? 1u : 0u) << (j * 4 + 3);
            }
        } else {
            const uint4* p = (const uint4*)((const float*)src + (long)row * 2048 + w * 32);
            #pragma unroll
            for (int j = 0; j < 8; ++j) {
                const uint4 q = p[j];
                v |= ((q.x & 0x7fffffffu) ? 1u : 0u) << (j * 4 + 0);
                v |= ((q.y & 0x7fffffffu) ? 1u : 0u) << (j * 4 + 1);
                v |= ((q.z & 0x7fffffffu) ? 1u : 0u) << (j * 4 + 2);
                v |= ((q.w & 0x7fffffffu) ? 1u : 0u) << (j * 4 + 3);
            }
        }
        bits[(long)z * 131072 + rem] = v;
        return;
    }
    const int b2 = blockIdx.x - 2048;           // 0..255 -> (x 0..63, y 0..3)
    gemm_body<0, 0, 0, 256, 0, 0, 0>(b2 >> 2, b2 & 3, 0, gene_emb, 256,
                                     bt_hi, bt_lo, 0, 0, pre_b1,
                                     nullptr, nullptr, tmp0, 256, nullptr);
}

// ===========================================================================
// Merged C (128 thr, grid 288): blocks 0-31 CSR build (one thread per row);
// blocks 32-287 preGEMM2 with LN1+relu fused on A (tmp1 = relu(LN(tmp0))@w2+b2).
// ===========================================================================
__global__ __launch_bounds__(128) void mergedC_kernel(
    const u32* __restrict__ bits, int* __restrict__ deg, int* __restrict__ colidx,
    const float* __restrict__ tmp0,
    const ushort* __restrict__ bt_hi, const ushort* __restrict__ bt_lo,
    const float* __restrict__ pre_b2, const float* __restrict__ pre_ln_g,
    const float* __restrict__ pre_ln_b, float* __restrict__ tmp1)
{
    if (blockIdx.x < 32) {
        const int flat = blockIdx.x * 128 + threadIdx.x;   // [0, 4096)
        const int z = flat >> 11, r = flat & 2047;
        const u32* b = bits + (long)z * 131072 + r * 64;
        int* ci = colidx + ((long)z * 2048 + r) * CSTRIDE;
        int d = 0;
        for (int w = 0; w < 64; ++w) {
            u32 x = b[w];
            while (x) {
                const int j = __ffs(x) - 1;
                if (d < CSTRIDE) ci[d] = w * 32 + j;
                ++d;
                x &= x - 1;
            }
        }
        deg[z * 2048 + r] = d < CSTRIDE ? d : CSTRIDE;
        return;
    }
    const int b2 = blockIdx.x - 32;
    gemm_body<0, 0, 0, 256, 1, 1, 0>(b2 >> 2, b2 & 3, 0, tmp0, 256,
                                     bt_hi, bt_lo, 1, 0, pre_b2,
                                     pre_ln_g, pre_ln_b, tmp1, 256, nullptr);
}

// GEMM wrappers ------------------------------------------------------------
__global__ __launch_bounds__(128) void qkvm_kernel(
    const float* __restrict__ tmp1,
    const ushort* __restrict__ bt_hi, const ushort* __restrict__ bt_lo,
    const float* __restrict__ pre_ln_g, const float* __restrict__ pre_ln_b,
    float* __restrict__ qkvb, float* __restrict__ xg1)
{
    gemm_body<0, 1, 1, 256, 1, 1, 1>(blockIdx.x, blockIdx.y, blockIdx.z,
                                     tmp1, 256, bt_hi, bt_lo, 2, 0, nullptr,
                                     pre_ln_g, pre_ln_b, qkvb, 256, xg1);
}
__global__ __launch_bounds__(128) void wo_m_kernel(
    const float* __restrict__ ctx2,
    const ushort* __restrict__ bt_hi, const ushort* __restrict__ bt_lo,
    float* __restrict__ xg1)
{
    gemm_body<1, 0, 0, 512, 0, 0, 0>(blockIdx.x, blockIdx.y, 0, ctx2, 512,
                                     bt_hi, bt_lo, 5, 9, nullptr,
                                     nullptr, nullptr, xg1, 256, nullptr);
}
__global__ __launch_bounds__(128) void qkvs_kernel(
    const float* __restrict__ xg1,
    const ushort* __restrict__ bt_hi, const ushort* __restrict__ bt_lo,
    float* __restrict__ qkvb)
{
    gemm_body<0, 1, 2, 256, 0, 0, 0>(blockIdx.x, blockIdx.y, blockIdx.z,
                                     xg1, 256, bt_hi, bt_lo, 10, 0, nullptr,
                                     nullptr, nullptr, qkvb, 256, nullptr);
}
__global__ __launch_bounds__(128) void wo_s_kernel(
    const float* __restrict__ ctx2,
    const ushort* __restrict__ bt_hi, const ushort* __restrict__ bt_lo,
    float* __restrict__ xg1)
{
    gemm_body<1, 0, 0, 256, 0, 0, 0>(blockIdx.x, blockIdx.y, 0, ctx2, 512,
                                     bt_hi, bt_lo, 13, 0, nullptr,
                                     nullptr, nullptr, xg1, 256, nullptr);
}

// ===========================================================================
// Sparse masked attention (M block), exp2 domain. One wave per (row, graph).
// ===========================================================================
__global__ __launch_bounds__(64) void attn_sparse_kernel(
    const ushort* __restrict__ qkvb, const int* __restrict__ deg,
    const int* __restrict__ colidx, float* __restrict__ ctx)
{
    const int r = blockIdx.x, z = blockIdx.y;
    const ushort* qb = qkvb + (long)z * 1572864;
    const ushort* kb = qb + 524288;
    const ushort* vr = qb + 1048576;
    const int l = threadIdx.x;
    const int h = l >> 3, dg = l & 7;
    float* orow = &ctx[(long)r * 512 + z * 256 + h * 32 + dg * 4];
    const int n = deg[z * 2048 + r];
    if (n == 0) {
        float a0 = 0.f, a1 = 0.f, a2 = 0.f, a3 = 0.f;
        for (int k = 0; k < 2048; ++k) {
            const us4 vv = *(const us4*)&vr[((h * 2048 + k) << 5) + dg * 4];
            a0 += bf2f(vv[0]); a1 += bf2f(vv[1]); a2 += bf2f(vv[2]); a3 += bf2f(vv[3]);
        }
        float4 o; const float inv = 1.f / 2048.f;
        o.x = a0 * inv; o.y = a1 * inv; o.z = a2 * inv; o.w = a3 * inv;
        *(float4*)orow = o;
        return;
    }
    float q0, q1, q2, q3;
    {
        const us4 qv = *(const us4*)&qb[((h * 2048 + r) << 5) + dg * 4];
        q0 = bf2f(qv[0]); q1 = bf2f(qv[1]); q2 = bf2f(qv[2]); q3 = bf2f(qv[3]);
    }
    const int* ci = colidx + ((long)z * 2048 + r) * CSTRIDE;
    float m = -INFINITY, lsum = 0.f;
    float a0 = 0.f, a1 = 0.f, a2 = 0.f, a3 = 0.f;
    int kn = ci[0];
    us4 kv = *(const us4*)&kb[((h * 2048 + kn) << 5) + dg * 4];
    us4 vv = *(const us4*)&vr[((h * 2048 + kn) << 5) + dg * 4];
    for (int e = 0; e < n; ++e) {
        const us4 kc = kv, vc = vv;
        if (e + 1 < n) {
            kn = ci[e + 1];
            kv = *(const us4*)&kb[((h * 2048 + kn) << 5) + dg * 4];
            vv = *(const us4*)&vr[((h * 2048 + kn) << 5) + dg * 4];
        }
        float s = q0 * bf2f(kc[0]) + q1 * bf2f(kc[1]) +
                  q2 * bf2f(kc[2]) + q3 * bf2f(kc[3]);
        s += __shfl_xor(s, 1); s += __shfl_xor(s, 2); s += __shfl_xor(s, 4);
        const float mn = fmaxf(m, s);
        const float fac = __builtin_amdgcn_exp2f(m - mn);
        const float p = __builtin_amdgcn_exp2f(s - mn);
        lsum = lsum * fac + p;
        a0 = a0 * fac + p * bf2f(vc[0]);
        a1 = a1 * fac + p * bf2f(vc[1]);
        a2 = a2 * fac + p * bf2f(vc[2]);
        a3 = a3 * fac + p * bf2f(vc[3]);
        m = mn;
    }
    const float inv = 1.f / lsum;
    float4 o; o.x = a0 * inv; o.y = a1 * inv; o.z = a2 * inv; o.w = a3 * inv;
    *(float4*)orow = o;
}

// ===========================================================================
// Dense attention (S block): 32x32x16 swapped MFMA, in-register P via
// cvt_pk_bf16 + permlane32_swap, exp2 domain, k-split x8 (512 threads).
// ===========================================================================
__global__ __launch_bounds__(512) void attn_dense_kernel(
    const ushort* __restrict__ qkvb, float* __restrict__ ctx)
{
    const ushort* qb = qkvb;
    const ushort* kb = qb + 524288;
    const ushort* vt = qb + 1048576;
    const int h = blockIdx.x, qt = blockIdx.y;
    const int wv = threadIdx.x >> 6;
    const int l = threadIdx.x & 63;
    const int lq = l & 31;
    const int hi = l >> 5;
    const int qglob = qt * 32 + lq;

    __shared__ float Mm[7][32], Ml[7][32];
    __shared__ float Macc[7][64][16];
    __shared__ float ctile[32][33];

    const int qoff = ((h * 2048 + qglob) << 5) + hi * 8;
    const short8 qf0 = *(const short8*)&qb[qoff];
    const short8 qf1 = *(const short8*)&qb[qoff + 16];

    float m = -INFINITY, lsum = 0.f;
    f32x16 acc, zz16;
    #pragma unroll
    for (int i = 0; i < 16; ++i) { acc[i] = 0.f; zz16[i] = 0.f; }

    const int kt0 = wv * 256;
    #pragma unroll 2
    for (int it = 0; it < 8; ++it) {
        const int kbase = kt0 + it * 32;
        const int koff = ((h * 2048 + kbase + lq) << 5) + hi * 8;
        const short8 kf0 = *(const short8*)&kb[koff];
        const short8 kf1 = *(const short8*)&kb[koff + 16];
        f32x16 s = __builtin_amdgcn_mfma_f32_32x32x16_bf16(kf0, qf0, zz16, 0, 0, 0);
        s = __builtin_amdgcn_mfma_f32_32x32x16_bf16(kf1, qf1, s, 0, 0, 0);
        float sc[16];
        #pragma unroll
        for (int i = 0; i < 16; ++i) sc[i] = s[i];
        float t[8];
        #pragma unroll
        for (int i = 0; i < 8; ++i) t[i] = fmaxf(sc[i], sc[i + 8]);
        #pragma unroll
        for (int i = 0; i < 4; ++i) t[i] = fmaxf(t[i], t[i + 4]);
        float mt = fmaxf(fmaxf(t[0], t[1]), fmaxf(t[2], t[3]));
        mt = fmaxf(mt, __shfl_xor(mt, 32));
        const float mn = fmaxf(m, mt);
        if (__ballot(mn != m)) {
            const float fac = __builtin_amdgcn_exp2f(m - mn);
            lsum *= fac;
            #pragma unroll
            for (int i = 0; i < 16; ++i) acc[i] *= fac;
            m = mn;
        }
        #pragma unroll
        for (int i = 0; i < 16; ++i) sc[i] = __builtin_amdgcn_exp2f(sc[i] - m);
        #pragma unroll
        for (int i = 0; i < 8; ++i) t[i] = sc[i] + sc[i + 8];
        #pragma unroll
        for (int i = 0; i < 4; ++i) t[i] = t[i] + t[i + 4];
        float ps = (t[0] + t[1]) + (t[2] + t[3]);
        ps += __shfl_xor(ps, 32);
        lsum += ps;
        u32 pk[8];
        #pragma unroll
        for (int g = 0; g < 4; ++g) {
            asm("v_cvt_pk_bf16_f32 %0, %1, %2"
                : "=v"(pk[2 * g]) : "v"(sc[4 * g + 0]), "v"(sc[4 * g + 1]));
            asm("v_cvt_pk_bf16_f32 %0, %1, %2"
                : "=v"(pk[2 * g + 1]) : "v"(sc[4 * g + 2]), "v"(sc[4 * g + 3]));
        }
        asm volatile("v_permlane32_swap_b32 %0, %1" : "+v"(pk[0]), "+v"(pk[2]));
        asm volatile("v_permlane32_swap_b32 %0, %1" : "+v"(pk[1]), "+v"(pk[3]));
        asm volatile("v_permlane32_swap_b32 %0, %1" : "+v"(pk[4]), "+v"(pk[6]));
        asm volatile("v_permlane32_swap_b32 %0, %1" : "+v"(pk[5]), "+v"(pk[7]));
        short8 pB0, pB1;
        ((u32*)&pB0)[0] = pk[0]; ((u32*)&pB0)[1] = pk[1];
        ((u32*)&pB0)[2] = pk[2]; ((u32*)&pB0)[3] = pk[3];
        ((u32*)&pB1)[0] = pk[4]; ((u32*)&pB1)[1] = pk[5];
        ((u32*)&pB1)[2] = pk[6]; ((u32*)&pB1)[3] = pk[7];
        const int voff = ((h * 32 + lq) << 11) + kbase + hi * 8;
        const short8 vf0 = *(const short8*)&vt[voff];
        const short8 vf1 = *(const short8*)&vt[voff + 16];
        acc = __builtin_amdgcn_mfma_f32_32x32x16_bf16(vf0, pB0, acc, 0, 0, 0);
        acc = __builtin_amdgcn_mfma_f32_32x32x16_bf16(vf1, pB1, acc, 0, 0, 0);
    }

    if (wv) {
        if (l < 32) { Mm[wv - 1][l] = m; Ml[wv - 1][l] = lsum; }
        #pragma unroll
        for (int i = 0; i < 16; ++i) Macc[wv - 1][l][i] = acc[i];
    }
    __syncthreads();
    if (wv == 0) {
        float M = m;
        #pragma unroll
        for (int w = 0; w < 7; ++w) M = fmaxf(M, Mm[w][lq]);
        const float f0 = __builtin_amdgcn_exp2f(m - M);
        float den = lsum * f0;
        float o[16];
        #pragma unroll
        for (int i = 0; i < 16; ++i) o[i] = acc[i] * f0;
        #pragma unroll
        for (int w = 0; w < 7; ++w) {
            const float fw = __builtin_amdgcn_exp2f(Mm[w][lq] - M);
            den += Ml[w][lq] * fw;
            #pragma unroll
            for (int i = 0; i < 16; ++i) o[i] += Macc[w][l][i] * fw;
        }
        const float inv = 1.f / den;
        #pragma unroll
        for (int i = 0; i < 16; ++i)
            ctile[(i & 3) + 8 * (i >> 2) + 4 * hi][lq] = o[i] * inv;
    }
    __syncthreads();
    if (threadIdx.x < 256) {
        const int t = threadIdx.x;
        const int q = t >> 3, d0 = (t & 7) << 2;
        float4 ov;
        ov.x = ctile[d0 + 0][q]; ov.y = ctile[d0 + 1][q];
        ov.z = ctile[d0 + 2][q]; ov.w = ctile[d0 + 3][q];
        *(float4*)&ctx[(long)(qt * 32 + q) * 512 + h * 32 + d0] = ov;
    }
}

// ===========================================================================
// Aggregation GEMM with LN3 fused on A (=xg1, no relu): y<8 -> t tile;
// y==8 -> gate fully in-register (no atomics; flash merge downstream).
// ===========================================================================
__global__ __launch_bounds__(64) void aggr_gemm_kernel(
    const float* __restrict__ xg1,
    const ushort* __restrict__ bt_hi, const ushort* __restrict__ bt_lo,
    const float* __restrict__ ln_g, const float* __restrict__ ln_b,
    const float* __restrict__ tr_b, const float* __restrict__ g_b1,
    const float* __restrict__ g_w2, const float* __restrict__ g_b2,
    float* __restrict__ t_out, float* __restrict__ gv)
{
    const int l = threadIdx.x;
    const int lr = l & 15, lg = l >> 4;
    const int row0 = blockIdx.x * 16;
    const int gate = (blockIdx.y == 8);
    const int slot = gate ? 14 : 15;
    const int col0 = gate ? 0 : blockIdx.y * 32;
    const int NF = gate ? 8 : 2;
    const ushort* bh0 = bt_hi + (long)slot * 65536;
    const ushort* bl0 = bt_lo + (long)slot * 65536;
    const float* arow = xg1 + (long)(row0 + lr) * 256;

    // LN3 stats (exact; 4 lanes share a row via lg -> shfl_xor 16/32)
    float s = 0.f, s2 = 0.f;
    #pragma unroll
    for (int ks = 0; ks < 8; ++ks) {
        const float4 a0 = *(const float4*)&arow[ks * 32 + lg * 8];
        const float4 a1 = *(const float4*)&arow[ks * 32 + lg * 8 + 4];
        s  += (a0.x + a0.y) + (a0.z + a0.w) + (a1.x + a1.y) + (a1.z + a1.w);
        s2 += a0.x * a0.x + a0.y * a0.y + a0.z * a0.z + a0.w * a0.w +
              a1.x * a1.x + a1.y * a1.y + a1.z * a1.z + a1.w * a1.w;
    }
    s += __shfl_xor(s, 16);  s += __shfl_xor(s, 32);
    s2 += __shfl_xor(s2, 16); s2 += __shfl_xor(s2, 32);
    const float mean = s * (1.f / 256.f);
    const float rs = rsqrtf(s2 * (1.f / 256.f) - mean * mean + 1e-5f);

    const f32x4 z4 = {0.f, 0.f, 0.f, 0.f};
    f32x4 acc[8] = {z4, z4, z4, z4, z4, z4, z4, z4};

    #pragma unroll
    for (int ks = 0; ks < 8; ++ks) {
        const int k0 = ks * 32;
        float av[8], gvv[8], bvv[8];
        *(float4*)&av[0] = *(const float4*)&arow[k0 + lg * 8];
        *(float4*)&av[4] = *(const float4*)&arow[k0 + lg * 8 + 4];
        *(float4*)&gvv[0] = *(const float4*)&ln_g[k0 + lg * 8];
        *(float4*)&gvv[4] = *(const float4*)&ln_g[k0 + lg * 8 + 4];
        *(float4*)&bvv[0] = *(const float4*)&ln_b[k0 + lg * 8];
        *(float4*)&bvv[4] = *(const float4*)&ln_b[k0 + lg * 8 + 4];
        short8 ahi, alo;
        #pragma unroll
        for (int j = 0; j < 8; ++j) {
            const float vn = (av[j] - mean) * rs * gvv[j] + bvv[j];
            const u32 bi = __float_as_uint(vn);
            ahi[j] = (short)(bi >> 16);
            const float fh = __uint_as_float(bi & 0xffff0000u);
            alo[j] = (short)f2bf(vn - fh);
        }
        for (int f = 0; f < NF; ++f) {
            const long bo = (long)(col0 + f * 16 + lr) * 256 + k0 + lg * 8;
            const short8 bhi = *(const short8*)&bh0[bo];
            const short8 blo = *(const short8*)&bl0[bo];
            acc[f] = __builtin_amdgcn_mfma_f32_16x16x32_bf16(ahi, bhi, acc[f], 0, 0, 0);
            acc[f] = __builtin_amdgcn_mfma_f32_16x16x32_bf16(alo, bhi, acc[f], 0, 0, 0);
            acc[f] = __builtin_amdgcn_mfma_f32_16x16x32_bf16(ahi, blo, acc[f], 0, 0, 0);
        }
    }

    if (!gate) {
        #pragma unroll
        for (int f = 0; f < 2; ++f) {
            const int col = col0 + f * 16 + lr;
            const float bv = tr_b[col];
            #pragma unroll
            for (int r = 0; r < 4; ++r) {
                const int rr = row0 + lg * 4 + r;
                t_out[(long)rr * 256 + col] = fmaxf(acc[f][r] + bv, 0.f);
            }
        }
    } else {
        float b1v[8], w2v[8];
        #pragma unroll
        for (int f = 0; f < 8; ++f) {
            b1v[f] = g_b1[f * 16 + lr];
            w2v[f] = g_w2[f * 16 + lr];
        }
        const float b2 = g_b2[0];
        #pragma unroll
        for (int r = 0; r < 4; ++r) {
            float t = 0.f;
            #pragma unroll
            for (int f = 0; f < 8; ++f)
                t += fmaxf(acc[f][r] + b1v[f], 0.f) * w2v[f];
            #pragma unroll
            for (int o = 1; o < 16; o <<= 1) t += __shfl_xor(t, o);
            if (lr == 0) gv[row0 + lg * 4 + r] = t + b2;
        }
    }
}

// partial[b][col] = sum over 32 rows of exp(g - M_b) * t[r][col]; per-block
// local max M_b + exp-sum (flash-style; merged exactly in head2).
__global__ __launch_bounds__(256) void wsum_part_kernel(
    const float* __restrict__ gv, const float* __restrict__ t,
    float* __restrict__ partial, float* __restrict__ denp, float* __restrict__ mpart)
{
    const float L2E = 1.4426950408889634f;
    const int b = blockIdx.x, tid = threadIdx.x;
    float M = -INFINITY;
    #pragma unroll
    for (int i = 0; i < 32; ++i) M = fmaxf(M, gv[b * 32 + i]);
    float s = 0.f, den = 0.f;
    #pragma unroll 4
    for (int i = 0; i < 32; ++i) {
        const int r = b * 32 + i;
        const float w = __builtin_amdgcn_exp2f((gv[r] - M) * L2E);
        den += w;
        s += w * t[(long)r * 256 + tid];
    }
    partial[b * 256 + tid] = s;
    if (tid == 0) { denp[b] = den; mpart[b] = M; }
}

// flash-merge 64 blocks, then out = pooled @ head_w + head_b
__global__ __launch_bounds__(256) void head2_kernel(
    const float* __restrict__ partial, const float* __restrict__ denp,
    const float* __restrict__ mpart, const float* __restrict__ hw,
    const float* __restrict__ hb, float* __restrict__ out)
{
    __shared__ float fb[64];
    __shared__ float dtot;
    __shared__ float red0[4], red1[4];
    const float L2E = 1.4426950408889634f;
    const int tid = threadIdx.x;
    if (tid < 64) {
        const float mb = mpart[tid];
        float M = mb;
        #pragma unroll
        for (int o = 1; o < 64; o <<= 1) M = fmaxf(M, __shfl_xor(M, o));
        const float f = __builtin_amdgcn_exp2f((mb - M) * L2E);
        fb[tid] = f;
        float dv = f * denp[tid];
        #pragma unroll
        for (int o = 1; o < 64; o <<= 1) dv += __shfl_xor(dv, o);
        if (tid == 0) dtot = dv;
    }
    __syncthreads();
    float p = 0.f;
    #pragma unroll 8
    for (int b = 0; b < 64; ++b) p += fb[b] * partial[b * 256 + tid];
    p /= dtot;
    float s0 = p * hw[tid * 2 + 0];
    float s1 = p * hw[tid * 2 + 1];
    #pragma unroll
    for (int o = 1; o < 64; o <<= 1) { s0 += __shfl_xor(s0, o); s1 += __shfl_xor(s1, o); }
    if ((tid & 63) == 0) { red0[tid >> 6] = s0; red1[tid >> 6] = s1; }
    __syncthreads();
    if (tid == 0) {
        out[0] = red0[0] + red0[1] + red0[2] + red0[3] + hb[0];
        out[1] = red1[0] + red1[1] + red1[2] + red1[3] + hb[1];
    }
}

// ---------------------------------------------------------------------------
extern "C" void kernel_launch(void* const* d_in, const int* in_sizes, int n_in,
                              void* d_out, int out_size, void* d_ws, size_t ws_size,
                              hipStream_t stream)
{
    (void)in_sizes; (void)n_in; (void)out_size; (void)ws_size;
    const float* gene_emb = (const float*)d_in[0];
    const float* pre_w1   = (const float*)d_in[3];
    const float* pre_b1   = (const float*)d_in[4];
    const float* pre_w2   = (const float*)d_in[5];
    const float* pre_b2   = (const float*)d_in[6];
    const float* pre_ln_g = (const float*)d_in[7];
    const float* pre_ln_b = (const float*)d_in[8];
    const float* wm       = (const float*)d_in[9];
    const float* wsw      = (const float*)d_in[10];
    const float* ln_g     = (const float*)d_in[11];  // row 0 (genes)
    const float* ln_b     = (const float*)d_in[12];
    const float* gate_w1  = (const float*)d_in[13];
    const float* gate_b1  = (const float*)d_in[14];
    const float* gate_w2  = (const float*)d_in[15];
    const float* gate_b2  = (const float*)d_in[16];
    const float* tr_w     = (const float*)d_in[17];
    const float* tr_b     = (const float*)d_in[18];
    const float* head_w   = (const float*)d_in[19];
    const float* head_b   = (const float*)d_in[20];
    const u8* adj_pp      = (const u8*)d_in[21];
    const u8* adj_rr      = (const u8*)d_in[22];
    // d_in[1],[2],[23],[24] dead (reaction/metab branches never reach output)

    const long NHf = (long)Gn * Hd;
    float* tmp0    = (float*)d_ws;                     // preG1 out, later t-matrix
    float* tmp1    = tmp0 + NHf;                       // preG2 out
    float* xg1     = tmp1 + NHf;                       // residual accumulator
    float* ctx2    = xg1 + NHf;                        // [2048][512]
    float* gv      = ctx2 + 2 * NHf;                   // [2048]
    float* partial = gv + Gn;                          // [64][256]
    float* denp    = partial + 64 * 256;               // [64]
    float* mpart   = denp + 64;                        // [64]
    int* det0      = (int*)(mpart + 64);               // [64]
    int* det1      = det0 + 64;                        // [64]
    int* deg       = det1 + 64;                        // [2][2048]
    int* colidx    = deg + 4096;                       // [2][2048][192]
    u32* bits      = (u32*)(colidx + 2L * 2048 * CSTRIDE);
    ushort* qkvb   = (ushort*)(bits + 262144);         // 2 x 1572864 bf16
    ushort* bt_hi  = qkvb + 2L * 1572864;              // 16 slots x 65536
    ushort* bt_lo  = bt_hi + 16L * 65536;

    dim3 B256(256), B128(128), T64(64);

    // 1: detect (blocks 0-63) || weight pre-split (blocks 64-191)
    mergedA_kernel<<<dim3(192), B256, 0, stream>>>(adj_pp, det0, det1,
        pre_w1, pre_w2, wm, wsw, gate_w1, tr_w, bt_hi, bt_lo);
    // 2: pack masks (blocks 0-2047) || preGEMM1 (blocks 2048-2303)
    mergedB_kernel<<<dim3(2304), B128, 0, stream>>>(adj_pp, adj_rr, det0, det1,
        bits, gene_emb, bt_hi, bt_lo, pre_b1, tmp0);
    // 3: CSR (blocks 0-31) || preGEMM2 with LN1+relu fused (blocks 32-287)
    mergedC_kernel<<<dim3(288), B128, 0, stream>>>(bits, deg, colidx, tmp0,
        bt_hi, bt_lo, pre_b2, pre_ln_g, pre_ln_b, tmp1);
    // 4: QKV-M with LN2+relu fused; (y=0,z=0) blocks write xg1 = LN output
    qkvm_kernel<<<dim3(64, 4, 6), B128, 0, stream>>>(tmp1, bt_hi, bt_lo,
        pre_ln_g, pre_ln_b, (float*)qkvb, xg1);
    // 5: sparse masked attention (both M graphs)
    attn_sparse_kernel<<<dim3(2048, 2), T64, 0, stream>>>(qkvb, deg, colidx, ctx2);
    // 6: fused dual-Wo (K=512) accumulate into xg1
    wo_m_kernel<<<dim3(64, 4), B128, 0, stream>>>(ctx2, bt_hi, bt_lo, xg1);
    // 7: QKV-S (V transposed)
    qkvs_kernel<<<dim3(64, 4, 3), B128, 0, stream>>>(xg1, bt_hi, bt_lo, (float*)qkvb);
    // 8: dense self-attention
    attn_dense_kernel<<<dim3(8, 64), dim3(512), 0, stream>>>(qkvb, ctx2);
    // 9: Wo-S accumulate into xg1
    wo_s_kernel<<<dim3(64, 4), B128, 0, stream>>>(ctx2, bt_hi, bt_lo, xg1);
    // 10: aggregation GEMM with LN3 fused (tr tiles y<8, in-register gate y=8)
    aggr_gemm_kernel<<<dim3(128, 9), T64, 0, stream>>>(xg1, bt_hi, bt_lo,
        ln_g, ln_b, tr_b, gate_b1, gate_w2, gate_b2, tmp0, gv);
    // 11: weighted sum (flash-style local max per block)
    wsum_part_kernel<<<dim3(64), B256, 0, stream>>>(gv, tmp0, partial, denp, mpart);
    // 12: merge + head
    head2_kernel<<<dim3(1), B256, 0, stream>>>(partial, denp, mpart, head_w, head_b, (float*)d_out);
}

// Round 11
// 191.794 us; speedup vs baseline: 1.7958x; 1.0649x over previous
//
#include <hip/hip_runtime.h>
#include <hip/hip_bf16.h>
#include <cmath>
#include <cstdint>

typedef unsigned int u32;
typedef unsigned char u8;
typedef unsigned short ushort;
typedef __attribute__((ext_vector_type(8))) short short8;
typedef __attribute__((ext_vector_type(4))) float f32x4;
typedef __attribute__((ext_vector_type(16))) float f32x16;
typedef __attribute__((ext_vector_type(4))) unsigned short us4;

#define Gn 2048
#define Hd 256
#define CSTRIDE 192

static __device__ __forceinline__ ushort f2bf(float x) {
    __hip_bfloat16 b = __float2bfloat16(x);
    return *reinterpret_cast<ushort*>(&b);
}
static __device__ __forceinline__ float bf2f(ushort u) {
    return __uint_as_float(((u32)u) << 16);
}

// ===========================================================================
// Weight arenas are FRAGMENT-MAJOR (R11 change): element (col,k) of W^T lives
// at slot*65536 + ((col>>4)*8 + (k>>5))*512 + (((k&31)>>3)*16 + (col&15))*8
// + (k&7). A wave's MFMA B-fragment (16 cols x 32 k) is then one contiguous
// 1KB burst: lane l reads [base + l*8 .. +8) — fully coalesced (was 16
// scattered cache lines at 512B stride -> latency-bound GEMMs, MfmaUtil 4%).
// ===========================================================================

// ===========================================================================
// GEMM body (device fn): bf16x3 split-precision MFMA, 32x64 tile, 2 waves.
// LNF: apply LayerNorm(+LNRELU relu) to A rows on the fly. Exact fp32 LN.
// WRA: (by==0 && bz==0) blocks write normalized A rows to Aout (residual).
// OUTMODE 1 = QKV bf16 epilogue (Q pre-scaled 1/sqrt(32)*log2e).
// QKVMODE 1 (M): V row-layout; QKVMODE 2 (S): V transposed.
// KT=512: ks>=8 reads slot2 arena (fused dual-Wo accumulate).
// ===========================================================================
template <int BETA, int OUTMODE, int QKVMODE, int KT, int LNF, int LNRELU, int WRA>
static __device__ __forceinline__ void gemm_body(
    const int bx, const int by, const int bz,
    const float* __restrict__ A, int lda,
    const ushort* __restrict__ bt_hi, const ushort* __restrict__ bt_lo,
    int slot0, int slot2, const float* __restrict__ bias,
    const float* __restrict__ lng, const float* __restrict__ lnb,
    float* __restrict__ C, int N, float* __restrict__ Aout)
{
    const int tid = threadIdx.x;
    const int wv = tid >> 6, l = tid & 63;
    const int lr = l & 15, lg = l >> 4;
    const int row = bx * 32 + wv * 16 + lr;
    const int col0 = by * 64;
    int slot = slot0, zq = 0, buf = 0;
    if (QKVMODE == 1) { slot = slot0 + bz + bz / 3; zq = bz % 3; buf = bz / 3; }
    else if (QKVMODE == 2) { slot = slot0 + bz; zq = bz; }
    const ushort* bhb = bt_hi + (long)slot * 65536;
    const ushort* blb = bt_lo + (long)slot * 65536;
    const float* arow = A + (long)row * lda;

    float mean = 0.f, rs = 0.f;
    if (LNF) {
        float s = 0.f, s2 = 0.f;
        #pragma unroll
        for (int ks = 0; ks < 8; ++ks) {
            const float4 a0 = *(const float4*)&arow[ks * 32 + lg * 8];
            const float4 a1 = *(const float4*)&arow[ks * 32 + lg * 8 + 4];
            s  += (a0.x + a0.y) + (a0.z + a0.w) + (a1.x + a1.y) + (a1.z + a1.w);
            s2 += a0.x * a0.x + a0.y * a0.y + a0.z * a0.z + a0.w * a0.w +
                  a1.x * a1.x + a1.y * a1.y + a1.z * a1.z + a1.w * a1.w;
        }
        s += __shfl_xor(s, 16);  s += __shfl_xor(s, 32);
        s2 += __shfl_xor(s2, 16); s2 += __shfl_xor(s2, 32);
        mean = s * (1.f / 256.f);
        rs = rsqrtf(s2 * (1.f / 256.f) - mean * mean + 1e-5f);
    }

    const f32x4 z4 = {0.f, 0.f, 0.f, 0.f};
    f32x4 acc[4] = {z4, z4, z4, z4};

    #pragma unroll
    for (int ks = 0; ks < KT / 32; ++ks) {
        const int k0 = ks * 32;
        const ushort* bh; const ushort* bl; int kbi = ks;
        if (KT == 512 && k0 >= 256) {
            bh = bt_hi + (long)slot2 * 65536;
            bl = bt_lo + (long)slot2 * 65536;
            kbi = ks - 8;
        } else { bh = bhb; bl = blb; }
        float av[8];
        *(float4*)&av[0] = *(const float4*)&arow[k0 + lg * 8];
        *(float4*)&av[4] = *(const float4*)&arow[k0 + lg * 8 + 4];
        if (LNF) {
            float gvv[8], bvv[8];
            *(float4*)&gvv[0] = *(const float4*)&lng[k0 + lg * 8];
            *(float4*)&gvv[4] = *(const float4*)&lng[k0 + lg * 8 + 4];
            *(float4*)&bvv[0] = *(const float4*)&lnb[k0 + lg * 8];
            *(float4*)&bvv[4] = *(const float4*)&lnb[k0 + lg * 8 + 4];
            #pragma unroll
            for (int j = 0; j < 8; ++j) {
                float v = (av[j] - mean) * rs * gvv[j] + bvv[j];
                if (LNRELU) v = fmaxf(v, 0.f);
                av[j] = v;
            }
            if (WRA && by == 0 && bz == 0) {
                *(float4*)&Aout[(long)row * 256 + k0 + lg * 8] = *(float4*)&av[0];
                *(float4*)&Aout[(long)row * 256 + k0 + lg * 8 + 4] = *(float4*)&av[4];
            }
        }
        short8 ahi, alo;
        #pragma unroll
        for (int j = 0; j < 8; ++j) {
            const u32 bi = __float_as_uint(av[j]);
            ahi[j] = (short)(bi >> 16);
            const float fh = __uint_as_float(bi & 0xffff0000u);
            alo[j] = (short)f2bf(av[j] - fh);
        }
        #pragma unroll
        for (int f = 0; f < 4; ++f) {
            // fragment-major: colblk = by*4+f, kblk = kbi; lane l -> +l*8
            const long bo = (long)(((by * 4 + f) * 8 + kbi) << 9) + (l << 3);
            const short8 bhi = *(const short8*)&bh[bo];
            const short8 blo = *(const short8*)&bl[bo];
            acc[f] = __builtin_amdgcn_mfma_f32_16x16x32_bf16(ahi, bhi, acc[f], 0, 0, 0);
            acc[f] = __builtin_amdgcn_mfma_f32_16x16x32_bf16(alo, bhi, acc[f], 0, 0, 0);
            acc[f] = __builtin_amdgcn_mfma_f32_16x16x32_bf16(ahi, blo, acc[f], 0, 0, 0);
        }
    }

    const float QS = 0.17677669529663687f * 1.4426950408889634f;

    #pragma unroll
    for (int f = 0; f < 4; ++f) {
        const int col = col0 + f * 16 + lr;
        const float bv = bias ? bias[col] : 0.f;
        #pragma unroll
        for (int r = 0; r < 4; ++r) {
            const int rr = bx * 32 + wv * 16 + lg * 4 + r;
            float v = acc[f][r] + bv;
            if (OUTMODE == 1) {
                if (zq == 0) v *= QS;
                ushort* ob = (ushort*)C + (long)buf * 1572864;
                const int h = col >> 5, d = col & 31;
                if (QKVMODE == 1 || zq < 2)
                    ob[zq * 524288 + ((h * 2048 + rr) << 5) + d] = f2bf(v);
                else
                    ob[1048576 + ((h * 32 + d) << 11) + rr] = f2bf(v);
            } else {
                if (BETA) v += C[(long)rr * N + col];
                C[(long)rr * N + col] = v;
            }
        }
    }
}

// ===========================================================================
// Merged A (256 thr, grid 192): blocks 0-63 mask-dtype detect (per-block
// slots, no atomics/no init); blocks 64-191 weight pre-split (fragment-major).
// ===========================================================================
__global__ __launch_bounds__(256) void mergedA_kernel(
    const u8* __restrict__ adj, int* __restrict__ det0, int* __restrict__ det1,
    const float* __restrict__ pre_w1, const float* __restrict__ pre_w2,
    const float* __restrict__ wm, const float* __restrict__ wsw,
    const float* __restrict__ gate_w1, const float* __restrict__ tr_w,
    ushort* __restrict__ bt_hi, ushort* __restrict__ bt_lo)
{
    __shared__ float T[32][257];
    __shared__ int sd0[4], sd1[4];
    const int tid = threadIdx.x;
    if (blockIdx.x < 64) {
        const int idx = blockIdx.x * 256 + tid;
        const uint4 w = ((const uint4*)adj)[idx];
        int c0 = ((w.x & 0xffu) ? 1 : 0) + ((w.y & 0xffu) ? 1 : 0) +
                 ((w.z & 0xffu) ? 1 : 0) + ((w.w & 0xffu) ? 1 : 0);
        int c1 = ((w.x & 0xffffff00u) ? 1 : 0) + ((w.y & 0xffffff00u) ? 1 : 0) +
                 ((w.z & 0xffffff00u) ? 1 : 0) + ((w.w & 0xffffff00u) ? 1 : 0);
        #pragma unroll
        for (int o = 1; o < 64; o <<= 1) { c0 += __shfl_xor(c0, o); c1 += __shfl_xor(c1, o); }
        if ((tid & 63) == 0) { sd0[tid >> 6] = c0; sd1[tid >> 6] = c1; }
        __syncthreads();
        if (tid == 0) {
            det0[blockIdx.x] = sd0[0] + sd0[1] + sd0[2] + sd0[3];
            det1[blockIdx.x] = sd1[0] + sd1[1] + sd1[2] + sd1[3];
        }
        return;
    }
    const int b2 = blockIdx.x - 64;
    const int slot = b2 >> 3;
    const int kb = b2 & 7;
    const int k0 = kb * 32;
    const float* src; int ncols = 256;
    if (slot == 0) src = pre_w1;
    else if (slot == 1) src = pre_w2;
    else if (slot < 6) src = wm + (long)(slot - 2) * 65536;
    else if (slot < 10) src = wm + (long)(4 + slot - 6) * 65536;
    else if (slot < 14) src = wsw + (long)(slot - 10) * 65536;
    else if (slot == 14) { src = gate_w1; ncols = 128; }
    else src = tr_w;

    const int lsh = (ncols == 256) ? 6 : 5;
    const int tot = 32 << lsh;
    for (int i = tid; i < tot; i += 256) {
        const int kk = i >> lsh, c4 = (i & ((1 << lsh) - 1)) << 2;
        const float4 v = *(const float4*)&src[(long)(k0 + kk) * ncols + c4];
        T[kk][c4 + 0] = v.x; T[kk][c4 + 1] = v.y;
        T[kk][c4 + 2] = v.z; T[kk][c4 + 3] = v.w;
    }
    __syncthreads();
    if (tid < ncols) {
        ushort hb[32], lb[32];
        #pragma unroll
        for (int kk = 0; kk < 32; ++kk) {
            const float x = T[kk][tid];
            const u32 bi = __float_as_uint(x);
            const ushort h = (ushort)(bi >> 16);
            const float fh = __uint_as_float(bi & 0xffff0000u);
            hb[kk] = h; lb[kk] = f2bf(x - fh);
        }
        // fragment-major store: cb = tid>>4, lr = tid&15; kk -> (lg2 = kk>>3, j)
        const int cb = tid >> 4, lr = tid & 15;
        const long base = (long)slot * 65536 + ((cb * 8 + kb) << 9);
        ushort* oh = bt_hi + base;
        ushort* ol = bt_lo + base;
        #pragma unroll
        for (int lg2 = 0; lg2 < 4; ++lg2) {
            const int off = (lg2 * 16 + lr) << 3;
            *(uint4*)&oh[off] = *(const uint4*)&hb[lg2 * 8];
            *(uint4*)&ol[off] = *(const uint4*)&lb[lg2 * 8];
        }
    }
}

// ===========================================================================
// Merged B (128 thr, grid 2304): blocks 0-2047 pack masks into bitwords;
// blocks 2048-2303 preGEMM1 (tmp0 = gene_emb @ pre_w1 + b1).
// ===========================================================================
__global__ __launch_bounds__(128) void mergedB_kernel(
    const u8* __restrict__ src0, const u8* __restrict__ src1,
    const int* __restrict__ det0, const int* __restrict__ det1,
    u32* __restrict__ bits,
    const float* __restrict__ gene_emb,
    const ushort* __restrict__ bt_hi, const ushort* __restrict__ bt_lo,
    const float* __restrict__ pre_b1, float* __restrict__ tmp0)
{
    const int tid = threadIdx.x;
    if (blockIdx.x < 2048) {
        const int lane = tid & 63;
        int c0 = det0[lane], c1 = det1[lane];
        #pragma unroll
        for (int o = 1; o < 64; o <<= 1) { c0 += __shfl_xor(c0, o); c1 += __shfl_xor(c1, o); }
        const int f = (c0 > 0) ? ((c1 > 0) ? 1 : 0) : 2;
        const int W = blockIdx.x * 128 + tid;
        const int z = W >> 17;
        const int rem = W & 131071;
        const int row = rem >> 6, w = rem & 63;
        const u8* src = z ? src1 : src0;
        u32 v = 0;
        if (f == 1) {
            const uint4* p = (const uint4*)(src + (long)row * 2048 + w * 32);
            const uint4 q0 = p[0], q1 = p[1];
            const u32 ws8[8] = {q0.x, q0.y, q0.z, q0.w, q1.x, q1.y, q1.z, q1.w};
            #pragma unroll
            for (int j = 0; j < 8; ++j) {
                const u32 x = ws8[j];
                const u32 m = (((x & 0x7f7f7f7fu) + 0x7f7f7f7fu) | x) & 0x80808080u;
                const u32 b4 = ((m >> 7) & 1u) | ((m >> 14) & 2u) |
                               ((m >> 21) & 4u) | ((m >> 28) & 8u);
                v |= b4 << (j * 4);
            }
        } else if (f == 0) {
            const uint4* p = (const uint4*)((const int*)src + (long)row * 2048 + w * 32);
            #pragma unroll
            for (int j = 0; j < 8; ++j) {
                const uint4 q = p[j];
                v |= (q.x ? 1u : 0u) << (j * 4 + 0);
                v |= (q.y ? 1u : 0u) << (j * 4 + 1);
                v |= (q.z ? 1u : 0u) << (j * 4 + 2);
                v |= (q.w ? 1u : 0u) << (j * 4 + 3);
            }
        } else {
            const uint4* p = (const uint4*)((const float*)src + (long)row * 2048 + w * 32);
            #pragma unroll
            for (int j = 0; j < 8; ++j) {
                const uint4 q = p[j];
                v |= ((q.x & 0x7fffffffu) ? 1u : 0u) << (j * 4 + 0);
                v |= ((q.y & 0x7fffffffu) ? 1u : 0u) << (j * 4 + 1);
                v |= ((q.z & 0x7fffffffu) ? 1u : 0u) << (j * 4 + 2);
                v |= ((q.w & 0x7fffffffu) ? 1u : 0u) << (j * 4 + 3);
            }
        }
        bits[(long)z * 131072 + rem] = v;
        return;
    }
    const int b2 = blockIdx.x - 2048;
    gemm_body<0, 0, 0, 256, 0, 0, 0>(b2 >> 2, b2 & 3, 0, gene_emb, 256,
                                     bt_hi, bt_lo, 0, 0, pre_b1,
                                     nullptr, nullptr, tmp0, 256, nullptr);
}

// ===========================================================================
// Merged C (128 thr, grid 288): blocks 0-31 CSR build; blocks 32-287
// preGEMM2 with LN1+relu fused on A (tmp1 = relu(LN(tmp0))@w2+b2).
// ===========================================================================
__global__ __launch_bounds__(128) void mergedC_kernel(
    const u32* __restrict__ bits, int* __restrict__ deg, int* __restrict__ colidx,
    const float* __restrict__ tmp0,
    const ushort* __restrict__ bt_hi, const ushort* __restrict__ bt_lo,
    const float* __restrict__ pre_b2, const float* __restrict__ pre_ln_g,
    const float* __restrict__ pre_ln_b, float* __restrict__ tmp1)
{
    if (blockIdx.x < 32) {
        const int flat = blockIdx.x * 128 + threadIdx.x;
        const int z = flat >> 11, r = flat & 2047;
        const u32* b = bits + (long)z * 131072 + r * 64;
        int* ci = colidx + ((long)z * 2048 + r) * CSTRIDE;
        int d = 0;
        for (int w = 0; w < 64; ++w) {
            u32 x = b[w];
            while (x) {
                const int j = __ffs(x) - 1;
                if (d < CSTRIDE) ci[d] = w * 32 + j;
                ++d;
                x &= x - 1;
            }
        }
        deg[z * 2048 + r] = d < CSTRIDE ? d : CSTRIDE;
        return;
    }
    const int b2 = blockIdx.x - 32;
    gemm_body<0, 0, 0, 256, 1, 1, 0>(b2 >> 2, b2 & 3, 0, tmp0, 256,
                                     bt_hi, bt_lo, 1, 0, pre_b2,
                                     pre_ln_g, pre_ln_b, tmp1, 256, nullptr);
}

// GEMM wrappers ------------------------------------------------------------
__global__ __launch_bounds__(128) void qkvm_kernel(
    const float* __restrict__ tmp1,
    const ushort* __restrict__ bt_hi, const ushort* __restrict__ bt_lo,
    const float* __restrict__ pre_ln_g, const float* __restrict__ pre_ln_b,
    float* __restrict__ qkvb, float* __restrict__ xg1)
{
    gemm_body<0, 1, 1, 256, 1, 1, 1>(blockIdx.x, blockIdx.y, blockIdx.z,
                                     tmp1, 256, bt_hi, bt_lo, 2, 0, nullptr,
                                     pre_ln_g, pre_ln_b, qkvb, 256, xg1);
}
__global__ __launch_bounds__(128) void wo_m_kernel(
    const float* __restrict__ ctx2,
    const ushort* __restrict__ bt_hi, const ushort* __restrict__ bt_lo,
    float* __restrict__ xg1)
{
    gemm_body<1, 0, 0, 512, 0, 0, 0>(blockIdx.x, blockIdx.y, 0, ctx2, 512,
                                     bt_hi, bt_lo, 5, 9, nullptr,
                                     nullptr, nullptr, xg1, 256, nullptr);
}
__global__ __launch_bounds__(128) void qkvs_kernel(
    const float* __restrict__ xg1,
    const ushort* __restrict__ bt_hi, const ushort* __restrict__ bt_lo,
    float* __restrict__ qkvb)
{
    gemm_body<0, 1, 2, 256, 0, 0, 0>(blockIdx.x, blockIdx.y, blockIdx.z,
                                     xg1, 256, bt_hi, bt_lo, 10, 0, nullptr,
                                     nullptr, nullptr, qkvb, 256, nullptr);
}
__global__ __launch_bounds__(128) void wo_s_kernel(
    const float* __restrict__ ctx2,
    const ushort* __restrict__ bt_hi, const ushort* __restrict__ bt_lo,
    float* __restrict__ xg1)
{
    gemm_body<1, 0, 0, 256, 0, 0, 0>(blockIdx.x, blockIdx.y, 0, ctx2, 512,
                                     bt_hi, bt_lo, 13, 0, nullptr,
                                     nullptr, nullptr, xg1, 256, nullptr);
}

// ===========================================================================
// Sparse masked attention (M block), exp2 domain. One wave per (row, graph).
// ===========================================================================
__global__ __launch_bounds__(64) void attn_sparse_kernel(
    const ushort* __restrict__ qkvb, const int* __restrict__ deg,
    const int* __restrict__ colidx, float* __restrict__ ctx)
{
    const int r = blockIdx.x, z = blockIdx.y;
    const ushort* qb = qkvb + (long)z * 1572864;
    const ushort* kb = qb + 524288;
    const ushort* vr = qb + 1048576;
    const int l = threadIdx.x;
    const int h = l >> 3, dg = l & 7;
    float* orow = &ctx[(long)r * 512 + z * 256 + h * 32 + dg * 4];
    const int n = deg[z * 2048 + r];
    if (n == 0) {
        float a0 = 0.f, a1 = 0.f, a2 = 0.f, a3 = 0.f;
        for (int k = 0; k < 2048; ++k) {
            const us4 vv = *(const us4*)&vr[((h * 2048 + k) << 5) + dg * 4];
            a0 += bf2f(vv[0]); a1 += bf2f(vv[1]); a2 += bf2f(vv[2]); a3 += bf2f(vv[3]);
        }
        float4 o; const float inv = 1.f / 2048.f;
        o.x = a0 * inv; o.y = a1 * inv; o.z = a2 * inv; o.w = a3 * inv;
        *(float4*)orow = o;
        return;
    }
    float q0, q1, q2, q3;
    {
        const us4 qv = *(const us4*)&qb[((h * 2048 + r) << 5) + dg * 4];
        q0 = bf2f(qv[0]); q1 = bf2f(qv[1]); q2 = bf2f(qv[2]); q3 = bf2f(qv[3]);
    }
    const int* ci = colidx + ((long)z * 2048 + r) * CSTRIDE;
    float m = -INFINITY, lsum = 0.f;
    float a0 = 0.f, a1 = 0.f, a2 = 0.f, a3 = 0.f;
    int kn = ci[0];
    us4 kv = *(const us4*)&kb[((h * 2048 + kn) << 5) + dg * 4];
    us4 vv = *(const us4*)&vr[((h * 2048 + kn) << 5) + dg * 4];
    for (int e = 0; e < n; ++e) {
        const us4 kc = kv, vc = vv;
        if (e + 1 < n) {
            kn = ci[e + 1];
            kv = *(const us4*)&kb[((h * 2048 + kn) << 5) + dg * 4];
            vv = *(const us4*)&vr[((h * 2048 + kn) << 5) + dg * 4];
        }
        float s = q0 * bf2f(kc[0]) + q1 * bf2f(kc[1]) +
                  q2 * bf2f(kc[2]) + q3 * bf2f(kc[3]);
        s += __shfl_xor(s, 1); s += __shfl_xor(s, 2); s += __shfl_xor(s, 4);
        const float mn = fmaxf(m, s);
        const float fac = __builtin_amdgcn_exp2f(m - mn);
        const float p = __builtin_amdgcn_exp2f(s - mn);
        lsum = lsum * fac + p;
        a0 = a0 * fac + p * bf2f(vc[0]);
        a1 = a1 * fac + p * bf2f(vc[1]);
        a2 = a2 * fac + p * bf2f(vc[2]);
        a3 = a3 * fac + p * bf2f(vc[3]);
        m = mn;
    }
    const float inv = 1.f / lsum;
    float4 o; o.x = a0 * inv; o.y = a1 * inv; o.z = a2 * inv; o.w = a3 * inv;
    *(float4*)orow = o;
}

// ===========================================================================
// Dense attention (S block): 32x32x16 swapped MFMA, in-register P via
// cvt_pk_bf16 + permlane32_swap, exp2 domain, k-split x8 (512 threads).
// ===========================================================================
__global__ __launch_bounds__(512) void attn_dense_kernel(
    const ushort* __restrict__ qkvb, float* __restrict__ ctx)
{
    const ushort* qb = qkvb;
    const ushort* kb = qb + 524288;
    const ushort* vt = qb + 1048576;
    const int h = blockIdx.x, qt = blockIdx.y;
    const int wv = threadIdx.x >> 6;
    const int l = threadIdx.x & 63;
    const int lq = l & 31;
    const int hi = l >> 5;
    const int qglob = qt * 32 + lq;

    __shared__ float Mm[7][32], Ml[7][32];
    __shared__ float Macc[7][64][16];
    __shared__ float ctile[32][33];

    const int qoff = ((h * 2048 + qglob) << 5) + hi * 8;
    const short8 qf0 = *(const short8*)&qb[qoff];
    const short8 qf1 = *(const short8*)&qb[qoff + 16];

    float m = -INFINITY, lsum = 0.f;
    f32x16 acc, zz16;
    #pragma unroll
    for (int i = 0; i < 16; ++i) { acc[i] = 0.f; zz16[i] = 0.f; }

    const int kt0 = wv * 256;
    #pragma unroll 2
    for (int it = 0; it < 8; ++it) {
        const int kbase = kt0 + it * 32;
        const int koff = ((h * 2048 + kbase + lq) << 5) + hi * 8;
        const short8 kf0 = *(const short8*)&kb[koff];
        const short8 kf1 = *(const short8*)&kb[koff + 16];
        f32x16 s = __builtin_amdgcn_mfma_f32_32x32x16_bf16(kf0, qf0, zz16, 0, 0, 0);
        s = __builtin_amdgcn_mfma_f32_32x32x16_bf16(kf1, qf1, s, 0, 0, 0);
        float sc[16];
        #pragma unroll
        for (int i = 0; i < 16; ++i) sc[i] = s[i];
        float t[8];
        #pragma unroll
        for (int i = 0; i < 8; ++i) t[i] = fmaxf(sc[i], sc[i + 8]);
        #pragma unroll
        for (int i = 0; i < 4; ++i) t[i] = fmaxf(t[i], t[i + 4]);
        float mt = fmaxf(fmaxf(t[0], t[1]), fmaxf(t[2], t[3]));
        mt = fmaxf(mt, __shfl_xor(mt, 32));
        const float mn = fmaxf(m, mt);
        if (__ballot(mn != m)) {
            const float fac = __builtin_amdgcn_exp2f(m - mn);
            lsum *= fac;
            #pragma unroll
            for (int i = 0; i < 16; ++i) acc[i] *= fac;
            m = mn;
        }
        #pragma unroll
        for (int i = 0; i < 16; ++i) sc[i] = __builtin_amdgcn_exp2f(sc[i] - m);
        #pragma unroll
        for (int i = 0; i < 8; ++i) t[i] = sc[i] + sc[i + 8];
        #pragma unroll
        for (int i = 0; i < 4; ++i) t[i] = t[i] + t[i + 4];
        float ps = (t[0] + t[1]) + (t[2] + t[3]);
        ps += __shfl_xor(ps, 32);
        lsum += ps;
        u32 pk[8];
        #pragma unroll
        for (int g = 0; g < 4; ++g) {
            asm("v_cvt_pk_bf16_f32 %0, %1, %2"
                : "=v"(pk[2 * g]) : "v"(sc[4 * g + 0]), "v"(sc[4 * g + 1]));
            asm("v_cvt_pk_bf16_f32 %0, %1, %2"
                : "=v"(pk[2 * g + 1]) : "v"(sc[4 * g + 2]), "v"(sc[4 * g + 3]));
        }
        asm volatile("v_permlane32_swap_b32 %0, %1" : "+v"(pk[0]), "+v"(pk[2]));
        asm volatile("v_permlane32_swap_b32 %0, %1" : "+v"(pk[1]), "+v"(pk[3]));
        asm volatile("v_permlane32_swap_b32 %0, %1" : "+v"(pk[4]), "+v"(pk[6]));
        asm volatile("v_permlane32_swap_b32 %0, %1" : "+v"(pk[5]), "+v"(pk[7]));
        short8 pB0, pB1;
        ((u32*)&pB0)[0] = pk[0]; ((u32*)&pB0)[1] = pk[1];
        ((u32*)&pB0)[2] = pk[2]; ((u32*)&pB0)[3] = pk[3];
        ((u32*)&pB1)[0] = pk[4]; ((u32*)&pB1)[1] = pk[5];
        ((u32*)&pB1)[2] = pk[6]; ((u32*)&pB1)[3] = pk[7];
        const int voff = ((h * 32 + lq) << 11) + kbase + hi * 8;
        const short8 vf0 = *(const short8*)&vt[voff];
        const short8 vf1 = *(const short8*)&vt[voff + 16];
        acc = __builtin_amdgcn_mfma_f32_32x32x16_bf16(vf0, pB0, acc, 0, 0, 0);
        acc = __builtin_amdgcn_mfma_f32_32x32x16_bf16(vf1, pB1, acc, 0, 0, 0);
    }

    if (wv) {
        if (l < 32) { Mm[wv - 1][l] = m; Ml[wv - 1][l] = lsum; }
        #pragma unroll
        for (int i = 0; i < 16; ++i) Macc[wv - 1][l][i] = acc[i];
    }
    __syncthreads();
    if (wv == 0) {
        float M = m;
        #pragma unroll
        for (int w = 0; w < 7; ++w) M = fmaxf(M, Mm[w][lq]);
        const float f0 = __builtin_amdgcn_exp2f(m - M);
        float den = lsum * f0;
        float o[16];
        #pragma unroll
        for (int i = 0; i < 16; ++i) o[i] = acc[i] * f0;
        #pragma unroll
        for (int w = 0; w < 7; ++w) {
            const float fw = __builtin_amdgcn_exp2f(Mm[w][lq] - M);
            den += Ml[w][lq] * fw;
            #pragma unroll
            for (int i = 0; i < 16; ++i) o[i] += Macc[w][l][i] * fw;
        }
        const float inv = 1.f / den;
        #pragma unroll
        for (int i = 0; i < 16; ++i)
            ctile[(i & 3) + 8 * (i >> 2) + 4 * hi][lq] = o[i] * inv;
    }
    __syncthreads();
    if (threadIdx.x < 256) {
        const int t = threadIdx.x;
        const int q = t >> 3, d0 = (t & 7) << 2;
        float4 ov;
        ov.x = ctile[d0 + 0][q]; ov.y = ctile[d0 + 1][q];
        ov.z = ctile[d0 + 2][q]; ov.w = ctile[d0 + 3][q];
        *(float4*)&ctx[(long)(qt * 32 + q) * 512 + h * 32 + d0] = ov;
    }
}

// ===========================================================================
// Aggregation GEMM with LN3 fused on A (=xg1, no relu): y<8 -> t tile;
// y==8 -> gate fully in-register (no atomics; flash merge downstream).
// ===========================================================================
__global__ __launch_bounds__(64) void aggr_gemm_kernel(
    const float* __restrict__ xg1,
    const ushort* __restrict__ bt_hi, const ushort* __restrict__ bt_lo,
    const float* __restrict__ ln_g, const float* __restrict__ ln_b,
    const float* __restrict__ tr_b, const float* __restrict__ g_b1,
    const float* __restrict__ g_w2, const float* __restrict__ g_b2,
    float* __restrict__ t_out, float* __restrict__ gv)
{
    const int l = threadIdx.x;
    const int lr = l & 15, lg = l >> 4;
    const int row0 = blockIdx.x * 16;
    const int gate = (blockIdx.y == 8);
    const int slot = gate ? 14 : 15;
    const int col0 = gate ? 0 : blockIdx.y * 32;
    const int NF = gate ? 8 : 2;
    const ushort* bh0 = bt_hi + (long)slot * 65536;
    const ushort* bl0 = bt_lo + (long)slot * 65536;
    const float* arow = xg1 + (long)(row0 + lr) * 256;

    float s = 0.f, s2 = 0.f;
    #pragma unroll
    for (int ks = 0; ks < 8; ++ks) {
        const float4 a0 = *(const float4*)&arow[ks * 32 + lg * 8];
        const float4 a1 = *(const float4*)&arow[ks * 32 + lg * 8 + 4];
        s  += (a0.x + a0.y) + (a0.z + a0.w) + (a1.x + a1.y) + (a1.z + a1.w);
        s2 += a0.x * a0.x + a0.y * a0.y + a0.z * a0.z + a0.w * a0.w +
              a1.x * a1.x + a1.y * a1.y + a1.z * a1.z + a1.w * a1.w;
    }
    s += __shfl_xor(s, 16);  s += __shfl_xor(s, 32);
    s2 += __shfl_xor(s2, 16); s2 += __shfl_xor(s2, 32);
    const float mean = s * (1.f / 256.f);
    const float rs = rsqrtf(s2 * (1.f / 256.f) - mean * mean + 1e-5f);

    const f32x4 z4 = {0.f, 0.f, 0.f, 0.f};
    f32x4 acc[8] = {z4, z4, z4, z4, z4, z4, z4, z4};

    #pragma unroll
    for (int ks = 0; ks < 8; ++ks) {
        const int k0 = ks * 32;
        float av[8], gvv[8], bvv[8];
        *(float4*)&av[0] = *(const float4*)&arow[k0 + lg * 8];
        *(float4*)&av[4] = *(const float4*)&arow[k0 + lg * 8 + 4];
        *(float4*)&gvv[0] = *(const float4*)&ln_g[k0 + lg * 8];
        *(float4*)&gvv[4] = *(const float4*)&ln_g[k0 + lg * 8 + 4];
        *(float4*)&bvv[0] = *(const float4*)&ln_b[k0 + lg * 8];
        *(float4*)&bvv[4] = *(const float4*)&ln_b[k0 + lg * 8 + 4];
        short8 ahi, alo;
        #pragma unroll
        for (int j = 0; j < 8; ++j) {
            const float vn = (av[j] - mean) * rs * gvv[j] + bvv[j];
            const u32 bi = __float_as_uint(vn);
            ahi[j] = (short)(bi >> 16);
            const float fh = __uint_as_float(bi & 0xffff0000u);
            alo[j] = (short)f2bf(vn - fh);
        }
        for (int f = 0; f < NF; ++f) {
            // fragment-major: cb = gate ? f : by*2+f
            const int cb = gate ? f : ((int)blockIdx.y * 2 + f);
            const long bo = (long)((cb * 8 + ks) << 9) + (l << 3);
            const short8 bhi = *(const short8*)&bh0[bo];
            const short8 blo = *(const short8*)&bl0[bo];
            acc[f] = __builtin_amdgcn_mfma_f32_16x16x32_bf16(ahi, bhi, acc[f], 0, 0, 0);
            acc[f] = __builtin_amdgcn_mfma_f32_16x16x32_bf16(alo, bhi, acc[f], 0, 0, 0);
            acc[f] = __builtin_amdgcn_mfma_f32_16x16x32_bf16(ahi, blo, acc[f], 0, 0, 0);
        }
    }

    if (!gate) {
        #pragma unroll
        for (int f = 0; f < 2; ++f) {
            const int col = col0 + f * 16 + lr;
            const float bv = tr_b[col];
            #pragma unroll
            for (int r = 0; r < 4; ++r) {
                const int rr = row0 + lg * 4 + r;
                t_out[(long)rr * 256 + col] = fmaxf(acc[f][r] + bv, 0.f);
            }
        }
    } else {
        float b1v[8], w2v[8];
        #pragma unroll
        for (int f = 0; f < 8; ++f) {
            b1v[f] = g_b1[f * 16 + lr];
            w2v[f] = g_w2[f * 16 + lr];
        }
        const float b2 = g_b2[0];
        #pragma unroll
        for (int r = 0; r < 4; ++r) {
            float t = 0.f;
            #pragma unroll
            for (int f = 0; f < 8; ++f)
                t += fmaxf(acc[f][r] + b1v[f], 0.f) * w2v[f];
            #pragma unroll
            for (int o = 1; o < 16; o <<= 1) t += __shfl_xor(t, o);
            if (lr == 0) gv[row0 + lg * 4 + r] = t + b2;
        }
    }
}

// partial[b][col] = sum over 32 rows of exp(g - M_b) * t[r][col]; per-block
// local max M_b + exp-sum (flash-style; merged exactly in head2).
__global__ __launch_bounds__(256) void wsum_part_kernel(
    const float* __restrict__ gv, const float* __restrict__ t,
    float* __restrict__ partial, float* __restrict__ denp, float* __restrict__ mpart)
{
    const float L2E = 1.4426950408889634f;
    const int b = blockIdx.x, tid = threadIdx.x;
    float M = -INFINITY;
    #pragma unroll
    for (int i = 0; i < 32; ++i) M = fmaxf(M, gv[b * 32 + i]);
    float s = 0.f, den = 0.f;
    #pragma unroll 4
    for (int i = 0; i < 32; ++i) {
        const int r = b * 32 + i;
        const float w = __builtin_amdgcn_exp2f((gv[r] - M) * L2E);
        den += w;
        s += w * t[(long)r * 256 + tid];
    }
    partial[b * 256 + tid] = s;
    if (tid == 0) { denp[b] = den; mpart[b] = M; }
}

// flash-merge 64 blocks, then out = pooled @ head_w + head_b
__global__ __launch_bounds__(256) void head2_kernel(
    const float* __restrict__ partial, const float* __restrict__ denp,
    const float* __restrict__ mpart, const float* __restrict__ hw,
    const float* __restrict__ hb, float* __restrict__ out)
{
    __shared__ float fb[64];
    __shared__ float dtot;
    __shared__ float red0[4], red1[4];
    const float L2E = 1.4426950408889634f;
    const int tid = threadIdx.x;
    if (tid < 64) {
        const float mb = mpart[tid];
        float M = mb;
        #pragma unroll
        for (int o = 1; o < 64; o <<= 1) M = fmaxf(M, __shfl_xor(M, o));
        const float f = __builtin_amdgcn_exp2f((mb - M) * L2E);
        fb[tid] = f;
        float dv = f * denp[tid];
        #pragma unroll
        for (int o = 1; o < 64; o <<= 1) dv += __shfl_xor(dv, o);
        if (tid == 0) dtot = dv;
    }
    __syncthreads();
    float p = 0.f;
    #pragma unroll 8
    for (int b = 0; b < 64; ++b) p += fb[b] * partial[b * 256 + tid];
    p /= dtot;
    float s0 = p * hw[tid * 2 + 0];
    float s1 = p * hw[tid * 2 + 1];
    #pragma unroll
    for (int o = 1; o < 64; o <<= 1) { s0 += __shfl_xor(s0, o); s1 += __shfl_xor(s1, o); }
    if ((tid & 63) == 0) { red0[tid >> 6] = s0; red1[tid >> 6] = s1; }
    __syncthreads();
    if (tid == 0) {
        out[0] = red0[0] + red0[1] + red0[2] + red0[3] + hb[0];
        out[1] = red1[0] + red1[1] + red1[2] + red1[3] + hb[1];
    }
}

// ---------------------------------------------------------------------------
extern "C" void kernel_launch(void* const* d_in, const int* in_sizes, int n_in,
                              void* d_out, int out_size, void* d_ws, size_t ws_size,
                              hipStream_t stream)
{
    (void)in_sizes; (void)n_in; (void)out_size; (void)ws_size;
    const float* gene_emb = (const float*)d_in[0];
    const float* pre_w1   = (const float*)d_in[3];
    const float* pre_b1   = (const float*)d_in[4];
    const float* pre_w2   = (const float*)d_in[5];
    const float* pre_b2   = (const float*)d_in[6];
    const float* pre_ln_g = (const float*)d_in[7];
    const float* pre_ln_b = (const float*)d_in[8];
    const float* wm       = (const float*)d_in[9];
    const float* wsw      = (const float*)d_in[10];
    const float* ln_g     = (const float*)d_in[11];
    const float* ln_b     = (const float*)d_in[12];
    const float* gate_w1  = (const float*)d_in[13];
    const float* gate_b1  = (const float*)d_in[14];
    const float* gate_w2  = (const float*)d_in[15];
    const float* gate_b2  = (const float*)d_in[16];
    const float* tr_w     = (const float*)d_in[17];
    const float* tr_b     = (const float*)d_in[18];
    const float* head_w   = (const float*)d_in[19];
    const float* head_b   = (const float*)d_in[20];
    const u8* adj_pp      = (const u8*)d_in[21];
    const u8* adj_rr      = (const u8*)d_in[22];
    // d_in[1],[2],[23],[24] dead (reaction/metab branches never reach output)

    const long NHf = (long)Gn * Hd;
    float* tmp0    = (float*)d_ws;
    float* tmp1    = tmp0 + NHf;
    float* xg1     = tmp1 + NHf;
    float* ctx2    = xg1 + NHf;
    float* gv      = ctx2 + 2 * NHf;
    float* partial = gv + Gn;
    float* denp    = partial + 64 * 256;
    float* mpart   = denp + 64;
    int* det0      = (int*)(mpart + 64);
    int* det1      = det0 + 64;
    int* deg       = det1 + 64;
    int* colidx    = deg + 4096;
    u32* bits      = (u32*)(colidx + 2L * 2048 * CSTRIDE);
    ushort* qkvb   = (ushort*)(bits + 262144);
    ushort* bt_hi  = qkvb + 2L * 1572864;
    ushort* bt_lo  = bt_hi + 16L * 65536;

    dim3 B256(256), B128(128), T64(64);

    // 1: detect || weight pre-split (fragment-major arenas)
    mergedA_kernel<<<dim3(192), B256, 0, stream>>>(adj_pp, det0, det1,
        pre_w1, pre_w2, wm, wsw, gate_w1, tr_w, bt_hi, bt_lo);
    // 2: pack masks || preGEMM1
    mergedB_kernel<<<dim3(2304), B128, 0, stream>>>(adj_pp, adj_rr, det0, det1,
        bits, gene_emb, bt_hi, bt_lo, pre_b1, tmp0);
    // 3: CSR || preGEMM2 (LN1+relu fused)
    mergedC_kernel<<<dim3(288), B128, 0, stream>>>(bits, deg, colidx, tmp0,
        bt_hi, bt_lo, pre_b2, pre_ln_g, pre_ln_b, tmp1);
    // 4: QKV-M (LN2+relu fused; writes xg1)
    qkvm_kernel<<<dim3(64, 4, 6), B128, 0, stream>>>(tmp1, bt_hi, bt_lo,
        pre_ln_g, pre_ln_b, (float*)qkvb, xg1);
    // 5: sparse masked attention
    attn_sparse_kernel<<<dim3(2048, 2), T64, 0, stream>>>(qkvb, deg, colidx, ctx2);
    // 6: fused dual-Wo (K=512)
    wo_m_kernel<<<dim3(64, 4), B128, 0, stream>>>(ctx2, bt_hi, bt_lo, xg1);
    // 7: QKV-S
    qkvs_kernel<<<dim3(64, 4, 3), B128, 0, stream>>>(xg1, bt_hi, bt_lo, (float*)qkvb);
    // 8: dense self-attention
    attn_dense_kernel<<<dim3(8, 64), dim3(512), 0, stream>>>(qkvb, ctx2);
    // 9: Wo-S
    wo_s_kernel<<<dim3(64, 4), B128, 0, stream>>>(ctx2, bt_hi, bt_lo, xg1);
    // 10: aggregation GEMM (LN3 fused)
    aggr_gemm_kernel<<<dim3(128, 9), T64, 0, stream>>>(xg1, bt_hi, bt_lo,
        ln_g, ln_b, tr_b, gate_b1, gate_w2, gate_b2, tmp0, gv);
    // 11: weighted sum
    wsum_part_kernel<<<dim3(64), B256, 0, stream>>>(gv, tmp0, partial, denp, mpart);
    // 12: merge + head
    head2_kernel<<<dim3(1), B256, 0, stream>>>(partial, denp, mpart, head_w, head_b, (float*)d_out);
}

// Round 12
// 186.045 us; speedup vs baseline: 1.8513x; 1.0309x over previous
//
#include <hip/hip_runtime.h>
#include <hip/hip_bf16.h>
#include <cmath>
#include <cstdint>

typedef unsigned int u32;
typedef unsigned char u8;
typedef unsigned short ushort;
typedef __attribute__((ext_vector_type(8))) short short8;
typedef __attribute__((ext_vector_type(4))) float f32x4;
typedef __attribute__((ext_vector_type(16))) float f32x16;
typedef __attribute__((ext_vector_type(4))) unsigned short us4;

#define Gn 2048
#define Hd 256
#define CSTRIDE 192

static __device__ __forceinline__ ushort f2bf(float x) {
    __hip_bfloat16 b = __float2bfloat16(x);
    return *reinterpret_cast<ushort*>(&b);
}
static __device__ __forceinline__ float bf2f(ushort u) {
    return __uint_as_float(((u32)u) << 16);
}

// ===========================================================================
// Weight arenas are FRAGMENT-MAJOR: element (col,k) of W^T lives at
// slot*65536 + ((col>>4)*8 + (k>>5))*512 + (((k&31)>>3)*16 + (col&15))*8
// + (k&7). A wave's MFMA B-fragment (16 cols x 32 k) is one contiguous 1KB
// burst: lane l reads [base + l*8 .. +8).
// ===========================================================================

// ===========================================================================
// GEMM body: bf16x3 split-precision MFMA, 32x64 tile, 2 waves.
// LNF: LayerNorm(+LNRELU) applied to A rows on the fly (exact fp32).
// WRA: (by==0 && bz==0) blocks write normalized A rows to Aout.
// OUTMODE 1 = QKV bf16 epilogue (Q pre-scaled 1/sqrt(32)*log2e).
// QKVMODE 1 (M): V row-layout; QKVMODE 2 (S): V transposed.
// KT=512: ks>=8 reads slot2 arena (fused dual-Wo accumulate).
// ===========================================================================
template <int BETA, int OUTMODE, int QKVMODE, int KT, int LNF, int LNRELU, int WRA>
static __device__ __forceinline__ void gemm_body(
    const int bx, const int by, const int bz,
    const float* __restrict__ A, int lda,
    const ushort* __restrict__ bt_hi, const ushort* __restrict__ bt_lo,
    int slot0, int slot2, const float* __restrict__ bias,
    const float* __restrict__ lng, const float* __restrict__ lnb,
    float* __restrict__ C, int N, float* __restrict__ Aout)
{
    const int tid = threadIdx.x;
    const int wv = tid >> 6, l = tid & 63;
    const int lr = l & 15, lg = l >> 4;
    const int row = bx * 32 + wv * 16 + lr;
    const int col0 = by * 64;
    int slot = slot0, zq = 0, buf = 0;
    if (QKVMODE == 1) { slot = slot0 + bz + bz / 3; zq = bz % 3; buf = bz / 3; }
    else if (QKVMODE == 2) { slot = slot0 + bz; zq = bz; }
    const ushort* bhb = bt_hi + (long)slot * 65536;
    const ushort* blb = bt_lo + (long)slot * 65536;
    const float* arow = A + (long)row * lda;

    float mean = 0.f, rs = 0.f;
    if (LNF) {
        float s = 0.f, s2 = 0.f;
        #pragma unroll
        for (int ks = 0; ks < 8; ++ks) {
            const float4 a0 = *(const float4*)&arow[ks * 32 + lg * 8];
            const float4 a1 = *(const float4*)&arow[ks * 32 + lg * 8 + 4];
            s  += (a0.x + a0.y) + (a0.z + a0.w) + (a1.x + a1.y) + (a1.z + a1.w);
            s2 += a0.x * a0.x + a0.y * a0.y + a0.z * a0.z + a0.w * a0.w +
                  a1.x * a1.x + a1.y * a1.y + a1.z * a1.z + a1.w * a1.w;
        }
        s += __shfl_xor(s, 16);  s += __shfl_xor(s, 32);
        s2 += __shfl_xor(s2, 16); s2 += __shfl_xor(s2, 32);
        mean = s * (1.f / 256.f);
        rs = rsqrtf(s2 * (1.f / 256.f) - mean * mean + 1e-5f);
    }

    const f32x4 z4 = {0.f, 0.f, 0.f, 0.f};
    f32x4 acc[4] = {z4, z4, z4, z4};

    #pragma unroll
    for (int ks = 0; ks < KT / 32; ++ks) {
        const int k0 = ks * 32;
        const ushort* bh; const ushort* bl; int kbi = ks;
        if (KT == 512 && k0 >= 256) {
            bh = bt_hi + (long)slot2 * 65536;
            bl = bt_lo + (long)slot2 * 65536;
            kbi = ks - 8;
        } else { bh = bhb; bl = blb; }
        float av[8];
        *(float4*)&av[0] = *(const float4*)&arow[k0 + lg * 8];
        *(float4*)&av[4] = *(const float4*)&arow[k0 + lg * 8 + 4];
        if (LNF) {
            float gvv[8], bvv[8];
            *(float4*)&gvv[0] = *(const float4*)&lng[k0 + lg * 8];
            *(float4*)&gvv[4] = *(const float4*)&lng[k0 + lg * 8 + 4];
            *(float4*)&bvv[0] = *(const float4*)&lnb[k0 + lg * 8];
            *(float4*)&bvv[4] = *(const float4*)&lnb[k0 + lg * 8 + 4];
            #pragma unroll
            for (int j = 0; j < 8; ++j) {
                float v = (av[j] - mean) * rs * gvv[j] + bvv[j];
                if (LNRELU) v = fmaxf(v, 0.f);
                av[j] = v;
            }
            if (WRA && by == 0 && bz == 0) {
                *(float4*)&Aout[(long)row * 256 + k0 + lg * 8] = *(float4*)&av[0];
                *(float4*)&Aout[(long)row * 256 + k0 + lg * 8 + 4] = *(float4*)&av[4];
            }
        }
        short8 ahi, alo;
        #pragma unroll
        for (int j = 0; j < 8; ++j) {
            const u32 bi = __float_as_uint(av[j]);
            ahi[j] = (short)(bi >> 16);
            const float fh = __uint_as_float(bi & 0xffff0000u);
            alo[j] = (short)f2bf(av[j] - fh);
        }
        #pragma unroll
        for (int f = 0; f < 4; ++f) {
            const long bo = (long)(((by * 4 + f) * 8 + kbi) << 9) + (l << 3);
            const short8 bhi = *(const short8*)&bh[bo];
            const short8 blo = *(const short8*)&bl[bo];
            acc[f] = __builtin_amdgcn_mfma_f32_16x16x32_bf16(ahi, bhi, acc[f], 0, 0, 0);
            acc[f] = __builtin_amdgcn_mfma_f32_16x16x32_bf16(alo, bhi, acc[f], 0, 0, 0);
            acc[f] = __builtin_amdgcn_mfma_f32_16x16x32_bf16(ahi, blo, acc[f], 0, 0, 0);
        }
    }

    const float QS = 0.17677669529663687f * 1.4426950408889634f;

    #pragma unroll
    for (int f = 0; f < 4; ++f) {
        const int col = col0 + f * 16 + lr;
        const float bv = bias ? bias[col] : 0.f;
        #pragma unroll
        for (int r = 0; r < 4; ++r) {
            const int rr = bx * 32 + wv * 16 + lg * 4 + r;
            float v = acc[f][r] + bv;
            if (OUTMODE == 1) {
                if (zq == 0) v *= QS;
                ushort* ob = (ushort*)C + (long)buf * 1572864;
                const int h = col >> 5, d = col & 31;
                if (QKVMODE == 1 || zq < 2)
                    ob[zq * 524288 + ((h * 2048 + rr) << 5) + d] = f2bf(v);
                else
                    ob[1048576 + ((h * 32 + d) << 11) + rr] = f2bf(v);
            } else {
                if (BETA) v += C[(long)rr * N + col];
                C[(long)rr * N + col] = v;
            }
        }
    }
}

// ===========================================================================
// Merged A (256 thr, grid 192): blocks 0-63 mask-dtype detect; blocks 64-191
// weight pre-split (fragment-major). Block 0 also zeroes the wsum ticket.
// ===========================================================================
__global__ __launch_bounds__(256) void mergedA_kernel(
    const u8* __restrict__ adj, int* __restrict__ det0, int* __restrict__ det1,
    const float* __restrict__ pre_w1, const float* __restrict__ pre_w2,
    const float* __restrict__ wm, const float* __restrict__ wsw,
    const float* __restrict__ gate_w1, const float* __restrict__ tr_w,
    ushort* __restrict__ bt_hi, ushort* __restrict__ bt_lo,
    u32* __restrict__ ticket)
{
    __shared__ float T[32][257];
    __shared__ int sd0[4], sd1[4];
    const int tid = threadIdx.x;
    if (blockIdx.x == 0 && tid == 0) *ticket = 0;
    if (blockIdx.x < 64) {
        const int idx = blockIdx.x * 256 + tid;
        const uint4 w = ((const uint4*)adj)[idx];
        int c0 = ((w.x & 0xffu) ? 1 : 0) + ((w.y & 0xffu) ? 1 : 0) +
                 ((w.z & 0xffu) ? 1 : 0) + ((w.w & 0xffu) ? 1 : 0);
        int c1 = ((w.x & 0xffffff00u) ? 1 : 0) + ((w.y & 0xffffff00u) ? 1 : 0) +
                 ((w.z & 0xffffff00u) ? 1 : 0) + ((w.w & 0xffffff00u) ? 1 : 0);
        #pragma unroll
        for (int o = 1; o < 64; o <<= 1) { c0 += __shfl_xor(c0, o); c1 += __shfl_xor(c1, o); }
        if ((tid & 63) == 0) { sd0[tid >> 6] = c0; sd1[tid >> 6] = c1; }
        __syncthreads();
        if (tid == 0) {
            det0[blockIdx.x] = sd0[0] + sd0[1] + sd0[2] + sd0[3];
            det1[blockIdx.x] = sd1[0] + sd1[1] + sd1[2] + sd1[3];
        }
        return;
    }
    const int b2 = blockIdx.x - 64;
    const int slot = b2 >> 3;
    const int kb = b2 & 7;
    const int k0 = kb * 32;
    const float* src; int ncols = 256;
    if (slot == 0) src = pre_w1;
    else if (slot == 1) src = pre_w2;
    else if (slot < 6) src = wm + (long)(slot - 2) * 65536;
    else if (slot < 10) src = wm + (long)(4 + slot - 6) * 65536;
    else if (slot < 14) src = wsw + (long)(slot - 10) * 65536;
    else if (slot == 14) { src = gate_w1; ncols = 128; }
    else src = tr_w;

    const int lsh = (ncols == 256) ? 6 : 5;
    const int tot = 32 << lsh;
    for (int i = tid; i < tot; i += 256) {
        const int kk = i >> lsh, c4 = (i & ((1 << lsh) - 1)) << 2;
        const float4 v = *(const float4*)&src[(long)(k0 + kk) * ncols + c4];
        T[kk][c4 + 0] = v.x; T[kk][c4 + 1] = v.y;
        T[kk][c4 + 2] = v.z; T[kk][c4 + 3] = v.w;
    }
    __syncthreads();
    if (tid < ncols) {
        ushort hb[32], lb[32];
        #pragma unroll
        for (int kk = 0; kk < 32; ++kk) {
            const float x = T[kk][tid];
            const u32 bi = __float_as_uint(x);
            const ushort h = (ushort)(bi >> 16);
            const float fh = __uint_as_float(bi & 0xffff0000u);
            hb[kk] = h; lb[kk] = f2bf(x - fh);
        }
        const int cb = tid >> 4, lr = tid & 15;
        const long base = (long)slot * 65536 + ((cb * 8 + kb) << 9);
        ushort* oh = bt_hi + base;
        ushort* ol = bt_lo + base;
        #pragma unroll
        for (int lg2 = 0; lg2 < 4; ++lg2) {
            const int off = (lg2 * 16 + lr) << 3;
            *(uint4*)&oh[off] = *(const uint4*)&hb[lg2 * 8];
            *(uint4*)&ol[off] = *(const uint4*)&lb[lg2 * 8];
        }
    }
}

// ===========================================================================
// Merged B (128 thr, grid 2304): blocks 0-2047 pack masks AND build CSR for
// their 2 rows (LDS-staged words; threads 0-1 enumerate after barrier);
// blocks 2048-2303 preGEMM1 (tmp0 = gene_emb @ pre_w1 + b1).
// ===========================================================================
__global__ __launch_bounds__(128) void mergedB_kernel(
    const u8* __restrict__ src0, const u8* __restrict__ src1,
    const int* __restrict__ det0, const int* __restrict__ det1,
    u32* __restrict__ bits, int* __restrict__ deg, int* __restrict__ colidx,
    const float* __restrict__ gene_emb,
    const ushort* __restrict__ bt_hi, const ushort* __restrict__ bt_lo,
    const float* __restrict__ pre_b1, float* __restrict__ tmp0)
{
    __shared__ u32 sw[128];
    const int tid = threadIdx.x;
    if (blockIdx.x < 2048) {
        const int lane = tid & 63;
        int c0 = det0[lane], c1 = det1[lane];
        #pragma unroll
        for (int o = 1; o < 64; o <<= 1) { c0 += __shfl_xor(c0, o); c1 += __shfl_xor(c1, o); }
        const int f = (c0 > 0) ? ((c1 > 0) ? 1 : 0) : 2;
        const int W = blockIdx.x * 128 + tid;
        const int z = W >> 17;
        const int rem = W & 131071;
        const int row = rem >> 6, w = rem & 63;
        const u8* src = z ? src1 : src0;
        u32 v = 0;
        if (f == 1) {
            const uint4* p = (const uint4*)(src + (long)row * 2048 + w * 32);
            const uint4 q0 = p[0], q1 = p[1];
            const u32 ws8[8] = {q0.x, q0.y, q0.z, q0.w, q1.x, q1.y, q1.z, q1.w};
            #pragma unroll
            for (int j = 0; j < 8; ++j) {
                const u32 x = ws8[j];
                const u32 m = (((x & 0x7f7f7f7fu) + 0x7f7f7f7fu) | x) & 0x80808080u;
                const u32 b4 = ((m >> 7) & 1u) | ((m >> 14) & 2u) |
                               ((m >> 21) & 4u) | ((m >> 28) & 8u);
                v |= b4 << (j * 4);
            }
        } else if (f == 0) {
            const uint4* p = (const uint4*)((const int*)src + (long)row * 2048 + w * 32);
            #pragma unroll
            for (int j = 0; j < 8; ++j) {
                const uint4 q = p[j];
                v |= (q.x ? 1u : 0u) << (j * 4 + 0);
                v |= (q.y ? 1u : 0u) << (j * 4 + 1);
                v |= (q.z ? 1u : 0u) << (j * 4 + 2);
                v |= (q.w ? 1u : 0u) << (j * 4 + 3);
            }
        } else {
            const uint4* p = (const uint4*)((const float*)src + (long)row * 2048 + w * 32);
            #pragma unroll
            for (int j = 0; j < 8; ++j) {
                const uint4 q = p[j];
                v |= ((q.x & 0x7fffffffu) ? 1u : 0u) << (j * 4 + 0);
                v |= ((q.y & 0x7fffffffu) ? 1u : 0u) << (j * 4 + 1);
                v |= ((q.z & 0x7fffffffu) ? 1u : 0u) << (j * 4 + 2);
                v |= ((q.w & 0x7fffffffu) ? 1u : 0u) << (j * 4 + 3);
            }
        }
        bits[(long)z * 131072 + rem] = v;
        sw[tid] = v;
        __syncthreads();
        if (tid < 2) {
            const int rem0 = (blockIdx.x * 128) & 131071;
            const int r = (rem0 >> 6) + tid;
            int* ci = colidx + ((long)z * 2048 + r) * CSTRIDE;
            int d = 0;
            #pragma unroll 4
            for (int ww = 0; ww < 64; ++ww) {
                u32 x = sw[tid * 64 + ww];
                while (x) {
                    const int j = __ffs(x) - 1;
                    if (d < CSTRIDE) ci[d] = ww * 32 + j;
                    ++d;
                    x &= x - 1;
                }
            }
            deg[z * 2048 + r] = d < CSTRIDE ? d : CSTRIDE;
        }
        return;
    }
    const int b2 = blockIdx.x - 2048;
    gemm_body<0, 0, 0, 256, 0, 0, 0>(b2 >> 2, b2 & 3, 0, gene_emb, 256,
                                     bt_hi, bt_lo, 0, 0, pre_b1,
                                     nullptr, nullptr, tmp0, 256, nullptr);
}

// ===========================================================================
// Merged C (128 thr, grid 256): pure preGEMM2 with LN1+relu fused on A
// (tmp1 = relu(LN(tmp0))@w2+b2).  (CSR moved into mergedB.)
// ===========================================================================
__global__ __launch_bounds__(128) void mergedC_kernel(
    const float* __restrict__ tmp0,
    const ushort* __restrict__ bt_hi, const ushort* __restrict__ bt_lo,
    const float* __restrict__ pre_b2, const float* __restrict__ pre_ln_g,
    const float* __restrict__ pre_ln_b, float* __restrict__ tmp1)
{
    const int b2 = blockIdx.x;
    gemm_body<0, 0, 0, 256, 1, 1, 0>(b2 >> 2, b2 & 3, 0, tmp0, 256,
                                     bt_hi, bt_lo, 1, 0, pre_b2,
                                     pre_ln_g, pre_ln_b, tmp1, 256, nullptr);
}

// GEMM wrappers ------------------------------------------------------------
__global__ __launch_bounds__(128) void qkvm_kernel(
    const float* __restrict__ tmp1,
    const ushort* __restrict__ bt_hi, const ushort* __restrict__ bt_lo,
    const float* __restrict__ pre_ln_g, const float* __restrict__ pre_ln_b,
    float* __restrict__ qkvb, float* __restrict__ xg1)
{
    gemm_body<0, 1, 1, 256, 1, 1, 1>(blockIdx.x, blockIdx.y, blockIdx.z,
                                     tmp1, 256, bt_hi, bt_lo, 2, 0, nullptr,
                                     pre_ln_g, pre_ln_b, qkvb, 256, xg1);
}
__global__ __launch_bounds__(128) void wo_m_kernel(
    const float* __restrict__ ctx2,
    const ushort* __restrict__ bt_hi, const ushort* __restrict__ bt_lo,
    float* __restrict__ xg1)
{
    gemm_body<1, 0, 0, 512, 0, 0, 0>(blockIdx.x, blockIdx.y, 0, ctx2, 512,
                                     bt_hi, bt_lo, 5, 9, nullptr,
                                     nullptr, nullptr, xg1, 256, nullptr);
}
__global__ __launch_bounds__(128) void qkvs_kernel(
    const float* __restrict__ xg1,
    const ushort* __restrict__ bt_hi, const ushort* __restrict__ bt_lo,
    float* __restrict__ qkvb)
{
    gemm_body<0, 1, 2, 256, 0, 0, 0>(blockIdx.x, blockIdx.y, blockIdx.z,
                                     xg1, 256, bt_hi, bt_lo, 10, 0, nullptr,
                                     nullptr, nullptr, qkvb, 256, nullptr);
}
__global__ __launch_bounds__(128) void wo_s_kernel(
    const float* __restrict__ ctx2,
    const ushort* __restrict__ bt_hi, const ushort* __restrict__ bt_lo,
    float* __restrict__ xg1)
{
    gemm_body<1, 0, 0, 256, 0, 0, 0>(blockIdx.x, blockIdx.y, 0, ctx2, 512,
                                     bt_hi, bt_lo, 13, 0, nullptr,
                                     nullptr, nullptr, xg1, 256, nullptr);
}

// ===========================================================================
// Sparse masked attention (M block), exp2 domain. One wave per (row, graph).
// ===========================================================================
__global__ __launch_bounds__(64) void attn_sparse_kernel(
    const ushort* __restrict__ qkvb, const int* __restrict__ deg,
    const int* __restrict__ colidx, float* __restrict__ ctx)
{
    const int r = blockIdx.x, z = blockIdx.y;
    const ushort* qb = qkvb + (long)z * 1572864;
    const ushort* kb = qb + 524288;
    const ushort* vr = qb + 1048576;
    const int l = threadIdx.x;
    const int h = l >> 3, dg = l & 7;
    float* orow = &ctx[(long)r * 512 + z * 256 + h * 32 + dg * 4];
    const int n = deg[z * 2048 + r];
    if (n == 0) {
        float a0 = 0.f, a1 = 0.f, a2 = 0.f, a3 = 0.f;
        for (int k = 0; k < 2048; ++k) {
            const us4 vv = *(const us4*)&vr[((h * 2048 + k) << 5) + dg * 4];
            a0 += bf2f(vv[0]); a1 += bf2f(vv[1]); a2 += bf2f(vv[2]); a3 += bf2f(vv[3]);
        }
        float4 o; const float inv = 1.f / 2048.f;
        o.x = a0 * inv; o.y = a1 * inv; o.z = a2 * inv; o.w = a3 * inv;
        *(float4*)orow = o;
        return;
    }
    float q0, q1, q2, q3;
    {
        const us4 qv = *(const us4*)&qb[((h * 2048 + r) << 5) + dg * 4];
        q0 = bf2f(qv[0]); q1 = bf2f(qv[1]); q2 = bf2f(qv[2]); q3 = bf2f(qv[3]);
    }
    const int* ci = colidx + ((long)z * 2048 + r) * CSTRIDE;
    float m = -INFINITY, lsum = 0.f;
    float a0 = 0.f, a1 = 0.f, a2 = 0.f, a3 = 0.f;
    int kn = ci[0];
    us4 kv = *(const us4*)&kb[((h * 2048 + kn) << 5) + dg * 4];
    us4 vv = *(const us4*)&vr[((h * 2048 + kn) << 5) + dg * 4];
    for (int e = 0; e < n; ++e) {
        const us4 kc = kv, vc = vv;
        if (e + 1 < n) {
            kn = ci[e + 1];
            kv = *(const us4*)&kb[((h * 2048 + kn) << 5) + dg * 4];
            vv = *(const us4*)&vr[((h * 2048 + kn) << 5) + dg * 4];
        }
        float s = q0 * bf2f(kc[0]) + q1 * bf2f(kc[1]) +
                  q2 * bf2f(kc[2]) + q3 * bf2f(kc[3]);
        s += __shfl_xor(s, 1); s += __shfl_xor(s, 2); s += __shfl_xor(s, 4);
        const float mn = fmaxf(m, s);
        const float fac = __builtin_amdgcn_exp2f(m - mn);
        const float p = __builtin_amdgcn_exp2f(s - mn);
        lsum = lsum * fac + p;
        a0 = a0 * fac + p * bf2f(vc[0]);
        a1 = a1 * fac + p * bf2f(vc[1]);
        a2 = a2 * fac + p * bf2f(vc[2]);
        a3 = a3 * fac + p * bf2f(vc[3]);
        m = mn;
    }
    const float inv = 1.f / lsum;
    float4 o; o.x = a0 * inv; o.y = a1 * inv; o.z = a2 * inv; o.w = a3 * inv;
    *(float4*)orow = o;
}

// ===========================================================================
// Dense attention (S block): 32x32x16 swapped MFMA, in-register P via
// cvt_pk_bf16 + permlane32_swap, exp2 domain, k-split x8 (512 threads).
// R12: PARALLEL 8-way merge — all waves dump (m,l,acc) to LDS (acc padded
// [8][64][17] to break the stride-16 bank conflict); 512 threads each merge
// two (q,d) output elements. Replaces the wave0-only serial merge.
// ===========================================================================
__global__ __launch_bounds__(512) void attn_dense_kernel(
    const ushort* __restrict__ qkvb, float* __restrict__ ctx)
{
    const ushort* qb = qkvb;
    const ushort* kb = qb + 524288;
    const ushort* vt = qb + 1048576;
    const int h = blockIdx.x, qt = blockIdx.y;
    const int wv = threadIdx.x >> 6;
    const int l = threadIdx.x & 63;
    const int lq = l & 31;
    const int hi = l >> 5;
    const int qglob = qt * 32 + lq;

    __shared__ float Mm[8][32], Ml[8][32];
    __shared__ float Macc[8][64][17];
    __shared__ float ctile[32][33];

    const int qoff = ((h * 2048 + qglob) << 5) + hi * 8;
    const short8 qf0 = *(const short8*)&qb[qoff];
    const short8 qf1 = *(const short8*)&qb[qoff + 16];

    float m = -INFINITY, lsum = 0.f;
    f32x16 acc, zz16;
    #pragma unroll
    for (int i = 0; i < 16; ++i) { acc[i] = 0.f; zz16[i] = 0.f; }

    const int kt0 = wv * 256;
    #pragma unroll 2
    for (int it = 0; it < 8; ++it) {
        const int kbase = kt0 + it * 32;
        const int koff = ((h * 2048 + kbase + lq) << 5) + hi * 8;
        const short8 kf0 = *(const short8*)&kb[koff];
        const short8 kf1 = *(const short8*)&kb[koff + 16];
        f32x16 s = __builtin_amdgcn_mfma_f32_32x32x16_bf16(kf0, qf0, zz16, 0, 0, 0);
        s = __builtin_amdgcn_mfma_f32_32x32x16_bf16(kf1, qf1, s, 0, 0, 0);
        float sc[16];
        #pragma unroll
        for (int i = 0; i < 16; ++i) sc[i] = s[i];
        float t[8];
        #pragma unroll
        for (int i = 0; i < 8; ++i) t[i] = fmaxf(sc[i], sc[i + 8]);
        #pragma unroll
        for (int i = 0; i < 4; ++i) t[i] = fmaxf(t[i], t[i + 4]);
        float mt = fmaxf(fmaxf(t[0], t[1]), fmaxf(t[2], t[3]));
        mt = fmaxf(mt, __shfl_xor(mt, 32));
        const float mn = fmaxf(m, mt);
        if (__ballot(mn != m)) {
            const float fac = __builtin_amdgcn_exp2f(m - mn);
            lsum *= fac;
            #pragma unroll
            for (int i = 0; i < 16; ++i) acc[i] *= fac;
            m = mn;
        }
        #pragma unroll
        for (int i = 0; i < 16; ++i) sc[i] = __builtin_amdgcn_exp2f(sc[i] - m);
        #pragma unroll
        for (int i = 0; i < 8; ++i) t[i] = sc[i] + sc[i + 8];
        #pragma unroll
        for (int i = 0; i < 4; ++i) t[i] = t[i] + t[i + 4];
        float ps = (t[0] + t[1]) + (t[2] + t[3]);
        ps += __shfl_xor(ps, 32);
        lsum += ps;
        u32 pk[8];
        #pragma unroll
        for (int g = 0; g < 4; ++g) {
            asm("v_cvt_pk_bf16_f32 %0, %1, %2"
                : "=v"(pk[2 * g]) : "v"(sc[4 * g + 0]), "v"(sc[4 * g + 1]));
            asm("v_cvt_pk_bf16_f32 %0, %1, %2"
                : "=v"(pk[2 * g + 1]) : "v"(sc[4 * g + 2]), "v"(sc[4 * g + 3]));
        }
        asm volatile("v_permlane32_swap_b32 %0, %1" : "+v"(pk[0]), "+v"(pk[2]));
        asm volatile("v_permlane32_swap_b32 %0, %1" : "+v"(pk[1]), "+v"(pk[3]));
        asm volatile("v_permlane32_swap_b32 %0, %1" : "+v"(pk[4]), "+v"(pk[6]));
        asm volatile("v_permlane32_swap_b32 %0, %1" : "+v"(pk[5]), "+v"(pk[7]));
        short8 pB0, pB1;
        ((u32*)&pB0)[0] = pk[0]; ((u32*)&pB0)[1] = pk[1];
        ((u32*)&pB0)[2] = pk[2]; ((u32*)&pB0)[3] = pk[3];
        ((u32*)&pB1)[0] = pk[4]; ((u32*)&pB1)[1] = pk[5];
        ((u32*)&pB1)[2] = pk[6]; ((u32*)&pB1)[3] = pk[7];
        const int voff = ((h * 32 + lq) << 11) + kbase + hi * 8;
        const short8 vf0 = *(const short8*)&vt[voff];
        const short8 vf1 = *(const short8*)&vt[voff + 16];
        acc = __builtin_amdgcn_mfma_f32_32x32x16_bf16(vf0, pB0, acc, 0, 0, 0);
        acc = __builtin_amdgcn_mfma_f32_32x32x16_bf16(vf1, pB1, acc, 0, 0, 0);
    }

    // ---- parallel merge: all waves dump, 512 threads merge (q, d) pairs
    if (l < 32) { Mm[wv][l] = m; Ml[wv][l] = lsum; }
    #pragma unroll
    for (int i = 0; i < 16; ++i) Macc[wv][l][i] = acc[i];
    __syncthreads();
    {
        const int t = threadIdx.x;
        const int q = t & 31, j = t >> 5;    // j in 0..15
        float M = Mm[0][q];
        #pragma unroll
        for (int w = 1; w < 8; ++w) M = fmaxf(M, Mm[w][q]);
        float fw[8], den = 0.f;
        #pragma unroll
        for (int w = 0; w < 8; ++w) {
            fw[w] = __builtin_amdgcn_exp2f(Mm[w][q] - M);
            den += Ml[w][q] * fw[w];
        }
        const float inv = 1.f / den;
        #pragma unroll
        for (int half = 0; half < 2; ++half) {
            const int d = j + 16 * half;
            const int i = (d & 3) | ((d >> 3) << 2);
            const int h2 = (d >> 2) & 1;
            float o = 0.f;
            #pragma unroll
            for (int w = 0; w < 8; ++w) o += Macc[w][h2 * 32 + q][i] * fw[w];
            ctile[d][q] = o * inv;
        }
    }
    __syncthreads();
    if (threadIdx.x < 256) {
        const int t = threadIdx.x;
        const int q = t >> 3, d0 = (t & 7) << 2;
        float4 ov;
        ov.x = ctile[d0 + 0][q]; ov.y = ctile[d0 + 1][q];
        ov.z = ctile[d0 + 2][q]; ov.w = ctile[d0 + 3][q];
        *(float4*)&ctx[(long)(qt * 32 + q) * 512 + h * 32 + d0] = ov;
    }
}

// ===========================================================================
// Aggregation GEMM with LN3 fused on A (=xg1, no relu): y<8 -> t tile;
// y==8 -> gate fully in-register (no atomics; flash merge downstream).
// ===========================================================================
__global__ __launch_bounds__(64) void aggr_gemm_kernel(
    const float* __restrict__ xg1,
    const ushort* __restrict__ bt_hi, const ushort* __restrict__ bt_lo,
    const float* __restrict__ ln_g, const float* __restrict__ ln_b,
    const float* __restrict__ tr_b, const float* __restrict__ g_b1,
    const float* __restrict__ g_w2, const float* __restrict__ g_b2,
    float* __restrict__ t_out, float* __restrict__ gv)
{
    const int l = threadIdx.x;
    const int lr = l & 15, lg = l >> 4;
    const int row0 = blockIdx.x * 16;
    const int gate = (blockIdx.y == 8);
    const int slot = gate ? 14 : 15;
    const int col0 = gate ? 0 : blockIdx.y * 32;
    const int NF = gate ? 8 : 2;
    const ushort* bh0 = bt_hi + (long)slot * 65536;
    const ushort* bl0 = bt_lo + (long)slot * 65536;
    const float* arow = xg1 + (long)(row0 + lr) * 256;

    float s = 0.f, s2 = 0.f;
    #pragma unroll
    for (int ks = 0; ks < 8; ++ks) {
        const float4 a0 = *(const float4*)&arow[ks * 32 + lg * 8];
        const float4 a1 = *(const float4*)&arow[ks * 32 + lg * 8 + 4];
        s  += (a0.x + a0.y) + (a0.z + a0.w) + (a1.x + a1.y) + (a1.z + a1.w);
        s2 += a0.x * a0.x + a0.y * a0.y + a0.z * a0.z + a0.w * a0.w +
              a1.x * a1.x + a1.y * a1.y + a1.z * a1.z + a1.w * a1.w;
    }
    s += __shfl_xor(s, 16);  s += __shfl_xor(s, 32);
    s2 += __shfl_xor(s2, 16); s2 += __shfl_xor(s2, 32);
    const float mean = s * (1.f / 256.f);
    const float rs = rsqrtf(s2 * (1.f / 256.f) - mean * mean + 1e-5f);

    const f32x4 z4 = {0.f, 0.f, 0.f, 0.f};
    f32x4 acc[8] = {z4, z4, z4, z4, z4, z4, z4, z4};

    #pragma unroll
    for (int ks = 0; ks < 8; ++ks) {
        const int k0 = ks * 32;
        float av[8], gvv[8], bvv[8];
        *(float4*)&av[0] = *(const float4*)&arow[k0 + lg * 8];
        *(float4*)&av[4] = *(const float4*)&arow[k0 + lg * 8 + 4];
        *(float4*)&gvv[0] = *(const float4*)&ln_g[k0 + lg * 8];
        *(float4*)&gvv[4] = *(const float4*)&ln_g[k0 + lg * 8 + 4];
        *(float4*)&bvv[0] = *(const float4*)&ln_b[k0 + lg * 8];
        *(float4*)&bvv[4] = *(const float4*)&ln_b[k0 + lg * 8 + 4];
        short8 ahi, alo;
        #pragma unroll
        for (int j = 0; j < 8; ++j) {
            const float vn = (av[j] - mean) * rs * gvv[j] + bvv[j];
            const u32 bi = __float_as_uint(vn);
            ahi[j] = (short)(bi >> 16);
            const float fh = __uint_as_float(bi & 0xffff0000u);
            alo[j] = (short)f2bf(vn - fh);
        }
        for (int f = 0; f < NF; ++f) {
            const int cb = gate ? f : ((int)blockIdx.y * 2 + f);
            const long bo = (long)((cb * 8 + ks) << 9) + (l << 3);
            const short8 bhi = *(const short8*)&bh0[bo];
            const short8 blo = *(const short8*)&bl0[bo];
            acc[f] = __builtin_amdgcn_mfma_f32_16x16x32_bf16(ahi, bhi, acc[f], 0, 0, 0);
            acc[f] = __builtin_amdgcn_mfma_f32_16x16x32_bf16(alo, bhi, acc[f], 0, 0, 0);
            acc[f] = __builtin_amdgcn_mfma_f32_16x16x32_bf16(ahi, blo, acc[f], 0, 0, 0);
        }
    }

    if (!gate) {
        #pragma unroll
        for (int f = 0; f < 2; ++f) {
            const int col = col0 + f * 16 + lr;
            const float bv = tr_b[col];
            #pragma unroll
            for (int r = 0; r < 4; ++r) {
                const int rr = row0 + lg * 4 + r;
                t_out[(long)rr * 256 + col] = fmaxf(acc[f][r] + bv, 0.f);
            }
        }
    } else {
        float b1v[8], w2v[8];
        #pragma unroll
        for (int f = 0; f < 8; ++f) {
            b1v[f] = g_b1[f * 16 + lr];
            w2v[f] = g_w2[f * 16 + lr];
        }
        const float b2 = g_b2[0];
        #pragma unroll
        for (int r = 0; r < 4; ++r) {
            float t = 0.f;
            #pragma unroll
            for (int f = 0; f < 8; ++f)
                t += fmaxf(acc[f][r] + b1v[f], 0.f) * w2v[f];
            #pragma unroll
            for (int o = 1; o < 16; o <<= 1) t += __shfl_xor(t, o);
            if (lr == 0) gv[row0 + lg * 4 + r] = t + b2;
        }
    }
}

// ===========================================================================
// wsum + head (last-block finisher): partial[b][col] over 32 rows with
// per-block local max (flash); the last block (ticket) merges all 64
// partials exactly and computes out = pooled @ head_w + head_b.
// ===========================================================================
__global__ __launch_bounds__(256) void wsum_head_kernel(
    const float* __restrict__ gv, const float* __restrict__ t,
    float* __restrict__ partial, float* __restrict__ denp, float* __restrict__ mpart,
    const float* __restrict__ hw, const float* __restrict__ hb,
    float* __restrict__ out, u32* __restrict__ ticket)
{
    const float L2E = 1.4426950408889634f;
    const int b = blockIdx.x, tid = threadIdx.x;
    float M = -INFINITY;
    #pragma unroll
    for (int i = 0; i < 32; ++i) M = fmaxf(M, gv[b * 32 + i]);
    float s = 0.f, den = 0.f;
    #pragma unroll 4
    for (int i = 0; i < 32; ++i) {
        const int r = b * 32 + i;
        const float w = __builtin_amdgcn_exp2f((gv[r] - M) * L2E);
        den += w;
        s += w * t[(long)r * 256 + tid];
    }
    partial[b * 256 + tid] = s;
    if (tid == 0) { denp[b] = den; mpart[b] = M; }
    __threadfence();
    __syncthreads();
    __shared__ int lastFlag;
    if (tid == 0) lastFlag = (atomicAdd(ticket, 1u) == 63u) ? 1 : 0;
    __syncthreads();
    if (!lastFlag) return;
    __threadfence();  // acquire: make other blocks' writes visible

    __shared__ float fb[64];
    __shared__ float dtot;
    __shared__ float red0[4], red1[4];
    if (tid < 64) {
        const float mb = mpart[tid];
        float Mg = mb;
        #pragma unroll
        for (int o = 1; o < 64; o <<= 1) Mg = fmaxf(Mg, __shfl_xor(Mg, o));
        const float f = __builtin_amdgcn_exp2f((mb - Mg) * L2E);
        fb[tid] = f;
        float dv = f * denp[tid];
        #pragma unroll
        for (int o = 1; o < 64; o <<= 1) dv += __shfl_xor(dv, o);
        if (tid == 0) dtot = dv;
    }
    __syncthreads();
    float p = 0.f;
    #pragma unroll 8
    for (int bb = 0; bb < 64; ++bb) p += fb[bb] * partial[bb * 256 + tid];
    p /= dtot;
    float s0 = p * hw[tid * 2 + 0];
    float s1 = p * hw[tid * 2 + 1];
    #pragma unroll
    for (int o = 1; o < 64; o <<= 1) { s0 += __shfl_xor(s0, o); s1 += __shfl_xor(s1, o); }
    if ((tid & 63) == 0) { red0[tid >> 6] = s0; red1[tid >> 6] = s1; }
    __syncthreads();
    if (tid == 0) {
        out[0] = red0[0] + red0[1] + red0[2] + red0[3] + hb[0];
        out[1] = red1[0] + red1[1] + red1[2] + red1[3] + hb[1];
    }
}

// ---------------------------------------------------------------------------
extern "C" void kernel_launch(void* const* d_in, const int* in_sizes, int n_in,
                              void* d_out, int out_size, void* d_ws, size_t ws_size,
                              hipStream_t stream)
{
    (void)in_sizes; (void)n_in; (void)out_size; (void)ws_size;
    const float* gene_emb = (const float*)d_in[0];
    const float* pre_w1   = (const float*)d_in[3];
    const float* pre_b1   = (const float*)d_in[4];
    const float* pre_w2   = (const float*)d_in[5];
    const float* pre_b2   = (const float*)d_in[6];
    const float* pre_ln_g = (const float*)d_in[7];
    const float* pre_ln_b = (const float*)d_in[8];
    const float* wm       = (const float*)d_in[9];
    const float* wsw      = (const float*)d_in[10];
    const float* ln_g     = (const float*)d_in[11];
    const float* ln_b     = (const float*)d_in[12];
    const float* gate_w1  = (const float*)d_in[13];
    const float* gate_b1  = (const float*)d_in[14];
    const float* gate_w2  = (const float*)d_in[15];
    const float* gate_b2  = (const float*)d_in[16];
    const float* tr_w     = (const float*)d_in[17];
    const float* tr_b     = (const float*)d_in[18];
    const float* head_w   = (const float*)d_in[19];
    const float* head_b   = (const float*)d_in[20];
    const u8* adj_pp      = (const u8*)d_in[21];
    const u8* adj_rr      = (const u8*)d_in[22];
    // d_in[1],[2],[23],[24] dead (reaction/metab branches never reach output)

    const long NHf = (long)Gn * Hd;
    float* tmp0    = (float*)d_ws;
    float* tmp1    = tmp0 + NHf;
    float* xg1     = tmp1 + NHf;
    float* ctx2    = xg1 + NHf;
    float* gv      = ctx2 + 2 * NHf;
    float* partial = gv + Gn;
    float* denp    = partial + 64 * 256;
    float* mpart   = denp + 64;
    int* det0      = (int*)(mpart + 64);
    int* det1      = det0 + 64;
    u32* ticket    = (u32*)(det1 + 64);
    int* deg       = (int*)(ticket + 64);
    int* colidx    = deg + 4096;
    u32* bits      = (u32*)(colidx + 2L * 2048 * CSTRIDE);
    ushort* qkvb   = (ushort*)(bits + 262144);
    ushort* bt_hi  = qkvb + 2L * 1572864;
    ushort* bt_lo  = bt_hi + 16L * 65536;

    dim3 B256(256), B128(128), T64(64);

    // 1: detect || weight pre-split (also zeroes the wsum ticket)
    mergedA_kernel<<<dim3(192), B256, 0, stream>>>(adj_pp, det0, det1,
        pre_w1, pre_w2, wm, wsw, gate_w1, tr_w, bt_hi, bt_lo, ticket);
    // 2: pack masks + CSR || preGEMM1
    mergedB_kernel<<<dim3(2304), B128, 0, stream>>>(adj_pp, adj_rr, det0, det1,
        bits, deg, colidx, gene_emb, bt_hi, bt_lo, pre_b1, tmp0);
    // 3: preGEMM2 (LN1+relu fused)
    mergedC_kernel<<<dim3(256), B128, 0, stream>>>(tmp0, bt_hi, bt_lo,
        pre_b2, pre_ln_g, pre_ln_b, tmp1);
    // 4: QKV-M (LN2+relu fused; writes xg1)
    qkvm_kernel<<<dim3(64, 4, 6), B128, 0, stream>>>(tmp1, bt_hi, bt_lo,
        pre_ln_g, pre_ln_b, (float*)qkvb, xg1);
    // 5: sparse masked attention
    attn_sparse_kernel<<<dim3(2048, 2), T64, 0, stream>>>(qkvb, deg, colidx, ctx2);
    // 6: fused dual-Wo (K=512)
    wo_m_kernel<<<dim3(64, 4), B128, 0, stream>>>(ctx2, bt_hi, bt_lo, xg1);
    // 7: QKV-S
    qkvs_kernel<<<dim3(64, 4, 3), B128, 0, stream>>>(xg1, bt_hi, bt_lo, (float*)qkvb);
    // 8: dense self-attention (parallel 8-way merge)
    attn_dense_kernel<<<dim3(8, 64), dim3(512), 0, stream>>>(qkvb, ctx2);
    // 9: Wo-S
    wo_s_kernel<<<dim3(64, 4), B128, 0, stream>>>(ctx2, bt_hi, bt_lo, xg1);
    // 10: aggregation GEMM (LN3 fused)
    aggr_gemm_kernel<<<dim3(128, 9), T64, 0, stream>>>(xg1, bt_hi, bt_lo,
        ln_g, ln_b, tr_b, gate_b1, gate_w2, gate_b2, tmp0, gv);
    // 11: weighted sum + head (last-block finisher)
    wsum_head_kernel<<<dim3(64), B256, 0, stream>>>(gv, tmp0, partial, denp,
        mpart, head_w, head_b, (float*)d_out, ticket);
}